// Round 3
// baseline (3998.310 us; speedup 1.0000x reference)
//
#include <hip/hip_runtime.h>
#include <hip/hip_bf16.h>
#include <math.h>

typedef __bf16 bf16_t;
typedef __bf16 bf16x8 __attribute__((ext_vector_type(8)));
typedef __bf16 bf16x4 __attribute__((ext_vector_type(4)));
typedef float  f32x4  __attribute__((ext_vector_type(4)));

#define S_TOT 1024
#define T_W   32
#define D_EMB 300
#define KP    320
#define G3    768
#define Hh    256
#define H2    512
#define E_TOT 3072
#define NCANON 33

// ---------- dtype detector: flag=1 if float tensors are bf16, 0 if f32 ----------
__global__ void k_detect(const unsigned short* __restrict__ w, int* __restrict__ flag) {
  int lane = threadIdx.x;
  int sane = 0;
  for (int i = lane; i < 256; i += 64) {
    unsigned short v = w[2 * i];          // even 16-bit word of dword i
    int ex = (v >> 7) & 0xFF;             // bf16 exponent field
    sane += (ex >= 96 && ex <= 134) ? 1 : 0;
  }
  #pragma unroll
  for (int o = 32; o > 0; o >>= 1) sane += __shfl_down(sane, o, 64);
  if (lane == 0) flag[0] = (sane >= 128) ? 1 : 0;
}

// ---------- canonicalize all float tensors to f32 ----------
struct Canon {
  const void* src[NCANON];
  int off[NCANON + 1];
};
__global__ void k_canon(Canon c, const int* __restrict__ flag, float* __restrict__ dst) {
  int i = blockIdx.x * 256 + threadIdx.x;
  if (i >= c.off[NCANON]) return;
  int seg = 0;
  while (c.off[seg + 1] <= i) ++seg;
  int j = i - c.off[seg];
  dst[i] = flag[0] ? (float)((const bf16_t*)c.src[seg])[j]
                   : ((const float*)c.src[seg])[j];
}

__global__ void k_f2b(const float* __restrict__ s, bf16_t* __restrict__ d, int n) {
  int i = blockIdx.x * 256 + threadIdx.x;
  if (i < n) d[i] = (bf16_t)s[i];
}

__global__ void k_lens(const int* __restrict__ x, int* __restrict__ lens) {
  int s = blockIdx.x * blockDim.x + threadIdx.x;
  if (s >= S_TOT) return;
  int c = 0;
  for (int t = 0; t < T_W; ++t) c += (x[s * T_W + t] != 0) ? 1 : 0;
  lens[s] = c;
}

// wih [2][768][512] f32 -> [2][512][768] f32
__global__ void k_transpose(const float* __restrict__ w, float* __restrict__ out) {
  __shared__ float tile[32][33];
  int d  = blockIdx.z;
  int n0 = blockIdx.x * 32, k0 = blockIdx.y * 32;
  int tx = threadIdx.x & 31, ty = threadIdx.x >> 5;
  for (int i = ty; i < 32; i += 8)
    tile[i][tx] = w[((size_t)d * G3 + n0 + i) * H2 + k0 + tx];
  __syncthreads();
  for (int i = ty; i < 32; i += 8)
    out[((size_t)d * H2 + k0 + i) * G3 + n0 + tx] = tile[tx][i];
}

// ---------- fused gather + input projection: gi = embed[toks] @ wih^T + bih ----------
// A (embed) split into bf16 hi+lo (2 MFMA passes); B (wih, canonical f32) single-rounded.
__global__ __launch_bounds__(256) void k_giA(
    const int* __restrict__ toks, const void* __restrict__ embed,
    const float* __restrict__ wih, const float* __restrict__ bih,
    const int* __restrict__ flag, float* __restrict__ gi, int mbase) {
  __shared__ __align__(16) bf16_t Ah[64][32];
  __shared__ __align__(16) bf16_t Al[64][32];
  __shared__ __align__(16) bf16_t Bs[64][32];
  int tid = threadIdx.x;
  int wave = tid >> 6, lane = tid & 63;
  int l16 = lane & 15, quad = lane >> 4;
  int m0 = blockIdx.x * 64;
  int n0 = blockIdx.y * 64;
  int r  = tid >> 2;
  int kk = (tid & 3) * 8;
  int tok = toks[mbase + m0 + r];
  int isb = flag[0];
  const float*  ef = (const float*)embed + (size_t)tok * D_EMB;
  const bf16_t* eb = (const bf16_t*)embed + (size_t)tok * D_EMB;
  const float* wrow = wih + (size_t)(n0 + r) * D_EMB;
  f32x4 acc[4] = {{0.f,0.f,0.f,0.f},{0.f,0.f,0.f,0.f},{0.f,0.f,0.f,0.f},{0.f,0.f,0.f,0.f}};
  for (int k0 = 0; k0 < KP; k0 += 32) {
    int ka = k0 + kk;
    float av[8], bv[8];
    #pragma unroll
    for (int i = 0; i < 8; ++i) { av[i] = 0.f; bv[i] = 0.f; }
    if (ka < D_EMB) {        // 300 % 4 == 0: 4-groups never straddle the boundary
      if (isb) { bf16x4 t4 = *(const bf16x4*)(eb + ka);
                 av[0]=(float)t4[0]; av[1]=(float)t4[1]; av[2]=(float)t4[2]; av[3]=(float)t4[3]; }
      else     { float4 t4 = *(const float4*)(ef + ka);
                 av[0]=t4.x; av[1]=t4.y; av[2]=t4.z; av[3]=t4.w; }
      float4 w4 = *(const float4*)(wrow + ka);
      bv[0]=w4.x; bv[1]=w4.y; bv[2]=w4.z; bv[3]=w4.w;
    }
    if (ka + 4 < D_EMB) {
      if (isb) { bf16x4 t4 = *(const bf16x4*)(eb + ka + 4);
                 av[4]=(float)t4[0]; av[5]=(float)t4[1]; av[6]=(float)t4[2]; av[7]=(float)t4[3]; }
      else     { float4 t4 = *(const float4*)(ef + ka + 4);
                 av[4]=t4.x; av[5]=t4.y; av[6]=t4.z; av[7]=t4.w; }
      float4 w4 = *(const float4*)(wrow + ka + 4);
      bv[4]=w4.x; bv[5]=w4.y; bv[6]=w4.z; bv[7]=w4.w;
    }
    #pragma unroll
    for (int i = 0; i < 8; ++i) {
      bf16_t hi = (bf16_t)av[i];
      Ah[r][kk + i] = hi;
      Al[r][kk + i] = (bf16_t)(av[i] - (float)hi);
      Bs[r][kk + i] = (bf16_t)bv[i];
    }
    __syncthreads();
    bf16x8 ah = *(const bf16x8*)&Ah[wave * 16 + l16][quad * 8];
    bf16x8 al = *(const bf16x8*)&Al[wave * 16 + l16][quad * 8];
    #pragma unroll
    for (int j = 0; j < 4; ++j) {
      bf16x8 b8 = *(const bf16x8*)&Bs[j * 16 + l16][quad * 8];
      acc[j] = __builtin_amdgcn_mfma_f32_16x16x32_bf16(al, b8, acc[j], 0, 0, 0);
      acc[j] = __builtin_amdgcn_mfma_f32_16x16x32_bf16(ah, b8, acc[j], 0, 0, 0);
    }
    __syncthreads();
  }
  int row0 = m0 + wave * 16 + quad * 4;   // C/D: col=lane&15, row=quad*4+reg
  #pragma unroll
  for (int j = 0; j < 4; ++j) {
    int col = n0 + j * 16 + l16;
    float bvv = bih[col];
    #pragma unroll
    for (int rr = 0; rr < 4; ++rr)
      gi[(size_t)(row0 + rr) * G3 + col] = acc[j][rr] + bvv;
  }
}

// ---------- f32 SGEMM: C[M][N] = A[M][K] @ B[K][N] (+bias) ----------
__global__ __launch_bounds__(256) void k_sgemm(
    const float* __restrict__ A, const float* __restrict__ B,
    const float* __restrict__ bias, float* __restrict__ C,
    int M, int N, int K) {
  __shared__ float As[32][65];
  __shared__ float Bs[32][65];
  int bm = blockIdx.x * 64, bn = blockIdx.y * 64;
  int tid = threadIdx.x;
  int tx = tid & 15, ty = tid >> 4;
  float acc[4][4] = {};
  for (int k0 = 0; k0 < K; k0 += 32) {
    for (int i = tid; i < 64 * 32; i += 256) {
      int m = i >> 5, k = i & 31;
      As[k][m] = (bm + m < M) ? A[(size_t)(bm + m) * K + k0 + k] : 0.f;
    }
    for (int i = tid; i < 32 * 64; i += 256) {
      int k = i >> 6, n = i & 63;
      Bs[k][n] = B[(size_t)(k0 + k) * N + bn + n];
    }
    __syncthreads();
    #pragma unroll 8
    for (int k = 0; k < 32; ++k) {
      float a[4], b[4];
      #pragma unroll
      for (int i = 0; i < 4; ++i) a[i] = As[k][ty + i * 16];
      #pragma unroll
      for (int j = 0; j < 4; ++j) b[j] = Bs[k][tx + j * 16];
      #pragma unroll
      for (int i = 0; i < 4; ++i)
        #pragma unroll
        for (int j = 0; j < 4; ++j) acc[i][j] += a[i] * b[j];
    }
    __syncthreads();
  }
  for (int i = 0; i < 4; ++i) {
    int m = bm + ty + i * 16;
    if (m >= M) continue;
    for (int j = 0; j < 4; ++j) {
      int n = bn + tx + j * 16;
      C[(size_t)m * N + n] = acc[i][j] + (bias ? bias[n] : 0.f);
    }
  }
}

// ---------- GRU recurrence, 4 rows/block, split-K over 512 threads ----------
__global__ __launch_bounds__(512) void k_gru(
    const float* __restrict__ gi, const bf16_t* __restrict__ whh,
    const float* __restrict__ bhh, const int* __restrict__ lens,
    float* __restrict__ pool, int T, int dir, int sbase) {
  __shared__ __align__(16) float hsh[Hh][4];
  __shared__ float red[256][13];
  int tid = threadIdx.x;
  int j = tid & 255, half = tid >> 8;
  int b0 = sbase + blockIdx.x * 4;
  if (half == 0) { hsh[j][0] = hsh[j][1] = hsh[j][2] = hsh[j][3] = 0.f; }
  float pmax[4] = {-1e30f, -1e30f, -1e30f, -1e30f};
  int L[4];
  #pragma unroll
  for (int s = 0; s < 4; ++s) L[s] = lens ? lens[b0 + s] : T;
  float bhr = bhh[j], bhz = bhh[256 + j], bhn = bhh[512 + j];
  const bf16_t* wr = whh + (size_t)j * Hh + half * 128;
  const bf16_t* wz = whh + (size_t)(Hh + j) * Hh + half * 128;
  const bf16_t* wn = whh + (size_t)(2 * Hh + j) * Hh + half * 128;
  int kbase = half * 128;
  __syncthreads();
  for (int step = 0; step < T; ++step) {
    int t = dir ? (T - 1 - step) : step;
    float ar[4], az[4], an[4];
    #pragma unroll
    for (int s = 0; s < 4; ++s) {
      ar[s] = half ? 0.f : bhr; az[s] = half ? 0.f : bhz; an[s] = half ? 0.f : bhn;
    }
    #pragma unroll 4
    for (int k0 = 0; k0 < 128; k0 += 8) {
      bf16x8 w_r = *(const bf16x8*)(wr + k0);
      bf16x8 w_z = *(const bf16x8*)(wz + k0);
      bf16x8 w_n = *(const bf16x8*)(wn + k0);
      #pragma unroll
      for (int kk = 0; kk < 8; ++kk) {
        float4 hv = *(const float4*)(&hsh[kbase + k0 + kk][0]);
        float a = (float)w_r[kk], b = (float)w_z[kk], c = (float)w_n[kk];
        ar[0] += hv.x * a; ar[1] += hv.y * a; ar[2] += hv.z * a; ar[3] += hv.w * a;
        az[0] += hv.x * b; az[1] += hv.y * b; az[2] += hv.z * b; az[3] += hv.w * b;
        an[0] += hv.x * c; an[1] += hv.y * c; an[2] += hv.z * c; an[3] += hv.w * c;
      }
    }
    if (half) {
      #pragma unroll
      for (int s = 0; s < 4; ++s) { red[j][s] = ar[s]; red[j][4 + s] = az[s]; red[j][8 + s] = an[s]; }
    }
    __syncthreads();
    if (!half) {
      #pragma unroll
      for (int s = 0; s < 4; ++s) {
        size_t rb = ((size_t)(b0 + s - sbase) * T + t) * (size_t)G3;
        float gr = gi[rb + j]       + ar[s] + red[j][s];
        float gz = gi[rb + 256 + j] + az[s] + red[j][4 + s];
        float gn = gi[rb + 512 + j];
        float rr = 1.f / (1.f + expf(-gr));
        float zz = 1.f / (1.f + expf(-gz));
        float nn = tanhf(gn + rr * (an[s] + red[j][8 + s]));
        float hnew = (1.f - zz) * nn + zz * hsh[j][s];
        hsh[j][s] = hnew;
        if (t < L[s]) pmax[s] = fmaxf(pmax[s], hnew);
      }
    }
    __syncthreads();
  }
  if (!half) {
    #pragma unroll
    for (int s = 0; s < 4; ++s) {
      float v = pmax[s];
      if (v < -9e29f) v = 0.f;
      pool[(size_t)(b0 + s) * H2 + dir * Hh + j] = v;
    }
  }
}

// ---------- GRU, 1 row/block (sent/doc levels) ----------
__global__ __launch_bounds__(768) void k_gru1(
    const float* __restrict__ gi, const bf16_t* __restrict__ whh,
    const float* __restrict__ bhh, float* __restrict__ pool, int T, int dir) {
  __shared__ float hsh[Hh];
  __shared__ float ghs[G3];
  int b = blockIdx.x;
  int g = threadIdx.x;
  if (g < Hh) hsh[g] = 0.f;
  float bh = bhh[g];
  const bf16_t* wrow = whh + (size_t)g * Hh;
  float pmax = -1e30f;
  __syncthreads();
  for (int step = 0; step < T; ++step) {
    int t = dir ? (T - 1 - step) : step;
    float acc = bh;
    #pragma unroll 4
    for (int k0 = 0; k0 < Hh; k0 += 8) {
      bf16x8 w8 = *(const bf16x8*)(wrow + k0);
      #pragma unroll
      for (int kk = 0; kk < 8; ++kk) acc += hsh[k0 + kk] * (float)w8[kk];
    }
    ghs[g] = acc;
    __syncthreads();
    if (g < Hh) {
      size_t rb = ((size_t)b * T + t) * (size_t)G3;
      float rr = 1.f / (1.f + expf(-(gi[rb + g] + ghs[g])));
      float zz = 1.f / (1.f + expf(-(gi[rb + Hh + g] + ghs[Hh + g])));
      float nn = tanhf(gi[rb + 2 * Hh + g] + rr * ghs[2 * Hh + g]);
      float hnew = (1.f - zz) * nn + zz * hsh[g];
      hsh[g] = hnew;
      pmax = fmaxf(pmax, hnew);
    }
    __syncthreads();
  }
  if (g < Hh) pool[(size_t)b * H2 + dir * Hh + g] = (pmax < -9e29f) ? 0.f : pmax;
}

// ---------- epilogue ----------
__global__ void k_zero(float* __restrict__ p, int n) {
  int i = blockIdx.x * blockDim.x + threadIdx.x;
  if (i < n) p[i] = 0.f;
}

__global__ __launch_bounds__(512) void k_colsum(const float* __restrict__ ev, float* __restrict__ out) {
  int t = threadIdx.x;
  int r0 = blockIdx.x * 256;
  float s = 0.f;
  for (int r = 0; r < 256; ++r) s += ev[(size_t)(r0 + r) * H2 + t];
  atomicAdd(&out[t], s);
}

__global__ void k_ves(const float* __restrict__ W, const float* __restrict__ sum, float* __restrict__ ves) {
  int d = blockIdx.x * 64 + threadIdx.x;
  const float* row = W + (size_t)d * H2;
  float s = 0.f;
  for (int f = 0; f < H2; ++f) s += row[f] * sum[f];
  ves[d] = s * (1.f / 3072.f);
}

__global__ void k_sal(const float* __restrict__ W, const float* __restrict__ blog,
                      const float* __restrict__ dv, float* __restrict__ out) {
  int doc = blockIdx.y;
  int i = blockIdx.x * 64 + threadIdx.x;
  const float* row = W + (size_t)i * (2 * H2);
  const float* dvr = dv + (size_t)doc * H2;
  float s = 0.f;
  for (int f = 0; f < H2; ++f) s += row[f] * blog[f];
  for (int f = 0; f < H2; ++f) s += row[H2 + f] * dvr[f];
  out[(size_t)doc * H2 + i] = s;
}

__global__ __launch_bounds__(256) void k_eventprobs(
    const float* __restrict__ evv, const float* __restrict__ ves,
    const float* __restrict__ w_ec, const float* __restrict__ tfs,
    const float* __restrict__ st, const float* __restrict__ c_tf,
    const float* __restrict__ c_sent, const float* __restrict__ c_bias,
    const int* __restrict__ flag, float* __restrict__ probs, void* __restrict__ outp) {
  int lane = threadIdx.x & 63;
  int e = blockIdx.x * 4 + (threadIdx.x >> 6);
  const float* row = evv + (size_t)e * H2;
  float s = 0.f;
  for (int f = lane; f < H2; f += 64) s += row[f] * (w_ec[f] + ves[f]);
  #pragma unroll
  for (int o = 32; o > 0; o >>= 1) s += __shfl_down(s, o, 64);
  if (lane == 0) {
    float p = s + c_tf[0] * tfs[e] + c_bias[0] + c_sent[0] * st[e / 3];
    probs[e] = p;
    if (flag[0]) ((bf16_t*)outp)[S_TOT + e] = (bf16_t)p;
    else         ((float*)outp)[S_TOT + e] = p;
  }
}

__global__ __launch_bounds__(256) void k_sentout(
    const float* __restrict__ sv, const float* __restrict__ u,
    const float* __restrict__ evv, const float* __restrict__ probs,
    const float* __restrict__ wsal, const float* __restrict__ w_sc,
    const float* __restrict__ dpe, const float* __restrict__ spe,
    const float* __restrict__ w_sdp, const float* __restrict__ w_sp,
    const float* __restrict__ b_rel, const float* __restrict__ para,
    const float* __restrict__ sbias, const int* __restrict__ flag,
    void* __restrict__ outp) {
  int lane = threadIdx.x & 63;
  int s = blockIdx.x * 4 + (threadIdx.x >> 6);
  int doc = s >> 5, jj = s & 31;
  const float* svr = sv + (size_t)s * H2;
  const float* ur  = u + (size_t)s * H2;
  const float* wd  = wsal + (size_t)doc * H2;
  float acc = 0.f, e0 = 0.f, e1 = 0.f, e2 = 0.f;
  for (int f = lane; f < H2; f += 64) {
    float svf = svr[f], uf = ur[f];
    acc += svf * (w_sc[f] + wd[f]);
    e0 += uf * evv[(size_t)(s * 3 + 0) * H2 + f];
    e1 += uf * evv[(size_t)(s * 3 + 1) * H2 + f];
    e2 += uf * evv[(size_t)(s * 3 + 2) * H2 + f];
  }
  if (lane < 50) {
    int dpos = (doc * 40) / 32;
    int spos = (jj * 30) / 32;
    acc += dpe[dpos * 50 + lane] * w_sdp[lane] + spe[spos * 50 + lane] * w_sp[lane];
  }
  #pragma unroll
  for (int o = 32; o > 0; o >>= 1) {
    acc += __shfl_down(acc, o, 64);
    e0  += __shfl_down(e0, o, 64);
    e1  += __shfl_down(e1, o, 64);
    e2  += __shfl_down(e2, o, 64);
  }
  if (lane == 0) {
    float br = b_rel[0];
    float rel = (e0 + br) * probs[s * 3 + 0] + (e1 + br) * probs[s * 3 + 1]
              + (e2 + br) * probs[s * 3 + 2];
    float v = acc + para[0] * rel + sbias[0];
    if (flag[0]) ((bf16_t*)outp)[s] = (bf16_t)v;
    else         ((float*)outp)[s] = v;
  }
}

// ---------------- launcher ----------------
extern "C" void kernel_launch(void* const* d_in, const int* in_sizes, int n_in,
                              void* d_out, int out_size, void* d_ws, size_t ws_size,
                              hipStream_t stream) {
  (void)in_sizes; (void)n_in; (void)out_size;
  const int* x      = (const int*)d_in[0];
  const int* events = (const int*)d_in[1];
  const void* embed = d_in[8];

  char* ws = (char*)d_ws;
  size_t off = 0;
  auto alloc = [&](size_t bytes) -> void* {
    void* p = ws + off;
    off += (bytes + 255) & ~(size_t)255;
    return p;
  };

  // canonicalization table (order: see setup_inputs)
  static const int cidx[NCANON] = {9,10,11,12, 13,14,15,16, 17,18,19,20, 21,22,23,24,
                                   25,26,27,28,29,30,31, 32,33,34,35, 36,37,38,40, 5,7};
  static const int csz[NCANON]  = {2*G3*D_EMB, 2*G3*Hh, 2*G3, 2*G3,
                                   2*G3*H2,    2*G3*Hh, 2*G3, 2*G3,
                                   2*G3*H2,    2*G3*Hh, 2*G3, 2*G3,
                                   2*G3*D_EMB, 2*G3*Hh, 2*G3, 2*G3,
                                   40*50, 30*50, H2, H2*H2, 1, 1, 1,
                                   H2, H2*2*H2, 50, 50,
                                   H2*H2, 1, 1, 1, E_TOT, S_TOT};
  Canon cd;
  int tot = 0;
  for (int i = 0; i < NCANON; ++i) { cd.src[i] = d_in[cidx[i]]; cd.off[i] = tot; tot += csz[i]; }
  cd.off[NCANON] = tot;

  int*   flag  = (int*)alloc(256);
  float* canon = (float*)alloc((size_t)tot * 4);
  float* cptr[NCANON];
  for (int i = 0; i < NCANON; ++i) cptr[i] = canon + cd.off[i];
  // canonical pointers
  float *cw_wih = cptr[0], *cw_whh = cptr[1], *cw_bih = cptr[2], *cw_bhh = cptr[3];
  float *cs_wih = cptr[4], *cs_whh = cptr[5], *cs_bih = cptr[6], *cs_bhh = cptr[7];
  float *cd_wih = cptr[8], *cd_whh = cptr[9], *cd_bih = cptr[10], *cd_bhh = cptr[11];
  float *ce_wih = cptr[12], *ce_whh = cptr[13], *ce_bih = cptr[14], *ce_bhh = cptr[15];
  float *c_dpe = cptr[16], *c_spe = cptr[17], *c_wec = cptr[18], *c_Wes = cptr[19];
  float *c_tf = cptr[20], *c_sent = cptr[21], *c_ebias = cptr[22];
  float *c_wsc = cptr[23], *c_Wss = cptr[24], *c_wsdp = cptr[25], *c_wsp = cptr[26];
  float *c_Wer = cptr[27], *c_brel = cptr[28], *c_para = cptr[29], *c_sbias = cptr[30];
  float *c_tfs = cptr[31], *c_starg = cptr[32];

  bf16_t* whhW = (bf16_t*)alloc((size_t)2 * G3 * Hh * 2);
  bf16_t* whhE = (bf16_t*)alloc((size_t)2 * G3 * Hh * 2);
  bf16_t* whhS = (bf16_t*)alloc((size_t)2 * G3 * Hh * 2);
  bf16_t* whhD = (bf16_t*)alloc((size_t)2 * G3 * Hh * 2);
  float*  sv   = (float*)alloc((size_t)S_TOT * H2 * 4);
  float*  evv  = (float*)alloc((size_t)E_TOT * H2 * 4);
  float*  dv   = (float*)alloc((size_t)32 * H2 * 4);
  float*  blog = (float*)alloc((size_t)H2 * 4);
  float*  wSt  = (float*)alloc((size_t)2 * H2 * G3 * 4);
  float*  wDt  = (float*)alloc((size_t)2 * H2 * G3 * 4);
  float*  u    = (float*)alloc((size_t)S_TOT * H2 * 4);
  float*  esum = (float*)alloc((size_t)H2 * 4);
  float*  ves  = (float*)alloc((size_t)H2 * 4);
  float*  wsal = (float*)alloc((size_t)32 * H2 * 4);
  float*  probs= (float*)alloc((size_t)E_TOT * 4);
  int*    lens = (int*)alloc((size_t)S_TOT * 4);

  // gi buffer: remainder of ws, chunk-adaptive (f32 rows of 768)
  size_t fixed = off;
  size_t avail = (ws_size > fixed) ? (ws_size - fixed) : 0;
  long long rpc = (long long)(avail / ((size_t)G3 * 4));
  rpc &= ~1023LL;
  if (rpc < 1024) rpc = 1024;
  if (rpc > 32768) rpc = 32768;
  float* gib = (float*)(ws + fixed);

  // ---- prep ----
  k_detect<<<1, 64, 0, stream>>>((const unsigned short*)embed, flag);
  k_canon<<<(tot + 255) / 256, 256, 0, stream>>>(cd, flag, canon);
  int nwhh = 2 * G3 * Hh;
  k_f2b<<<(nwhh + 255) / 256, 256, 0, stream>>>(cw_whh, whhW, nwhh);
  k_f2b<<<(nwhh + 255) / 256, 256, 0, stream>>>(ce_whh, whhE, nwhh);
  k_f2b<<<(nwhh + 255) / 256, 256, 0, stream>>>(cs_whh, whhS, nwhh);
  k_f2b<<<(nwhh + 255) / 256, 256, 0, stream>>>(cd_whh, whhD, nwhh);
  k_lens<<<4, 256, 0, stream>>>(x, lens);
  k_transpose<<<dim3(24, 16, 2), 256, 0, stream>>>(cs_wih, wSt);
  k_transpose<<<dim3(24, 16, 2), 256, 0, stream>>>(cd_wih, wDt);

  // ---- word BiGRU -> sent_vec ----
  for (int dir = 0; dir < 2; ++dir) {
    for (long long r0 = 0; r0 < 32768; r0 += rpc) {
      long long rows = 32768 - r0; if (rows > rpc) rows = rpc;
      k_giA<<<dim3((int)(rows / 64), 12), 256, 0, stream>>>(
          x, embed, cw_wih + (size_t)dir * G3 * D_EMB, cw_bih + dir * G3, flag, gib, (int)r0);
      k_gru<<<(int)(rows / 128), 512, 0, stream>>>(
          gib, whhW + (size_t)dir * G3 * Hh, cw_bhh + dir * G3, lens, sv,
          32, dir, (int)(r0 / 32));
    }
  }
  // ---- event BiGRU -> event_vec ----
  for (int dir = 0; dir < 2; ++dir) {
    for (long long r0 = 0; r0 < 12288; r0 += rpc) {
      long long rows = 12288 - r0; if (rows > rpc) rows = rpc;
      k_giA<<<dim3((int)(rows / 64), 12), 256, 0, stream>>>(
          events, embed, ce_wih + (size_t)dir * G3 * D_EMB, ce_bih + dir * G3, flag, gib, (int)r0);
      k_gru<<<(int)(rows / 16), 512, 0, stream>>>(
          gib, whhE + (size_t)dir * G3 * Hh, ce_bhh + dir * G3, nullptr, evv,
          4, dir, (int)(r0 / 4));
    }
  }
  // ---- sent BiGRU (per doc) -> doc_vec ----
  for (int dir = 0; dir < 2; ++dir) {
    k_sgemm<<<dim3(16, 12), 256, 0, stream>>>(sv, wSt + (size_t)dir * H2 * G3,
                                              cs_bih + dir * G3, gib, 1024, G3, H2);
    k_gru1<<<32, 768, 0, stream>>>(gib, whhS + (size_t)dir * G3 * Hh,
                                   cs_bhh + dir * G3, dv, 32, dir);
  }
  // ---- doc BiGRU -> blog_vec ----
  for (int dir = 0; dir < 2; ++dir) {
    k_sgemm<<<dim3(1, 12), 256, 0, stream>>>(dv, wDt + (size_t)dir * H2 * G3,
                                             cd_bih + dir * G3, gib, 32, G3, H2);
    k_gru1<<<1, 768, 0, stream>>>(gib, whhD + (size_t)dir * G3 * Hh,
                                  cd_bhh + dir * G3, blog, 32, dir);
  }
  // ---- u = sent_vec @ W_event_rel ----
  k_sgemm<<<dim3(16, 8), 256, 0, stream>>>(sv, c_Wer, nullptr, u, 1024, H2, H2);
  // ---- event_sum, ves, wsal ----
  k_zero<<<1, 512, 0, stream>>>(esum, 512);
  k_colsum<<<12, 512, 0, stream>>>(evv, esum);
  k_ves<<<8, 64, 0, stream>>>(c_Wes, esum, ves);
  k_sal<<<dim3(8, 32), 64, 0, stream>>>(c_Wss, blog, dv, wsal);
  // ---- outputs ----
  k_eventprobs<<<768, 256, 0, stream>>>(evv, ves, c_wec, c_tfs, c_starg,
                                        c_tf, c_sent, c_ebias, flag, probs, d_out);
  k_sentout<<<256, 256, 0, stream>>>(sv, u, evv, probs, wsal, c_wsc, c_dpe, c_spe,
                                     c_wsdp, c_wsp, c_brel, c_para, c_sbias, flag, d_out);
}

// Round 4
// 3361.981 us; speedup vs baseline: 1.1893x; 1.1893x over previous
//
#include <hip/hip_runtime.h>
#include <hip/hip_bf16.h>
#include <math.h>

typedef __bf16 bf16_t;
typedef __bf16 bf16x8 __attribute__((ext_vector_type(8)));
typedef __bf16 bf16x4 __attribute__((ext_vector_type(4)));
typedef float  f32x4  __attribute__((ext_vector_type(4)));

#define S_TOT 1024
#define T_W   32
#define D_EMB 300
#define KP    320
#define G3    768
#define Hh    256
#define H2    512
#define E_TOT 3072
#define NCANON 33

// ---------- dtype detector: flag=1 if float tensors are bf16, 0 if f32 ----------
__global__ void k_detect(const unsigned short* __restrict__ w, int* __restrict__ flag) {
  int lane = threadIdx.x;
  int sane = 0;
  for (int i = lane; i < 256; i += 64) {
    unsigned short v = w[2 * i];
    int ex = (v >> 7) & 0xFF;
    sane += (ex >= 96 && ex <= 134) ? 1 : 0;
  }
  #pragma unroll
  for (int o = 32; o > 0; o >>= 1) sane += __shfl_down(sane, o, 64);
  if (lane == 0) flag[0] = (sane >= 128) ? 1 : 0;
}

// ---------- canonicalize all float tensors to f32 ----------
struct Canon {
  const void* src[NCANON];
  int off[NCANON + 1];
};
__global__ void k_canon(Canon c, const int* __restrict__ flag, float* __restrict__ dst) {
  int i = blockIdx.x * 256 + threadIdx.x;
  if (i >= c.off[NCANON]) return;
  int seg = 0;
  while (c.off[seg + 1] <= i) ++seg;
  int j = i - c.off[seg];
  dst[i] = flag[0] ? (float)((const bf16_t*)c.src[seg])[j]
                   : ((const float*)c.src[seg])[j];
}

__global__ void k_f2b(const float* __restrict__ s, bf16_t* __restrict__ d, int n) {
  int i = blockIdx.x * 256 + threadIdx.x;
  if (i < n) d[i] = (bf16_t)s[i];
}

__global__ void k_lens(const int* __restrict__ x, int* __restrict__ lens) {
  int s = blockIdx.x * blockDim.x + threadIdx.x;
  if (s >= S_TOT) return;
  int c = 0;
  for (int t = 0; t < T_W; ++t) c += (x[s * T_W + t] != 0) ? 1 : 0;
  lens[s] = c;
}

// wih [2][768][512] f32 -> [2][512][768] f32
__global__ void k_transpose(const float* __restrict__ w, float* __restrict__ out) {
  __shared__ float tile[32][33];
  int d  = blockIdx.z;
  int n0 = blockIdx.x * 32, k0 = blockIdx.y * 32;
  int tx = threadIdx.x & 31, ty = threadIdx.x >> 5;
  for (int i = ty; i < 32; i += 8)
    tile[i][tx] = w[((size_t)d * G3 + n0 + i) * H2 + k0 + tx];
  __syncthreads();
  for (int i = ty; i < 32; i += 8)
    out[((size_t)d * H2 + k0 + i) * G3 + n0 + tx] = tile[tx][i];
}

// ---------- fused gather + input projection: gi = embed[toks] @ wih^T + bih ----------
__global__ __launch_bounds__(256) void k_giA(
    const int* __restrict__ toks, const void* __restrict__ embed,
    const float* __restrict__ wih, const float* __restrict__ bih,
    const int* __restrict__ flag, float* __restrict__ gi, int mbase) {
  __shared__ __align__(16) bf16_t Ah[64][32];
  __shared__ __align__(16) bf16_t Al[64][32];
  __shared__ __align__(16) bf16_t Bs[64][32];
  int tid = threadIdx.x;
  int wave = tid >> 6, lane = tid & 63;
  int l16 = lane & 15, quad = lane >> 4;
  int m0 = blockIdx.x * 64;
  int n0 = blockIdx.y * 64;
  int r  = tid >> 2;
  int kk = (tid & 3) * 8;
  int tok = toks[mbase + m0 + r];
  int isb = flag[0];
  const float*  ef = (const float*)embed + (size_t)tok * D_EMB;
  const bf16_t* eb = (const bf16_t*)embed + (size_t)tok * D_EMB;
  const float* wrow = wih + (size_t)(n0 + r) * D_EMB;
  f32x4 acc[4] = {{0.f,0.f,0.f,0.f},{0.f,0.f,0.f,0.f},{0.f,0.f,0.f,0.f},{0.f,0.f,0.f,0.f}};
  for (int k0 = 0; k0 < KP; k0 += 32) {
    int ka = k0 + kk;
    float av[8], bv[8];
    #pragma unroll
    for (int i = 0; i < 8; ++i) { av[i] = 0.f; bv[i] = 0.f; }
    if (ka < D_EMB) {
      if (isb) { bf16x4 t4 = *(const bf16x4*)(eb + ka);
                 av[0]=(float)t4[0]; av[1]=(float)t4[1]; av[2]=(float)t4[2]; av[3]=(float)t4[3]; }
      else     { float4 t4 = *(const float4*)(ef + ka);
                 av[0]=t4.x; av[1]=t4.y; av[2]=t4.z; av[3]=t4.w; }
      float4 w4 = *(const float4*)(wrow + ka);
      bv[0]=w4.x; bv[1]=w4.y; bv[2]=w4.z; bv[3]=w4.w;
    }
    if (ka + 4 < D_EMB) {
      if (isb) { bf16x4 t4 = *(const bf16x4*)(eb + ka + 4);
                 av[4]=(float)t4[0]; av[5]=(float)t4[1]; av[6]=(float)t4[2]; av[7]=(float)t4[3]; }
      else     { float4 t4 = *(const float4*)(ef + ka + 4);
                 av[4]=t4.x; av[5]=t4.y; av[6]=t4.z; av[7]=t4.w; }
      float4 w4 = *(const float4*)(wrow + ka + 4);
      bv[4]=w4.x; bv[5]=w4.y; bv[6]=w4.z; bv[7]=w4.w;
    }
    #pragma unroll
    for (int i = 0; i < 8; ++i) {
      bf16_t hi = (bf16_t)av[i];
      Ah[r][kk + i] = hi;
      Al[r][kk + i] = (bf16_t)(av[i] - (float)hi);
      Bs[r][kk + i] = (bf16_t)bv[i];
    }
    __syncthreads();
    bf16x8 ah = *(const bf16x8*)&Ah[wave * 16 + l16][quad * 8];
    bf16x8 al = *(const bf16x8*)&Al[wave * 16 + l16][quad * 8];
    #pragma unroll
    for (int j = 0; j < 4; ++j) {
      bf16x8 b8 = *(const bf16x8*)&Bs[j * 16 + l16][quad * 8];
      acc[j] = __builtin_amdgcn_mfma_f32_16x16x32_bf16(al, b8, acc[j], 0, 0, 0);
      acc[j] = __builtin_amdgcn_mfma_f32_16x16x32_bf16(ah, b8, acc[j], 0, 0, 0);
    }
    __syncthreads();
  }
  int row0 = m0 + wave * 16 + quad * 4;   // C/D: col=lane&15, row=quad*4+reg
  #pragma unroll
  for (int j = 0; j < 4; ++j) {
    int col = n0 + j * 16 + l16;
    float bvv = bih[col];
    #pragma unroll
    for (int rr = 0; rr < 4; ++rr)
      gi[(size_t)(row0 + rr) * G3 + col] = acc[j][rr] + bvv;
  }
}

// ---------- f32 SGEMM: C[M][N] = A[M][K] @ B[K][N] (+bias) ----------
__global__ __launch_bounds__(256) void k_sgemm(
    const float* __restrict__ A, const float* __restrict__ B,
    const float* __restrict__ bias, float* __restrict__ C,
    int M, int N, int K) {
  __shared__ float As[32][65];
  __shared__ float Bs[32][65];
  int bm = blockIdx.x * 64, bn = blockIdx.y * 64;
  int tid = threadIdx.x;
  int tx = tid & 15, ty = tid >> 4;
  float acc[4][4] = {};
  for (int k0 = 0; k0 < K; k0 += 32) {
    for (int i = tid; i < 64 * 32; i += 256) {
      int m = i >> 5, k = i & 31;
      As[k][m] = (bm + m < M) ? A[(size_t)(bm + m) * K + k0 + k] : 0.f;
    }
    for (int i = tid; i < 32 * 64; i += 256) {
      int k = i >> 6, n = i & 63;
      Bs[k][n] = B[(size_t)(k0 + k) * N + bn + n];
    }
    __syncthreads();
    #pragma unroll 8
    for (int k = 0; k < 32; ++k) {
      float a[4], b[4];
      #pragma unroll
      for (int i = 0; i < 4; ++i) a[i] = As[k][ty + i * 16];
      #pragma unroll
      for (int j = 0; j < 4; ++j) b[j] = Bs[k][tx + j * 16];
      #pragma unroll
      for (int i = 0; i < 4; ++i)
        #pragma unroll
        for (int j = 0; j < 4; ++j) acc[i][j] += a[i] * b[j];
    }
    __syncthreads();
  }
  for (int i = 0; i < 4; ++i) {
    int m = bm + ty + i * 16;
    if (m >= M) continue;
    for (int j = 0; j < 4; ++j) {
      int n = bn + tx + j * 16;
      C[(size_t)m * N + n] = acc[i][j] + (bias ? bias[n] : 0.f);
    }
  }
}

// ---------- batched MFMA GRU: 16 rows/block, dirs fused via blockIdx.y ----------
// gi: [dir][rows][768] f32 chunk (rows = nsent_chunk * T). whh: [2][768][256] bf16.
// Each wave owns j-slice [wave*32, wave*32+32) across all 3 gates -> in-register update.
// h kept in LDS as bf16 hi+lo in MFMA-A fragment-major order.
__global__ __launch_bounds__(512) void k_gruM(
    const float* __restrict__ gi, size_t gi_dstride,
    const bf16_t* __restrict__ whh, const float* __restrict__ bhh,
    const int* __restrict__ lens, float* __restrict__ pool,
    int T, int sbase) {
  int dir = blockIdx.y;
  int tid = threadIdx.x;
  int wave = tid >> 6, lane = tid & 63;
  int l16 = lane & 15, quad = lane >> 4;
  int sblk = blockIdx.x * 16;                 // chunk-relative sentence base
  const float*  giD  = gi + (size_t)dir * gi_dstride;
  const bf16_t* whhD = whh + (size_t)dir * (size_t)G3 * Hh;
  const float*  bhhD = bhh + (size_t)dir * G3;

  // h fragments: [hi/lo][k0][quad][m][8]  (A-frag for lane(l16=m,quad): &hA[hl][k0][quad][m][0])
  __shared__ __align__(16) bf16_t hA[2][8][4][16][8];
  {
    bf16_t* hz = &hA[0][0][0][0][0];
    for (int i = tid; i < 2 * 8 * 4 * 16 * 8; i += 512) hz[i] = (bf16_t)0.f;
  }

  // step-invariant per-lane data
  float bh[3][2];
  const bf16_t* bptr[3][2];
  #pragma unroll
  for (int g = 0; g < 3; ++g)
    #pragma unroll
    for (int jt = 0; jt < 2; ++jt) {
      int n = g * Hh + wave * 32 + jt * 16 + l16;
      bh[g][jt] = bhhD[n];
      bptr[g][jt] = whhD + (size_t)n * Hh + quad * 8;
    }
  int Lm[4];
  #pragma unroll
  for (int r = 0; r < 4; ++r)
    Lm[r] = lens ? lens[sbase + sblk + quad * 4 + r] : T;

  float hprev[2][4], pmax[2][4];
  #pragma unroll
  for (int jt = 0; jt < 2; ++jt)
    #pragma unroll
    for (int r = 0; r < 4; ++r) { hprev[jt][r] = 0.f; pmax[jt][r] = -1e30f; }

  // prefetch gi for step 0
  float gv[3][2][4];
  {
    int t0 = dir ? (T - 1) : 0;
    #pragma unroll
    for (int jt = 0; jt < 2; ++jt) {
      int j = wave * 32 + jt * 16 + l16;
      #pragma unroll
      for (int r = 0; r < 4; ++r) {
        size_t rb = ((size_t)(sblk + quad * 4 + r) * T + t0) * (size_t)G3;
        gv[0][jt][r] = giD[rb + j];
        gv[1][jt][r] = giD[rb + Hh + j];
        gv[2][jt][r] = giD[rb + 2 * Hh + j];
      }
    }
  }
  __syncthreads();

  for (int step = 0; step < T; ++step) {
    // ---- MFMA phase: gh = h @ whh^T for this block's 16 rows ----
    f32x4 C[3][2];
    #pragma unroll
    for (int g = 0; g < 3; ++g)
      #pragma unroll
      for (int jt = 0; jt < 2; ++jt) C[g][jt] = (f32x4){0.f, 0.f, 0.f, 0.f};
    #pragma unroll
    for (int k0 = 0; k0 < 8; ++k0) {
      bf16x8 ah = *(const bf16x8*)&hA[0][k0][quad][l16][0];
      bf16x8 al = *(const bf16x8*)&hA[1][k0][quad][l16][0];
      #pragma unroll
      for (int g = 0; g < 3; ++g)
        #pragma unroll
        for (int jt = 0; jt < 2; ++jt) {
          bf16x8 b8 = *(const bf16x8*)(bptr[g][jt] + k0 * 32);
          C[g][jt] = __builtin_amdgcn_mfma_f32_16x16x32_bf16(al, b8, C[g][jt], 0, 0, 0);
          C[g][jt] = __builtin_amdgcn_mfma_f32_16x16x32_bf16(ah, b8, C[g][jt], 0, 0, 0);
        }
    }
    // ---- prefetch next step's gi (hidden under MFMA latency) ----
    float gn[3][2][4];
    if (step + 1 < T) {
      int t1 = dir ? (T - 2 - step) : (step + 1);
      #pragma unroll
      for (int jt = 0; jt < 2; ++jt) {
        int j = wave * 32 + jt * 16 + l16;
        #pragma unroll
        for (int r = 0; r < 4; ++r) {
          size_t rb = ((size_t)(sblk + quad * 4 + r) * T + t1) * (size_t)G3;
          gn[0][jt][r] = giD[rb + j];
          gn[1][jt][r] = giD[rb + Hh + j];
          gn[2][jt][r] = giD[rb + 2 * Hh + j];
        }
      }
    }
    __syncthreads();   // all A-frag reads complete before h rewrite
    // ---- in-register GRU update: lane owns (m=quad*4+r, j=wave*32+jt*16+l16) ----
    int t = dir ? (T - 1 - step) : step;
    #pragma unroll
    for (int jt = 0; jt < 2; ++jt) {
      int q2 = jt * 2 + (l16 >> 3);   // j>>3 & 3 with k0'=wave
      int ii = l16 & 7;
      #pragma unroll
      for (int r = 0; r < 4; ++r) {
        int m = quad * 4 + r;
        float rr = 1.f / (1.f + expf(-(gv[0][jt][r] + C[0][jt][r] + bh[0][jt])));
        float zz = 1.f / (1.f + expf(-(gv[1][jt][r] + C[1][jt][r] + bh[1][jt])));
        float nn = tanhf(gv[2][jt][r] + rr * (C[2][jt][r] + bh[2][jt]));
        float hnew = (1.f - zz) * nn + zz * hprev[jt][r];
        hprev[jt][r] = hnew;
        bf16_t hi = (bf16_t)hnew;
        hA[0][wave][q2][m][ii] = hi;
        hA[1][wave][q2][m][ii] = (bf16_t)(hnew - (float)hi);
        if (t < Lm[r]) pmax[jt][r] = fmaxf(pmax[jt][r], hnew);
      }
    }
    if (step + 1 < T) {
      #pragma unroll
      for (int g = 0; g < 3; ++g)
        #pragma unroll
        for (int jt = 0; jt < 2; ++jt)
          #pragma unroll
          for (int r = 0; r < 4; ++r) gv[g][jt][r] = gn[g][jt][r];
    }
    __syncthreads();   // h writes visible before next step's A reads
  }
  // ---- pool write ----
  #pragma unroll
  for (int jt = 0; jt < 2; ++jt) {
    int j = wave * 32 + jt * 16 + l16;
    #pragma unroll
    for (int r = 0; r < 4; ++r) {
      int sa = sbase + sblk + quad * 4 + r;
      float v = pmax[jt][r];
      if (v < -9e29f) v = 0.f;
      pool[(size_t)sa * H2 + dir * Hh + j] = v;
    }
  }
}

// ---------- GRU, 1 row/block (sent/doc levels) ----------
__global__ __launch_bounds__(768) void k_gru1(
    const float* __restrict__ gi, const bf16_t* __restrict__ whh,
    const float* __restrict__ bhh, float* __restrict__ pool, int T, int dir) {
  __shared__ float hsh[Hh];
  __shared__ float ghs[G3];
  int b = blockIdx.x;
  int g = threadIdx.x;
  if (g < Hh) hsh[g] = 0.f;
  float bh = bhh[g];
  const bf16_t* wrow = whh + (size_t)g * Hh;
  float pmax = -1e30f;
  __syncthreads();
  for (int step = 0; step < T; ++step) {
    int t = dir ? (T - 1 - step) : step;
    float acc = bh;
    #pragma unroll 4
    for (int k0 = 0; k0 < Hh; k0 += 8) {
      bf16x8 w8 = *(const bf16x8*)(wrow + k0);
      #pragma unroll
      for (int kk = 0; kk < 8; ++kk) acc += hsh[k0 + kk] * (float)w8[kk];
    }
    ghs[g] = acc;
    __syncthreads();
    if (g < Hh) {
      size_t rb = ((size_t)b * T + t) * (size_t)G3;
      float rr = 1.f / (1.f + expf(-(gi[rb + g] + ghs[g])));
      float zz = 1.f / (1.f + expf(-(gi[rb + Hh + g] + ghs[Hh + g])));
      float nn = tanhf(gi[rb + 2 * Hh + g] + rr * ghs[2 * Hh + g]);
      float hnew = (1.f - zz) * nn + zz * hsh[g];
      hsh[g] = hnew;
      pmax = fmaxf(pmax, hnew);
    }
    __syncthreads();
  }
  if (g < Hh) pool[(size_t)b * H2 + dir * Hh + g] = (pmax < -9e29f) ? 0.f : pmax;
}

// ---------- epilogue ----------
__global__ void k_zero(float* __restrict__ p, int n) {
  int i = blockIdx.x * blockDim.x + threadIdx.x;
  if (i < n) p[i] = 0.f;
}

__global__ __launch_bounds__(512) void k_colsum(const float* __restrict__ ev, float* __restrict__ out) {
  int t = threadIdx.x;
  int r0 = blockIdx.x * 256;
  float s = 0.f;
  for (int r = 0; r < 256; ++r) s += ev[(size_t)(r0 + r) * H2 + t];
  atomicAdd(&out[t], s);
}

__global__ void k_ves(const float* __restrict__ W, const float* __restrict__ sum, float* __restrict__ ves) {
  int d = blockIdx.x * 64 + threadIdx.x;
  const float* row = W + (size_t)d * H2;
  float s = 0.f;
  for (int f = 0; f < H2; ++f) s += row[f] * sum[f];
  ves[d] = s * (1.f / 3072.f);
}

__global__ void k_sal(const float* __restrict__ W, const float* __restrict__ blog,
                      const float* __restrict__ dv, float* __restrict__ out) {
  int doc = blockIdx.y;
  int i = blockIdx.x * 64 + threadIdx.x;
  const float* row = W + (size_t)i * (2 * H2);
  const float* dvr = dv + (size_t)doc * H2;
  float s = 0.f;
  for (int f = 0; f < H2; ++f) s += row[f] * blog[f];
  for (int f = 0; f < H2; ++f) s += row[H2 + f] * dvr[f];
  out[(size_t)doc * H2 + i] = s;
}

__global__ __launch_bounds__(256) void k_eventprobs(
    const float* __restrict__ evv, const float* __restrict__ ves,
    const float* __restrict__ w_ec, const float* __restrict__ tfs,
    const float* __restrict__ st, const float* __restrict__ c_tf,
    const float* __restrict__ c_sent, const float* __restrict__ c_bias,
    const int* __restrict__ flag, float* __restrict__ probs, void* __restrict__ outp) {
  int lane = threadIdx.x & 63;
  int e = blockIdx.x * 4 + (threadIdx.x >> 6);
  const float* row = evv + (size_t)e * H2;
  float s = 0.f;
  for (int f = lane; f < H2; f += 64) s += row[f] * (w_ec[f] + ves[f]);
  #pragma unroll
  for (int o = 32; o > 0; o >>= 1) s += __shfl_down(s, o, 64);
  if (lane == 0) {
    float p = s + c_tf[0] * tfs[e] + c_bias[0] + c_sent[0] * st[e / 3];
    probs[e] = p;
    if (flag[0]) ((bf16_t*)outp)[S_TOT + e] = (bf16_t)p;
    else         ((float*)outp)[S_TOT + e] = p;
  }
}

__global__ __launch_bounds__(256) void k_sentout(
    const float* __restrict__ sv, const float* __restrict__ u,
    const float* __restrict__ evv, const float* __restrict__ probs,
    const float* __restrict__ wsal, const float* __restrict__ w_sc,
    const float* __restrict__ dpe, const float* __restrict__ spe,
    const float* __restrict__ w_sdp, const float* __restrict__ w_sp,
    const float* __restrict__ b_rel, const float* __restrict__ para,
    const float* __restrict__ sbias, const int* __restrict__ flag,
    void* __restrict__ outp) {
  int lane = threadIdx.x & 63;
  int s = blockIdx.x * 4 + (threadIdx.x >> 6);
  int doc = s >> 5, jj = s & 31;
  const float* svr = sv + (size_t)s * H2;
  const float* ur  = u + (size_t)s * H2;
  const float* wd  = wsal + (size_t)doc * H2;
  float acc = 0.f, e0 = 0.f, e1 = 0.f, e2 = 0.f;
  for (int f = lane; f < H2; f += 64) {
    float svf = svr[f], uf = ur[f];
    acc += svf * (w_sc[f] + wd[f]);
    e0 += uf * evv[(size_t)(s * 3 + 0) * H2 + f];
    e1 += uf * evv[(size_t)(s * 3 + 1) * H2 + f];
    e2 += uf * evv[(size_t)(s * 3 + 2) * H2 + f];
  }
  if (lane < 50) {
    int dpos = (doc * 40) / 32;
    int spos = (jj * 30) / 32;
    acc += dpe[dpos * 50 + lane] * w_sdp[lane] + spe[spos * 50 + lane] * w_sp[lane];
  }
  #pragma unroll
  for (int o = 32; o > 0; o >>= 1) {
    acc += __shfl_down(acc, o, 64);
    e0  += __shfl_down(e0, o, 64);
    e1  += __shfl_down(e1, o, 64);
    e2  += __shfl_down(e2, o, 64);
  }
  if (lane == 0) {
    float br = b_rel[0];
    float rel = (e0 + br) * probs[s * 3 + 0] + (e1 + br) * probs[s * 3 + 1]
              + (e2 + br) * probs[s * 3 + 2];
    float v = acc + para[0] * rel + sbias[0];
    if (flag[0]) ((bf16_t*)outp)[s] = (bf16_t)v;
    else         ((float*)outp)[s] = v;
  }
}

// ---------------- launcher ----------------
extern "C" void kernel_launch(void* const* d_in, const int* in_sizes, int n_in,
                              void* d_out, int out_size, void* d_ws, size_t ws_size,
                              hipStream_t stream) {
  (void)in_sizes; (void)n_in; (void)out_size;
  const int* x      = (const int*)d_in[0];
  const int* events = (const int*)d_in[1];
  const void* embed = d_in[8];

  char* ws = (char*)d_ws;
  size_t off = 0;
  auto alloc = [&](size_t bytes) -> void* {
    void* p = ws + off;
    off += (bytes + 255) & ~(size_t)255;
    return p;
  };

  static const int cidx[NCANON] = {9,10,11,12, 13,14,15,16, 17,18,19,20, 21,22,23,24,
                                   25,26,27,28,29,30,31, 32,33,34,35, 36,37,38,40, 5,7};
  static const int csz[NCANON]  = {2*G3*D_EMB, 2*G3*Hh, 2*G3, 2*G3,
                                   2*G3*H2,    2*G3*Hh, 2*G3, 2*G3,
                                   2*G3*H2,    2*G3*Hh, 2*G3, 2*G3,
                                   2*G3*D_EMB, 2*G3*Hh, 2*G3, 2*G3,
                                   40*50, 30*50, H2, H2*H2, 1, 1, 1,
                                   H2, H2*2*H2, 50, 50,
                                   H2*H2, 1, 1, 1, E_TOT, S_TOT};
  Canon cd;
  int tot = 0;
  for (int i = 0; i < NCANON; ++i) { cd.src[i] = d_in[cidx[i]]; cd.off[i] = tot; tot += csz[i]; }
  cd.off[NCANON] = tot;

  int*   flag  = (int*)alloc(256);
  float* canon = (float*)alloc((size_t)tot * 4);
  float* cptr[NCANON];
  for (int i = 0; i < NCANON; ++i) cptr[i] = canon + cd.off[i];
  float *cw_wih = cptr[0], *cw_whh = cptr[1], *cw_bih = cptr[2], *cw_bhh = cptr[3];
  float *cs_wih = cptr[4], *cs_whh = cptr[5], *cs_bih = cptr[6], *cs_bhh = cptr[7];
  float *cd_wih = cptr[8], *cd_whh = cptr[9], *cd_bih = cptr[10], *cd_bhh = cptr[11];
  float *ce_wih = cptr[12], *ce_whh = cptr[13], *ce_bih = cptr[14], *ce_bhh = cptr[15];
  float *c_dpe = cptr[16], *c_spe = cptr[17], *c_wec = cptr[18], *c_Wes = cptr[19];
  float *c_tf = cptr[20], *c_sent = cptr[21], *c_ebias = cptr[22];
  float *c_wsc = cptr[23], *c_Wss = cptr[24], *c_wsdp = cptr[25], *c_wsp = cptr[26];
  float *c_Wer = cptr[27], *c_brel = cptr[28], *c_para = cptr[29], *c_sbias = cptr[30];
  float *c_tfs = cptr[31], *c_starg = cptr[32];

  bf16_t* whhW = (bf16_t*)alloc((size_t)2 * G3 * Hh * 2);
  bf16_t* whhE = (bf16_t*)alloc((size_t)2 * G3 * Hh * 2);
  bf16_t* whhS = (bf16_t*)alloc((size_t)2 * G3 * Hh * 2);
  bf16_t* whhD = (bf16_t*)alloc((size_t)2 * G3 * Hh * 2);
  float*  sv   = (float*)alloc((size_t)S_TOT * H2 * 4);
  float*  evv  = (float*)alloc((size_t)E_TOT * H2 * 4);
  float*  dv   = (float*)alloc((size_t)32 * H2 * 4);
  float*  blog = (float*)alloc((size_t)H2 * 4);
  float*  wSt  = (float*)alloc((size_t)2 * H2 * G3 * 4);
  float*  wDt  = (float*)alloc((size_t)2 * H2 * G3 * 4);
  float*  u    = (float*)alloc((size_t)S_TOT * H2 * 4);
  float*  esum = (float*)alloc((size_t)H2 * 4);
  float*  ves  = (float*)alloc((size_t)H2 * 4);
  float*  wsal = (float*)alloc((size_t)32 * H2 * 4);
  float*  probs= (float*)alloc((size_t)E_TOT * 4);
  int*    lens = (int*)alloc((size_t)S_TOT * 4);

  // gi chunk region: remainder of ws; holds BOTH dirs -> 2 * rpc * 768 f32 per chunk
  size_t fixed = off;
  size_t avail = (ws_size > fixed) ? (ws_size - fixed) : 0;
  long long rpc = (long long)(avail / ((size_t)G3 * 4 * 2));
  rpc &= ~511LL;                      // multiple of 512 rows
  if (rpc < 512) rpc = 512;
  if (rpc > 32768) rpc = 32768;
  float* gib = (float*)(ws + fixed);

  // ---- prep ----
  k_detect<<<1, 64, 0, stream>>>((const unsigned short*)embed, flag);
  k_canon<<<(tot + 255) / 256, 256, 0, stream>>>(cd, flag, canon);
  int nwhh = 2 * G3 * Hh;
  k_f2b<<<(nwhh + 255) / 256, 256, 0, stream>>>(cw_whh, whhW, nwhh);
  k_f2b<<<(nwhh + 255) / 256, 256, 0, stream>>>(ce_whh, whhE, nwhh);
  k_f2b<<<(nwhh + 255) / 256, 256, 0, stream>>>(cs_whh, whhS, nwhh);
  k_f2b<<<(nwhh + 255) / 256, 256, 0, stream>>>(cd_whh, whhD, nwhh);
  k_lens<<<4, 256, 0, stream>>>(x, lens);
  k_transpose<<<dim3(24, 16, 2), 256, 0, stream>>>(cs_wih, wSt);
  k_transpose<<<dim3(24, 16, 2), 256, 0, stream>>>(cd_wih, wDt);

  // ---- word BiGRU -> sent_vec ----
  for (long long r0 = 0; r0 < 32768; r0 += rpc) {
    long long rows = 32768 - r0; if (rows > rpc) rows = rpc;
    for (int d = 0; d < 2; ++d)
      k_giA<<<dim3((int)(rows / 64), 12), 256, 0, stream>>>(
          x, embed, cw_wih + (size_t)d * G3 * D_EMB, cw_bih + d * G3, flag,
          gib + (size_t)d * rows * G3, (int)r0);
    k_gruM<<<dim3((int)(rows / 512), 2), 512, 0, stream>>>(
        gib, (size_t)rows * G3, whhW, cw_bhh, lens, sv, 32, (int)(r0 / 32));
  }
  // ---- event BiGRU -> event_vec ----
  for (long long r0 = 0; r0 < 12288; r0 += rpc) {
    long long rows = 12288 - r0; if (rows > rpc) rows = rpc;
    for (int d = 0; d < 2; ++d)
      k_giA<<<dim3((int)(rows / 64), 12), 256, 0, stream>>>(
          events, embed, ce_wih + (size_t)d * G3 * D_EMB, ce_bih + d * G3, flag,
          gib + (size_t)d * rows * G3, (int)r0);
    k_gruM<<<dim3((int)(rows / 64), 2), 512, 0, stream>>>(
        gib, (size_t)rows * G3, whhE, ce_bhh, nullptr, evv, 4, (int)(r0 / 4));
  }
  // ---- sent BiGRU (per doc) -> doc_vec ----
  for (int dir = 0; dir < 2; ++dir) {
    k_sgemm<<<dim3(16, 12), 256, 0, stream>>>(sv, wSt + (size_t)dir * H2 * G3,
                                              cs_bih + dir * G3, gib, 1024, G3, H2);
    k_gru1<<<32, 768, 0, stream>>>(gib, whhS + (size_t)dir * G3 * Hh,
                                   cs_bhh + dir * G3, dv, 32, dir);
  }
  // ---- doc BiGRU -> blog_vec ----
  for (int dir = 0; dir < 2; ++dir) {
    k_sgemm<<<dim3(1, 12), 256, 0, stream>>>(dv, wDt + (size_t)dir * H2 * G3,
                                             cd_bih + dir * G3, gib, 32, G3, H2);
    k_gru1<<<1, 768, 0, stream>>>(gib, whhD + (size_t)dir * G3 * Hh,
                                  cd_bhh + dir * G3, blog, 32, dir);
  }
  // ---- u = sent_vec @ W_event_rel ----
  k_sgemm<<<dim3(16, 8), 256, 0, stream>>>(sv, c_Wer, nullptr, u, 1024, H2, H2);
  // ---- event_sum, ves, wsal ----
  k_zero<<<1, 512, 0, stream>>>(esum, 512);
  k_colsum<<<12, 512, 0, stream>>>(evv, esum);
  k_ves<<<8, 64, 0, stream>>>(c_Wes, esum, ves);
  k_sal<<<dim3(8, 32), 64, 0, stream>>>(c_Wss, blog, dv, wsal);
  // ---- outputs ----
  k_eventprobs<<<768, 256, 0, stream>>>(evv, ves, c_wec, c_tfs, c_starg,
                                        c_tf, c_sent, c_ebias, flag, probs, d_out);
  k_sentout<<<256, 256, 0, stream>>>(sv, u, evv, probs, wsal, c_wsc, c_dpe, c_spe,
                                     c_wsdp, c_wsp, c_brel, c_para, c_sbias, flag, d_out);
}

// Round 5
// 3356.866 us; speedup vs baseline: 1.1911x; 1.0015x over previous
//
#include <hip/hip_runtime.h>
#include <hip/hip_bf16.h>
#include <math.h>

typedef __bf16 bf16_t;
typedef __bf16 bf16x8 __attribute__((ext_vector_type(8)));
typedef __bf16 bf16x4 __attribute__((ext_vector_type(4)));
typedef float  f32x4  __attribute__((ext_vector_type(4)));

#define S_TOT 1024
#define T_W   32
#define D_EMB 300
#define KP    320
#define G3    768
#define Hh    256
#define H2    512
#define E_TOT 3072
#define NCANON 33

// ---------- dtype detector: flag=1 if float tensors are bf16, 0 if f32 ----------
__global__ void k_detect(const unsigned short* __restrict__ w, int* __restrict__ flag) {
  int lane = threadIdx.x;
  int sane = 0;
  for (int i = lane; i < 256; i += 64) {
    unsigned short v = w[2 * i];
    int ex = (v >> 7) & 0xFF;
    sane += (ex >= 96 && ex <= 134) ? 1 : 0;
  }
  #pragma unroll
  for (int o = 32; o > 0; o >>= 1) sane += __shfl_down(sane, o, 64);
  if (lane == 0) flag[0] = (sane >= 128) ? 1 : 0;
}

// ---------- canonicalize all float tensors to f32 ----------
struct Canon {
  const void* src[NCANON];
  int off[NCANON + 1];
};
__global__ void k_canon(Canon c, const int* __restrict__ flag, float* __restrict__ dst) {
  int i = blockIdx.x * 256 + threadIdx.x;
  if (i >= c.off[NCANON]) return;
  int seg = 0;
  while (c.off[seg + 1] <= i) ++seg;
  int j = i - c.off[seg];
  dst[i] = flag[0] ? (float)((const bf16_t*)c.src[seg])[j]
                   : ((const float*)c.src[seg])[j];
}

__global__ void k_f2b(const float* __restrict__ s, bf16_t* __restrict__ d, int n) {
  int i = blockIdx.x * 256 + threadIdx.x;
  if (i < n) d[i] = (bf16_t)s[i];
}

__global__ void k_lens(const int* __restrict__ x, int* __restrict__ lens) {
  int s = blockIdx.x * blockDim.x + threadIdx.x;
  if (s >= S_TOT) return;
  int c = 0;
  for (int t = 0; t < T_W; ++t) c += (x[s * T_W + t] != 0) ? 1 : 0;
  lens[s] = c;
}

// wih [2][768][512] f32 -> [2][512][768] f32
__global__ void k_transpose(const float* __restrict__ w, float* __restrict__ out) {
  __shared__ float tile[32][33];
  int d  = blockIdx.z;
  int n0 = blockIdx.x * 32, k0 = blockIdx.y * 32;
  int tx = threadIdx.x & 31, ty = threadIdx.x >> 5;
  for (int i = ty; i < 32; i += 8)
    tile[i][tx] = w[((size_t)d * G3 + n0 + i) * H2 + k0 + tx];
  __syncthreads();
  for (int i = ty; i < 32; i += 8)
    out[((size_t)d * H2 + k0 + i) * G3 + n0 + tx] = tile[tx][i];
}

// ---------- fused gather + input projection: gi = embed[toks] @ wih^T + bih ----------
__global__ __launch_bounds__(256) void k_giA(
    const int* __restrict__ toks, const void* __restrict__ embed,
    const float* __restrict__ wih, const float* __restrict__ bih,
    const int* __restrict__ flag, float* __restrict__ gi, int mbase) {
  __shared__ __align__(16) bf16_t Ah[64][32];
  __shared__ __align__(16) bf16_t Al[64][32];
  __shared__ __align__(16) bf16_t Bs[64][32];
  int tid = threadIdx.x;
  int wave = tid >> 6, lane = tid & 63;
  int l16 = lane & 15, quad = lane >> 4;
  int m0 = blockIdx.x * 64;
  int n0 = blockIdx.y * 64;
  int r  = tid >> 2;
  int kk = (tid & 3) * 8;
  int tok = toks[mbase + m0 + r];
  int isb = flag[0];
  const float*  ef = (const float*)embed + (size_t)tok * D_EMB;
  const bf16_t* eb = (const bf16_t*)embed + (size_t)tok * D_EMB;
  const float* wrow = wih + (size_t)(n0 + r) * D_EMB;
  f32x4 acc[4] = {{0.f,0.f,0.f,0.f},{0.f,0.f,0.f,0.f},{0.f,0.f,0.f,0.f},{0.f,0.f,0.f,0.f}};
  for (int k0 = 0; k0 < KP; k0 += 32) {
    int ka = k0 + kk;
    float av[8], bv[8];
    #pragma unroll
    for (int i = 0; i < 8; ++i) { av[i] = 0.f; bv[i] = 0.f; }
    if (ka < D_EMB) {
      if (isb) { bf16x4 t4 = *(const bf16x4*)(eb + ka);
                 av[0]=(float)t4[0]; av[1]=(float)t4[1]; av[2]=(float)t4[2]; av[3]=(float)t4[3]; }
      else     { float4 t4 = *(const float4*)(ef + ka);
                 av[0]=t4.x; av[1]=t4.y; av[2]=t4.z; av[3]=t4.w; }
      float4 w4 = *(const float4*)(wrow + ka);
      bv[0]=w4.x; bv[1]=w4.y; bv[2]=w4.z; bv[3]=w4.w;
    }
    if (ka + 4 < D_EMB) {
      if (isb) { bf16x4 t4 = *(const bf16x4*)(eb + ka + 4);
                 av[4]=(float)t4[0]; av[5]=(float)t4[1]; av[6]=(float)t4[2]; av[7]=(float)t4[3]; }
      else     { float4 t4 = *(const float4*)(ef + ka + 4);
                 av[4]=t4.x; av[5]=t4.y; av[6]=t4.z; av[7]=t4.w; }
      float4 w4 = *(const float4*)(wrow + ka + 4);
      bv[4]=w4.x; bv[5]=w4.y; bv[6]=w4.z; bv[7]=w4.w;
    }
    #pragma unroll
    for (int i = 0; i < 8; ++i) {
      bf16_t hi = (bf16_t)av[i];
      Ah[r][kk + i] = hi;
      Al[r][kk + i] = (bf16_t)(av[i] - (float)hi);
      Bs[r][kk + i] = (bf16_t)bv[i];
    }
    __syncthreads();
    bf16x8 ah = *(const bf16x8*)&Ah[wave * 16 + l16][quad * 8];
    bf16x8 al = *(const bf16x8*)&Al[wave * 16 + l16][quad * 8];
    #pragma unroll
    for (int j = 0; j < 4; ++j) {
      bf16x8 b8 = *(const bf16x8*)&Bs[j * 16 + l16][quad * 8];
      acc[j] = __builtin_amdgcn_mfma_f32_16x16x32_bf16(al, b8, acc[j], 0, 0, 0);
      acc[j] = __builtin_amdgcn_mfma_f32_16x16x32_bf16(ah, b8, acc[j], 0, 0, 0);
    }
    __syncthreads();
  }
  int row0 = m0 + wave * 16 + quad * 4;   // C/D: col=lane&15, row=quad*4+reg
  #pragma unroll
  for (int j = 0; j < 4; ++j) {
    int col = n0 + j * 16 + l16;
    float bvv = bih[col];
    #pragma unroll
    for (int rr = 0; rr < 4; ++rr)
      gi[(size_t)(row0 + rr) * G3 + col] = acc[j][rr] + bvv;
  }
}

// ---------- f32 SGEMM: C[M][N] = A[M][K] @ B[K][N] (+bias) ----------
__global__ __launch_bounds__(256) void k_sgemm(
    const float* __restrict__ A, const float* __restrict__ B,
    const float* __restrict__ bias, float* __restrict__ C,
    int M, int N, int K) {
  __shared__ float As[32][65];
  __shared__ float Bs[32][65];
  int bm = blockIdx.x * 64, bn = blockIdx.y * 64;
  int tid = threadIdx.x;
  int tx = tid & 15, ty = tid >> 4;
  float acc[4][4] = {};
  for (int k0 = 0; k0 < K; k0 += 32) {
    for (int i = tid; i < 64 * 32; i += 256) {
      int m = i >> 5, k = i & 31;
      As[k][m] = (bm + m < M) ? A[(size_t)(bm + m) * K + k0 + k] : 0.f;
    }
    for (int i = tid; i < 32 * 64; i += 256) {
      int k = i >> 6, n = i & 63;
      Bs[k][n] = B[(size_t)(k0 + k) * N + bn + n];
    }
    __syncthreads();
    #pragma unroll 8
    for (int k = 0; k < 32; ++k) {
      float a[4], b[4];
      #pragma unroll
      for (int i = 0; i < 4; ++i) a[i] = As[k][ty + i * 16];
      #pragma unroll
      for (int j = 0; j < 4; ++j) b[j] = Bs[k][tx + j * 16];
      #pragma unroll
      for (int i = 0; i < 4; ++i)
        #pragma unroll
        for (int j = 0; j < 4; ++j) acc[i][j] += a[i] * b[j];
    }
    __syncthreads();
  }
  for (int i = 0; i < 4; ++i) {
    int m = bm + ty + i * 16;
    if (m >= M) continue;
    for (int j = 0; j < 4; ++j) {
      int n = bn + tx + j * 16;
      C[(size_t)m * N + n] = acc[i][j] + (bias ? bias[n] : 0.f);
    }
  }
}

// ---------- batched MFMA GRU: 16 rows/block, dirs fused via blockIdx.y ----------
// __launch_bounds__(512, 2): 2 waves/SIMD -> 256 VGPR cap. Round-4's (512) default
// capped at 128 VGPRs and SPILLED the gi-prefetch + accumulators to scratch
// (WRITE_SIZE 235MB/dispatch, 600us). The live set is ~190 regs by design.
__global__ __launch_bounds__(512, 2) void k_gruM(
    const float* __restrict__ gi, size_t gi_dstride,
    const bf16_t* __restrict__ whh, const float* __restrict__ bhh,
    const int* __restrict__ lens, float* __restrict__ pool,
    int T, int sbase) {
  int dir = blockIdx.y;
  int tid = threadIdx.x;
  int wave = tid >> 6, lane = tid & 63;
  int l16 = lane & 15, quad = lane >> 4;
  int sblk = blockIdx.x * 16;
  const float*  giD  = gi + (size_t)dir * gi_dstride;
  const bf16_t* whhD = whh + (size_t)dir * (size_t)G3 * Hh;
  const float*  bhhD = bhh + (size_t)dir * G3;

  __shared__ __align__(16) bf16_t hA[2][8][4][16][8];
  {
    bf16_t* hz = &hA[0][0][0][0][0];
    for (int i = tid; i < 2 * 8 * 4 * 16 * 8; i += 512) hz[i] = (bf16_t)0.f;
  }

  float bh[3][2];
  const bf16_t* bptr[3][2];
  #pragma unroll
  for (int g = 0; g < 3; ++g)
    #pragma unroll
    for (int jt = 0; jt < 2; ++jt) {
      int n = g * Hh + wave * 32 + jt * 16 + l16;
      bh[g][jt] = bhhD[n];
      bptr[g][jt] = whhD + (size_t)n * Hh + quad * 8;
    }
  int Lm[4];
  #pragma unroll
  for (int r = 0; r < 4; ++r)
    Lm[r] = lens ? lens[sbase + sblk + quad * 4 + r] : T;

  float hprev[2][4], pmax[2][4];
  #pragma unroll
  for (int jt = 0; jt < 2; ++jt)
    #pragma unroll
    for (int r = 0; r < 4; ++r) { hprev[jt][r] = 0.f; pmax[jt][r] = -1e30f; }

  float gv[3][2][4];
  {
    int t0 = dir ? (T - 1) : 0;
    #pragma unroll
    for (int jt = 0; jt < 2; ++jt) {
      int j = wave * 32 + jt * 16 + l16;
      #pragma unroll
      for (int r = 0; r < 4; ++r) {
        size_t rb = ((size_t)(sblk + quad * 4 + r) * T + t0) * (size_t)G3;
        gv[0][jt][r] = giD[rb + j];
        gv[1][jt][r] = giD[rb + Hh + j];
        gv[2][jt][r] = giD[rb + 2 * Hh + j];
      }
    }
  }
  __syncthreads();

  for (int step = 0; step < T; ++step) {
    f32x4 C[3][2];
    #pragma unroll
    for (int g = 0; g < 3; ++g)
      #pragma unroll
      for (int jt = 0; jt < 2; ++jt) C[g][jt] = (f32x4){0.f, 0.f, 0.f, 0.f};
    #pragma unroll
    for (int k0 = 0; k0 < 8; ++k0) {
      bf16x8 ah = *(const bf16x8*)&hA[0][k0][quad][l16][0];
      bf16x8 al = *(const bf16x8*)&hA[1][k0][quad][l16][0];
      #pragma unroll
      for (int g = 0; g < 3; ++g)
        #pragma unroll
        for (int jt = 0; jt < 2; ++jt) {
          bf16x8 b8 = *(const bf16x8*)(bptr[g][jt] + k0 * 32);
          C[g][jt] = __builtin_amdgcn_mfma_f32_16x16x32_bf16(al, b8, C[g][jt], 0, 0, 0);
          C[g][jt] = __builtin_amdgcn_mfma_f32_16x16x32_bf16(ah, b8, C[g][jt], 0, 0, 0);
        }
    }
    float gn[3][2][4];
    if (step + 1 < T) {
      int t1 = dir ? (T - 2 - step) : (step + 1);
      #pragma unroll
      for (int jt = 0; jt < 2; ++jt) {
        int j = wave * 32 + jt * 16 + l16;
        #pragma unroll
        for (int r = 0; r < 4; ++r) {
          size_t rb = ((size_t)(sblk + quad * 4 + r) * T + t1) * (size_t)G3;
          gn[0][jt][r] = giD[rb + j];
          gn[1][jt][r] = giD[rb + Hh + j];
          gn[2][jt][r] = giD[rb + 2 * Hh + j];
        }
      }
    }
    __syncthreads();
    int t = dir ? (T - 1 - step) : step;
    #pragma unroll
    for (int jt = 0; jt < 2; ++jt) {
      int q2 = jt * 2 + (l16 >> 3);
      int ii = l16 & 7;
      #pragma unroll
      for (int r = 0; r < 4; ++r) {
        int m = quad * 4 + r;
        float rr = 1.f / (1.f + expf(-(gv[0][jt][r] + C[0][jt][r] + bh[0][jt])));
        float zz = 1.f / (1.f + expf(-(gv[1][jt][r] + C[1][jt][r] + bh[1][jt])));
        float nn = tanhf(gv[2][jt][r] + rr * (C[2][jt][r] + bh[2][jt]));
        float hnew = (1.f - zz) * nn + zz * hprev[jt][r];
        hprev[jt][r] = hnew;
        bf16_t hi = (bf16_t)hnew;
        hA[0][wave][q2][m][ii] = hi;
        hA[1][wave][q2][m][ii] = (bf16_t)(hnew - (float)hi);
        if (t < Lm[r]) pmax[jt][r] = fmaxf(pmax[jt][r], hnew);
      }
    }
    if (step + 1 < T) {
      #pragma unroll
      for (int g = 0; g < 3; ++g)
        #pragma unroll
        for (int jt = 0; jt < 2; ++jt)
          #pragma unroll
          for (int r = 0; r < 4; ++r) gv[g][jt][r] = gn[g][jt][r];
    }
    __syncthreads();
  }
  #pragma unroll
  for (int jt = 0; jt < 2; ++jt) {
    int j = wave * 32 + jt * 16 + l16;
    #pragma unroll
    for (int r = 0; r < 4; ++r) {
      int sa = sbase + sblk + quad * 4 + r;
      float v = pmax[jt][r];
      if (v < -9e29f) v = 0.f;
      pool[(size_t)sa * H2 + dir * Hh + j] = v;
    }
  }
}

// ---------- GRU, 1 row/block (sent/doc levels) ----------
__global__ __launch_bounds__(768) void k_gru1(
    const float* __restrict__ gi, const bf16_t* __restrict__ whh,
    const float* __restrict__ bhh, float* __restrict__ pool, int T, int dir) {
  __shared__ float hsh[Hh];
  __shared__ float ghs[G3];
  int b = blockIdx.x;
  int g = threadIdx.x;
  if (g < Hh) hsh[g] = 0.f;
  float bh = bhh[g];
  const bf16_t* wrow = whh + (size_t)g * Hh;
  float pmax = -1e30f;
  __syncthreads();
  for (int step = 0; step < T; ++step) {
    int t = dir ? (T - 1 - step) : step;
    float acc = bh;
    #pragma unroll 4
    for (int k0 = 0; k0 < Hh; k0 += 8) {
      bf16x8 w8 = *(const bf16x8*)(wrow + k0);
      #pragma unroll
      for (int kk = 0; kk < 8; ++kk) acc += hsh[k0 + kk] * (float)w8[kk];
    }
    ghs[g] = acc;
    __syncthreads();
    if (g < Hh) {
      size_t rb = ((size_t)b * T + t) * (size_t)G3;
      float rr = 1.f / (1.f + expf(-(gi[rb + g] + ghs[g])));
      float zz = 1.f / (1.f + expf(-(gi[rb + Hh + g] + ghs[Hh + g])));
      float nn = tanhf(gi[rb + 2 * Hh + g] + rr * ghs[2 * Hh + g]);
      float hnew = (1.f - zz) * nn + zz * hsh[g];
      hsh[g] = hnew;
      pmax = fmaxf(pmax, hnew);
    }
    __syncthreads();
  }
  if (g < Hh) pool[(size_t)b * H2 + dir * Hh + g] = (pmax < -9e29f) ? 0.f : pmax;
}

// ---------- epilogue ----------
// column partial sums of event_vec [3072][512]: 48 blocks x 64 rows -> part[48][512]
__global__ __launch_bounds__(512) void k_colsumP(const float* __restrict__ ev, float* __restrict__ part) {
  int t = threadIdx.x;
  int r0 = blockIdx.x * 64;
  float s = 0.f;
  for (int r = 0; r < 64; ++r) s += ev[(size_t)(r0 + r) * H2 + t];
  part[(size_t)blockIdx.x * H2 + t] = s;
}
__global__ __launch_bounds__(512) void k_esum(const float* __restrict__ part, float* __restrict__ out) {
  int t = threadIdx.x;
  float s = 0.f;
  for (int b = 0; b < 48; ++b) s += part[(size_t)b * H2 + t];
  out[t] = s;
}

__global__ void k_ves(const float* __restrict__ W, const float* __restrict__ sum, float* __restrict__ ves) {
  int d = blockIdx.x * 64 + threadIdx.x;
  const float* row = W + (size_t)d * H2;
  float s = 0.f;
  for (int f = 0; f < H2; ++f) s += row[f] * sum[f];
  ves[d] = s * (1.f / 3072.f);
}

__global__ void k_sal(const float* __restrict__ W, const float* __restrict__ blog,
                      const float* __restrict__ dv, float* __restrict__ out) {
  int doc = blockIdx.y;
  int i = blockIdx.x * 64 + threadIdx.x;
  const float* row = W + (size_t)i * (2 * H2);
  const float* dvr = dv + (size_t)doc * H2;
  float s = 0.f;
  for (int f = 0; f < H2; ++f) s += row[f] * blog[f];
  for (int f = 0; f < H2; ++f) s += row[H2 + f] * dvr[f];
  out[(size_t)doc * H2 + i] = s;
}

__global__ __launch_bounds__(256) void k_eventprobs(
    const float* __restrict__ evv, const float* __restrict__ ves,
    const float* __restrict__ w_ec, const float* __restrict__ tfs,
    const float* __restrict__ st, const float* __restrict__ c_tf,
    const float* __restrict__ c_sent, const float* __restrict__ c_bias,
    const int* __restrict__ flag, float* __restrict__ probs, void* __restrict__ outp) {
  int lane = threadIdx.x & 63;
  int e = blockIdx.x * 4 + (threadIdx.x >> 6);
  const float* row = evv + (size_t)e * H2;
  float s = 0.f;
  for (int f = lane; f < H2; f += 64) s += row[f] * (w_ec[f] + ves[f]);
  #pragma unroll
  for (int o = 32; o > 0; o >>= 1) s += __shfl_down(s, o, 64);
  if (lane == 0) {
    float p = s + c_tf[0] * tfs[e] + c_bias[0] + c_sent[0] * st[e / 3];
    probs[e] = p;
    if (flag[0]) ((bf16_t*)outp)[S_TOT + e] = (bf16_t)p;
    else         ((float*)outp)[S_TOT + e] = p;
  }
}

__global__ __launch_bounds__(256) void k_sentout(
    const float* __restrict__ sv, const float* __restrict__ u,
    const float* __restrict__ evv, const float* __restrict__ probs,
    const float* __restrict__ wsal, const float* __restrict__ w_sc,
    const float* __restrict__ dpe, const float* __restrict__ spe,
    const float* __restrict__ w_sdp, const float* __restrict__ w_sp,
    const float* __restrict__ b_rel, const float* __restrict__ para,
    const float* __restrict__ sbias, const int* __restrict__ flag,
    void* __restrict__ outp) {
  int lane = threadIdx.x & 63;
  int s = blockIdx.x * 4 + (threadIdx.x >> 6);
  int doc = s >> 5, jj = s & 31;
  const float* svr = sv + (size_t)s * H2;
  const float* ur  = u + (size_t)s * H2;
  const float* wd  = wsal + (size_t)doc * H2;
  float acc = 0.f, e0 = 0.f, e1 = 0.f, e2 = 0.f;
  for (int f = lane; f < H2; f += 64) {
    float svf = svr[f], uf = ur[f];
    acc += svf * (w_sc[f] + wd[f]);
    e0 += uf * evv[(size_t)(s * 3 + 0) * H2 + f];
    e1 += uf * evv[(size_t)(s * 3 + 1) * H2 + f];
    e2 += uf * evv[(size_t)(s * 3 + 2) * H2 + f];
  }
  if (lane < 50) {
    int dpos = (doc * 40) / 32;
    int spos = (jj * 30) / 32;
    acc += dpe[dpos * 50 + lane] * w_sdp[lane] + spe[spos * 50 + lane] * w_sp[lane];
  }
  #pragma unroll
  for (int o = 32; o > 0; o >>= 1) {
    acc += __shfl_down(acc, o, 64);
    e0  += __shfl_down(e0, o, 64);
    e1  += __shfl_down(e1, o, 64);
    e2  += __shfl_down(e2, o, 64);
  }
  if (lane == 0) {
    float br = b_rel[0];
    float rel = (e0 + br) * probs[s * 3 + 0] + (e1 + br) * probs[s * 3 + 1]
              + (e2 + br) * probs[s * 3 + 2];
    float v = acc + para[0] * rel + sbias[0];
    if (flag[0]) ((bf16_t*)outp)[s] = (bf16_t)v;
    else         ((float*)outp)[s] = v;
  }
}

// ---------------- launcher ----------------
extern "C" void kernel_launch(void* const* d_in, const int* in_sizes, int n_in,
                              void* d_out, int out_size, void* d_ws, size_t ws_size,
                              hipStream_t stream) {
  (void)in_sizes; (void)n_in; (void)out_size;
  const int* x      = (const int*)d_in[0];
  const int* events = (const int*)d_in[1];
  const void* embed = d_in[8];

  char* ws = (char*)d_ws;
  size_t off = 0;
  auto alloc = [&](size_t bytes) -> void* {
    void* p = ws + off;
    off += (bytes + 255) & ~(size_t)255;
    return p;
  };

  static const int cidx[NCANON] = {9,10,11,12, 13,14,15,16, 17,18,19,20, 21,22,23,24,
                                   25,26,27,28,29,30,31, 32,33,34,35, 36,37,38,40, 5,7};
  static const int csz[NCANON]  = {2*G3*D_EMB, 2*G3*Hh, 2*G3, 2*G3,
                                   2*G3*H2,    2*G3*Hh, 2*G3, 2*G3,
                                   2*G3*H2,    2*G3*Hh, 2*G3, 2*G3,
                                   2*G3*D_EMB, 2*G3*Hh, 2*G3, 2*G3,
                                   40*50, 30*50, H2, H2*H2, 1, 1, 1,
                                   H2, H2*2*H2, 50, 50,
                                   H2*H2, 1, 1, 1, E_TOT, S_TOT};
  Canon cd;
  int tot = 0;
  for (int i = 0; i < NCANON; ++i) { cd.src[i] = d_in[cidx[i]]; cd.off[i] = tot; tot += csz[i]; }
  cd.off[NCANON] = tot;

  int*   flag  = (int*)alloc(256);
  float* canon = (float*)alloc((size_t)tot * 4);
  float* cptr[NCANON];
  for (int i = 0; i < NCANON; ++i) cptr[i] = canon + cd.off[i];
  float *cw_wih = cptr[0], *cw_whh = cptr[1], *cw_bih = cptr[2], *cw_bhh = cptr[3];
  float *cs_wih = cptr[4], *cs_whh = cptr[5], *cs_bih = cptr[6], *cs_bhh = cptr[7];
  float *cd_wih = cptr[8], *cd_whh = cptr[9], *cd_bih = cptr[10], *cd_bhh = cptr[11];
  float *ce_wih = cptr[12], *ce_whh = cptr[13], *ce_bih = cptr[14], *ce_bhh = cptr[15];
  float *c_dpe = cptr[16], *c_spe = cptr[17], *c_wec = cptr[18], *c_Wes = cptr[19];
  float *c_tf = cptr[20], *c_sent = cptr[21], *c_ebias = cptr[22];
  float *c_wsc = cptr[23], *c_Wss = cptr[24], *c_wsdp = cptr[25], *c_wsp = cptr[26];
  float *c_Wer = cptr[27], *c_brel = cptr[28], *c_para = cptr[29], *c_sbias = cptr[30];
  float *c_tfs = cptr[31], *c_starg = cptr[32];

  bf16_t* whhW = (bf16_t*)alloc((size_t)2 * G3 * Hh * 2);
  bf16_t* whhE = (bf16_t*)alloc((size_t)2 * G3 * Hh * 2);
  bf16_t* whhS = (bf16_t*)alloc((size_t)2 * G3 * Hh * 2);
  bf16_t* whhD = (bf16_t*)alloc((size_t)2 * G3 * Hh * 2);
  float*  sv   = (float*)alloc((size_t)S_TOT * H2 * 4);
  float*  evv  = (float*)alloc((size_t)E_TOT * H2 * 4);
  float*  dv   = (float*)alloc((size_t)32 * H2 * 4);
  float*  blog = (float*)alloc((size_t)H2 * 4);
  float*  wSt  = (float*)alloc((size_t)2 * H2 * G3 * 4);
  float*  wDt  = (float*)alloc((size_t)2 * H2 * G3 * 4);
  float*  u    = (float*)alloc((size_t)S_TOT * H2 * 4);
  float*  part = (float*)alloc((size_t)48 * H2 * 4);
  float*  esum = (float*)alloc((size_t)H2 * 4);
  float*  ves  = (float*)alloc((size_t)H2 * 4);
  float*  wsal = (float*)alloc((size_t)32 * H2 * 4);
  float*  probs= (float*)alloc((size_t)E_TOT * 4);
  int*    lens = (int*)alloc((size_t)S_TOT * 4);

  size_t fixed = off;
  size_t avail = (ws_size > fixed) ? (ws_size - fixed) : 0;
  long long rpc = (long long)(avail / ((size_t)G3 * 4 * 2));
  rpc &= ~511LL;
  if (rpc < 512) rpc = 512;
  if (rpc > 32768) rpc = 32768;
  float* gib = (float*)(ws + fixed);

  // ---- prep ----
  k_detect<<<1, 64, 0, stream>>>((const unsigned short*)embed, flag);
  k_canon<<<(tot + 255) / 256, 256, 0, stream>>>(cd, flag, canon);
  int nwhh = 2 * G3 * Hh;
  k_f2b<<<(nwhh + 255) / 256, 256, 0, stream>>>(cw_whh, whhW, nwhh);
  k_f2b<<<(nwhh + 255) / 256, 256, 0, stream>>>(ce_whh, whhE, nwhh);
  k_f2b<<<(nwhh + 255) / 256, 256, 0, stream>>>(cs_whh, whhS, nwhh);
  k_f2b<<<(nwhh + 255) / 256, 256, 0, stream>>>(cd_whh, whhD, nwhh);
  k_lens<<<4, 256, 0, stream>>>(x, lens);
  k_transpose<<<dim3(24, 16, 2), 256, 0, stream>>>(cs_wih, wSt);
  k_transpose<<<dim3(24, 16, 2), 256, 0, stream>>>(cd_wih, wDt);

  // ---- word BiGRU -> sent_vec ----
  for (long long r0 = 0; r0 < 32768; r0 += rpc) {
    long long rows = 32768 - r0; if (rows > rpc) rows = rpc;
    for (int d = 0; d < 2; ++d)
      k_giA<<<dim3((int)(rows / 64), 12), 256, 0, stream>>>(
          x, embed, cw_wih + (size_t)d * G3 * D_EMB, cw_bih + d * G3, flag,
          gib + (size_t)d * rows * G3, (int)r0);
    k_gruM<<<dim3((int)(rows / 512), 2), 512, 0, stream>>>(
        gib, (size_t)rows * G3, whhW, cw_bhh, lens, sv, 32, (int)(r0 / 32));
  }
  // ---- event BiGRU -> event_vec ----
  for (long long r0 = 0; r0 < 12288; r0 += rpc) {
    long long rows = 12288 - r0; if (rows > rpc) rows = rpc;
    for (int d = 0; d < 2; ++d)
      k_giA<<<dim3((int)(rows / 64), 12), 256, 0, stream>>>(
          events, embed, ce_wih + (size_t)d * G3 * D_EMB, ce_bih + d * G3, flag,
          gib + (size_t)d * rows * G3, (int)r0);
    k_gruM<<<dim3((int)(rows / 64), 2), 512, 0, stream>>>(
        gib, (size_t)rows * G3, whhE, ce_bhh, nullptr, evv, 4, (int)(r0 / 4));
  }
  // ---- sent BiGRU (per doc) -> doc_vec ----
  for (int dir = 0; dir < 2; ++dir) {
    k_sgemm<<<dim3(16, 12), 256, 0, stream>>>(sv, wSt + (size_t)dir * H2 * G3,
                                              cs_bih + dir * G3, gib, 1024, G3, H2);
    k_gru1<<<32, 768, 0, stream>>>(gib, whhS + (size_t)dir * G3 * Hh,
                                   cs_bhh + dir * G3, dv, 32, dir);
  }
  // ---- doc BiGRU -> blog_vec ----
  for (int dir = 0; dir < 2; ++dir) {
    k_sgemm<<<dim3(1, 12), 256, 0, stream>>>(dv, wDt + (size_t)dir * H2 * G3,
                                             cd_bih + dir * G3, gib, 32, G3, H2);
    k_gru1<<<1, 768, 0, stream>>>(gib, whhD + (size_t)dir * G3 * Hh,
                                  cd_bhh + dir * G3, blog, 32, dir);
  }
  // ---- u = sent_vec @ W_event_rel ----
  k_sgemm<<<dim3(16, 8), 256, 0, stream>>>(sv, c_Wer, nullptr, u, 1024, H2, H2);
  // ---- event_sum, ves, wsal ----
  k_colsumP<<<48, 512, 0, stream>>>(evv, part);
  k_esum<<<1, 512, 0, stream>>>(part, esum);
  k_ves<<<8, 64, 0, stream>>>(c_Wes, esum, ves);
  k_sal<<<dim3(8, 32), 64, 0, stream>>>(c_Wss, blog, dv, wsal);
  // ---- outputs ----
  k_eventprobs<<<768, 256, 0, stream>>>(evv, ves, c_wec, c_tfs, c_starg,
                                        c_tf, c_sent, c_ebias, flag, probs, d_out);
  k_sentout<<<256, 256, 0, stream>>>(sv, u, evv, probs, wsal, c_wsc, c_dpe, c_spe,
                                     c_wsdp, c_wsp, c_brel, c_para, c_sbias, flag, d_out);
}

// Round 6
// 2879.597 us; speedup vs baseline: 1.3885x; 1.1657x over previous
//
#include <hip/hip_runtime.h>
#include <hip/hip_bf16.h>
#include <math.h>

typedef __bf16 bf16_t;
typedef __bf16 bf16x8 __attribute__((ext_vector_type(8)));
typedef __bf16 bf16x4 __attribute__((ext_vector_type(4)));
typedef float  f32x4  __attribute__((ext_vector_type(4)));

#define S_TOT 1024
#define T_W   32
#define D_EMB 300
#define KP    320
#define G3    768
#define Hh    256
#define H2    512
#define E_TOT 3072
#define NCANON 33

// ---------- dtype detector: flag=1 if float tensors are bf16, 0 if f32 ----------
__global__ void k_detect(const unsigned short* __restrict__ w, int* __restrict__ flag) {
  int lane = threadIdx.x;
  int sane = 0;
  for (int i = lane; i < 256; i += 64) {
    unsigned short v = w[2 * i];
    int ex = (v >> 7) & 0xFF;
    sane += (ex >= 96 && ex <= 134) ? 1 : 0;
  }
  #pragma unroll
  for (int o = 32; o > 0; o >>= 1) sane += __shfl_down(sane, o, 64);
  if (lane == 0) flag[0] = (sane >= 128) ? 1 : 0;
}

// ---------- canonicalize all float tensors to f32 ----------
struct Canon {
  const void* src[NCANON];
  int off[NCANON + 1];
};
__global__ void k_canon(Canon c, const int* __restrict__ flag, float* __restrict__ dst) {
  int i = blockIdx.x * 256 + threadIdx.x;
  if (i >= c.off[NCANON]) return;
  int seg = 0;
  while (c.off[seg + 1] <= i) ++seg;
  int j = i - c.off[seg];
  dst[i] = flag[0] ? (float)((const bf16_t*)c.src[seg])[j]
                   : ((const float*)c.src[seg])[j];
}

__global__ void k_f2b(const float* __restrict__ s, bf16_t* __restrict__ d, int n) {
  int i = blockIdx.x * 256 + threadIdx.x;
  if (i < n) d[i] = (bf16_t)s[i];
}

__global__ void k_lens(const int* __restrict__ x, int* __restrict__ lens) {
  int s = blockIdx.x * blockDim.x + threadIdx.x;
  if (s >= S_TOT) return;
  int c = 0;
  for (int t = 0; t < T_W; ++t) c += (x[s * T_W + t] != 0) ? 1 : 0;
  lens[s] = c;
}

// wih [2][768][512] f32 -> [2][512][768] f32
__global__ void k_transpose(const float* __restrict__ w, float* __restrict__ out) {
  __shared__ float tile[32][33];
  int d  = blockIdx.z;
  int n0 = blockIdx.x * 32, k0 = blockIdx.y * 32;
  int tx = threadIdx.x & 31, ty = threadIdx.x >> 5;
  for (int i = ty; i < 32; i += 8)
    tile[i][tx] = w[((size_t)d * G3 + n0 + i) * H2 + k0 + tx];
  __syncthreads();
  for (int i = ty; i < 32; i += 8)
    out[((size_t)d * H2 + k0 + i) * G3 + n0 + tx] = tile[tx][i];
}

// ---------- fused gather + input projection: gi = embed[toks] @ wih^T + bih ----------
__global__ __launch_bounds__(256) void k_giA(
    const int* __restrict__ toks, const void* __restrict__ embed,
    const float* __restrict__ wih, const float* __restrict__ bih,
    const int* __restrict__ flag, float* __restrict__ gi, int mbase) {
  __shared__ __align__(16) bf16_t Ah[64][32];
  __shared__ __align__(16) bf16_t Al[64][32];
  __shared__ __align__(16) bf16_t Bs[64][32];
  int tid = threadIdx.x;
  int wave = tid >> 6, lane = tid & 63;
  int l16 = lane & 15, quad = lane >> 4;
  int m0 = blockIdx.x * 64;
  int n0 = blockIdx.y * 64;
  int r  = tid >> 2;
  int kk = (tid & 3) * 8;
  int tok = toks[mbase + m0 + r];
  int isb = flag[0];
  const float*  ef = (const float*)embed + (size_t)tok * D_EMB;
  const bf16_t* eb = (const bf16_t*)embed + (size_t)tok * D_EMB;
  const float* wrow = wih + (size_t)(n0 + r) * D_EMB;
  f32x4 acc[4] = {{0.f,0.f,0.f,0.f},{0.f,0.f,0.f,0.f},{0.f,0.f,0.f,0.f},{0.f,0.f,0.f,0.f}};
  for (int k0 = 0; k0 < KP; k0 += 32) {
    int ka = k0 + kk;
    float av[8], bv[8];
    #pragma unroll
    for (int i = 0; i < 8; ++i) { av[i] = 0.f; bv[i] = 0.f; }
    if (ka < D_EMB) {
      if (isb) { bf16x4 t4 = *(const bf16x4*)(eb + ka);
                 av[0]=(float)t4[0]; av[1]=(float)t4[1]; av[2]=(float)t4[2]; av[3]=(float)t4[3]; }
      else     { float4 t4 = *(const float4*)(ef + ka);
                 av[0]=t4.x; av[1]=t4.y; av[2]=t4.z; av[3]=t4.w; }
      float4 w4 = *(const float4*)(wrow + ka);
      bv[0]=w4.x; bv[1]=w4.y; bv[2]=w4.z; bv[3]=w4.w;
    }
    if (ka + 4 < D_EMB) {
      if (isb) { bf16x4 t4 = *(const bf16x4*)(eb + ka + 4);
                 av[4]=(float)t4[0]; av[5]=(float)t4[1]; av[6]=(float)t4[2]; av[7]=(float)t4[3]; }
      else     { float4 t4 = *(const float4*)(ef + ka + 4);
                 av[4]=t4.x; av[5]=t4.y; av[6]=t4.z; av[7]=t4.w; }
      float4 w4 = *(const float4*)(wrow + ka + 4);
      bv[4]=w4.x; bv[5]=w4.y; bv[6]=w4.z; bv[7]=w4.w;
    }
    #pragma unroll
    for (int i = 0; i < 8; ++i) {
      bf16_t hi = (bf16_t)av[i];
      Ah[r][kk + i] = hi;
      Al[r][kk + i] = (bf16_t)(av[i] - (float)hi);
      Bs[r][kk + i] = (bf16_t)bv[i];
    }
    __syncthreads();
    bf16x8 ah = *(const bf16x8*)&Ah[wave * 16 + l16][quad * 8];
    bf16x8 al = *(const bf16x8*)&Al[wave * 16 + l16][quad * 8];
    #pragma unroll
    for (int j = 0; j < 4; ++j) {
      bf16x8 b8 = *(const bf16x8*)&Bs[j * 16 + l16][quad * 8];
      acc[j] = __builtin_amdgcn_mfma_f32_16x16x32_bf16(al, b8, acc[j], 0, 0, 0);
      acc[j] = __builtin_amdgcn_mfma_f32_16x16x32_bf16(ah, b8, acc[j], 0, 0, 0);
    }
    __syncthreads();
  }
  int row0 = m0 + wave * 16 + quad * 4;   // C/D: col=lane&15, row=quad*4+reg
  #pragma unroll
  for (int j = 0; j < 4; ++j) {
    int col = n0 + j * 16 + l16;
    float bvv = bih[col];
    #pragma unroll
    for (int rr = 0; rr < 4; ++rr)
      gi[(size_t)(row0 + rr) * G3 + col] = acc[j][rr] + bvv;
  }
}

// ---------- f32 SGEMM: C[M][N] = A[M][K] @ B[K][N] (+bias) ----------
__global__ __launch_bounds__(256) void k_sgemm(
    const float* __restrict__ A, const float* __restrict__ B,
    const float* __restrict__ bias, float* __restrict__ C,
    int M, int N, int K) {
  __shared__ float As[32][65];
  __shared__ float Bs[32][65];
  int bm = blockIdx.x * 64, bn = blockIdx.y * 64;
  int tid = threadIdx.x;
  int tx = tid & 15, ty = tid >> 4;
  float acc[4][4] = {};
  for (int k0 = 0; k0 < K; k0 += 32) {
    for (int i = tid; i < 64 * 32; i += 256) {
      int m = i >> 5, k = i & 31;
      As[k][m] = (bm + m < M) ? A[(size_t)(bm + m) * K + k0 + k] : 0.f;
    }
    for (int i = tid; i < 32 * 64; i += 256) {
      int k = i >> 6, n = i & 63;
      Bs[k][n] = B[(size_t)(k0 + k) * N + bn + n];
    }
    __syncthreads();
    #pragma unroll 8
    for (int k = 0; k < 32; ++k) {
      float a[4], b[4];
      #pragma unroll
      for (int i = 0; i < 4; ++i) a[i] = As[k][ty + i * 16];
      #pragma unroll
      for (int j = 0; j < 4; ++j) b[j] = Bs[k][tx + j * 16];
      #pragma unroll
      for (int i = 0; i < 4; ++i)
        #pragma unroll
        for (int j = 0; j < 4; ++j) acc[i][j] += a[i] * b[j];
    }
    __syncthreads();
  }
  for (int i = 0; i < 4; ++i) {
    int m = bm + ty + i * 16;
    if (m >= M) continue;
    for (int j = 0; j < 4; ++j) {
      int n = bn + tx + j * 16;
      C[(size_t)m * N + n] = acc[i][j] + (bias ? bias[n] : 0.f);
    }
  }
}

// ---------- batched MFMA GRU: 16 rows/block, dirs fused via blockIdx.y ----------
// Round-5 post-mortem: __launch_bounds__ 2nd arg is min BLOCKS/CU on this compiler
// (512,2 -> 16 waves/CU -> 128-VGPR cap, unchanged spill). Fix: make the kernel FIT
// in 128 regs — no gn double-buffer (gv loads at step head have the whole MFMA phase
// to land), and 32-bit element offsets instead of 64-bit pointers for whh rows.
__global__ __launch_bounds__(512, 2) void k_gruM(
    const float* __restrict__ gi, size_t gi_dstride,
    const bf16_t* __restrict__ whh, const float* __restrict__ bhh,
    const int* __restrict__ lens, float* __restrict__ pool,
    int T, int sbase) {
  int dir = blockIdx.y;
  int tid = threadIdx.x;
  int wave = tid >> 6, lane = tid & 63;
  int l16 = lane & 15, quad = lane >> 4;
  int sblk = blockIdx.x * 16;
  const float*  giD  = gi + (size_t)dir * gi_dstride;
  const bf16_t* whhD = whh + (size_t)dir * (size_t)G3 * Hh;
  const float*  bhhD = bhh + (size_t)dir * G3;

  __shared__ __align__(16) bf16_t hA[2][8][4][16][8];
  {
    bf16_t* hz = &hA[0][0][0][0][0];
    for (int i = tid; i < 2 * 8 * 4 * 16 * 8; i += 512) hz[i] = (bf16_t)0.f;
  }

  float bh[3][2];
  unsigned noff[3][2];             // element offsets into whhD
  #pragma unroll
  for (int g = 0; g < 3; ++g)
    #pragma unroll
    for (int jt = 0; jt < 2; ++jt) {
      int n = g * Hh + wave * 32 + jt * 16 + l16;
      bh[g][jt] = bhhD[n];
      noff[g][jt] = (unsigned)(n * Hh + quad * 8);
    }
  int Lm[4];
  #pragma unroll
  for (int r = 0; r < 4; ++r)
    Lm[r] = lens ? lens[sbase + sblk + quad * 4 + r] : T;

  float hprev[2][4], pmax[2][4];
  #pragma unroll
  for (int jt = 0; jt < 2; ++jt)
    #pragma unroll
    for (int r = 0; r < 4; ++r) { hprev[jt][r] = 0.f; pmax[jt][r] = -1e30f; }

  __syncthreads();

  for (int step = 0; step < T; ++step) {
    int t = dir ? (T - 1 - step) : step;
    // gi loads issued first; they complete during the MFMA phase below
    float gv[3][2][4];
    #pragma unroll
    for (int jt = 0; jt < 2; ++jt) {
      int j = wave * 32 + jt * 16 + l16;
      #pragma unroll
      for (int r = 0; r < 4; ++r) {
        size_t rb = ((size_t)(sblk + quad * 4 + r) * T + t) * (size_t)G3;
        gv[0][jt][r] = giD[rb + j];
        gv[1][jt][r] = giD[rb + Hh + j];
        gv[2][jt][r] = giD[rb + 2 * Hh + j];
      }
    }
    // MFMA phase: gh = h @ whh^T
    f32x4 C[3][2];
    #pragma unroll
    for (int g = 0; g < 3; ++g)
      #pragma unroll
      for (int jt = 0; jt < 2; ++jt) C[g][jt] = (f32x4){0.f, 0.f, 0.f, 0.f};
    #pragma unroll
    for (int k0 = 0; k0 < 8; ++k0) {
      bf16x8 ah = *(const bf16x8*)&hA[0][k0][quad][l16][0];
      bf16x8 al = *(const bf16x8*)&hA[1][k0][quad][l16][0];
      #pragma unroll
      for (int g = 0; g < 3; ++g)
        #pragma unroll
        for (int jt = 0; jt < 2; ++jt) {
          bf16x8 b8 = *(const bf16x8*)(whhD + noff[g][jt] + k0 * 32);
          C[g][jt] = __builtin_amdgcn_mfma_f32_16x16x32_bf16(al, b8, C[g][jt], 0, 0, 0);
          C[g][jt] = __builtin_amdgcn_mfma_f32_16x16x32_bf16(ah, b8, C[g][jt], 0, 0, 0);
        }
    }
    __syncthreads();   // hA reads complete before rewrite
    #pragma unroll
    for (int jt = 0; jt < 2; ++jt) {
      int q2 = jt * 2 + (l16 >> 3);
      int ii = l16 & 7;
      #pragma unroll
      for (int r = 0; r < 4; ++r) {
        int m = quad * 4 + r;
        float rr = 1.f / (1.f + expf(-(gv[0][jt][r] + C[0][jt][r] + bh[0][jt])));
        float zz = 1.f / (1.f + expf(-(gv[1][jt][r] + C[1][jt][r] + bh[1][jt])));
        float nn = tanhf(gv[2][jt][r] + rr * (C[2][jt][r] + bh[2][jt]));
        float hnew = (1.f - zz) * nn + zz * hprev[jt][r];
        hprev[jt][r] = hnew;
        bf16_t hi = (bf16_t)hnew;
        hA[0][wave][q2][m][ii] = hi;
        hA[1][wave][q2][m][ii] = (bf16_t)(hnew - (float)hi);
        if (t < Lm[r]) pmax[jt][r] = fmaxf(pmax[jt][r], hnew);
      }
    }
    __syncthreads();   // h writes visible before next step's A reads
  }
  #pragma unroll
  for (int jt = 0; jt < 2; ++jt) {
    int j = wave * 32 + jt * 16 + l16;
    #pragma unroll
    for (int r = 0; r < 4; ++r) {
      int sa = sbase + sblk + quad * 4 + r;
      float v = pmax[jt][r];
      if (v < -9e29f) v = 0.f;
      pool[(size_t)sa * H2 + dir * Hh + j] = v;
    }
  }
}

// ---------- GRU, 1 row/block (sent/doc levels) ----------
__global__ __launch_bounds__(768) void k_gru1(
    const float* __restrict__ gi, const bf16_t* __restrict__ whh,
    const float* __restrict__ bhh, float* __restrict__ pool, int T, int dir) {
  __shared__ float hsh[Hh];
  __shared__ float ghs[G3];
  int b = blockIdx.x;
  int g = threadIdx.x;
  if (g < Hh) hsh[g] = 0.f;
  float bh = bhh[g];
  const bf16_t* wrow = whh + (size_t)g * Hh;
  float pmax = -1e30f;
  __syncthreads();
  for (int step = 0; step < T; ++step) {
    int t = dir ? (T - 1 - step) : step;
    float acc = bh;
    #pragma unroll 4
    for (int k0 = 0; k0 < Hh; k0 += 8) {
      bf16x8 w8 = *(const bf16x8*)(wrow + k0);
      #pragma unroll
      for (int kk = 0; kk < 8; ++kk) acc += hsh[k0 + kk] * (float)w8[kk];
    }
    ghs[g] = acc;
    __syncthreads();
    if (g < Hh) {
      size_t rb = ((size_t)b * T + t) * (size_t)G3;
      float rr = 1.f / (1.f + expf(-(gi[rb + g] + ghs[g])));
      float zz = 1.f / (1.f + expf(-(gi[rb + Hh + g] + ghs[Hh + g])));
      float nn = tanhf(gi[rb + 2 * Hh + g] + rr * ghs[2 * Hh + g]);
      float hnew = (1.f - zz) * nn + zz * hsh[g];
      hsh[g] = hnew;
      pmax = fmaxf(pmax, hnew);
    }
    __syncthreads();
  }
  if (g < Hh) pool[(size_t)b * H2 + dir * Hh + g] = (pmax < -9e29f) ? 0.f : pmax;
}

// ---------- epilogue ----------
__global__ __launch_bounds__(512) void k_colsumP(const float* __restrict__ ev, float* __restrict__ part) {
  int t = threadIdx.x;
  int r0 = blockIdx.x * 64;
  float s = 0.f;
  for (int r = 0; r < 64; ++r) s += ev[(size_t)(r0 + r) * H2 + t];
  part[(size_t)blockIdx.x * H2 + t] = s;
}
__global__ __launch_bounds__(512) void k_esum(const float* __restrict__ part, float* __restrict__ out) {
  int t = threadIdx.x;
  float s = 0.f;
  for (int b = 0; b < 48; ++b) s += part[(size_t)b * H2 + t];
  out[t] = s;
}

__global__ void k_ves(const float* __restrict__ W, const float* __restrict__ sum, float* __restrict__ ves) {
  int d = blockIdx.x * 64 + threadIdx.x;
  const float* row = W + (size_t)d * H2;
  float s = 0.f;
  for (int f = 0; f < H2; ++f) s += row[f] * sum[f];
  ves[d] = s * (1.f / 3072.f);
}

__global__ void k_sal(const float* __restrict__ W, const float* __restrict__ blog,
                      const float* __restrict__ dv, float* __restrict__ out) {
  int doc = blockIdx.y;
  int i = blockIdx.x * 64 + threadIdx.x;
  const float* row = W + (size_t)i * (2 * H2);
  const float* dvr = dv + (size_t)doc * H2;
  float s = 0.f;
  for (int f = 0; f < H2; ++f) s += row[f] * blog[f];
  for (int f = 0; f < H2; ++f) s += row[H2 + f] * dvr[f];
  out[(size_t)doc * H2 + i] = s;
}

__global__ __launch_bounds__(256) void k_eventprobs(
    const float* __restrict__ evv, const float* __restrict__ ves,
    const float* __restrict__ w_ec, const float* __restrict__ tfs,
    const float* __restrict__ st, const float* __restrict__ c_tf,
    const float* __restrict__ c_sent, const float* __restrict__ c_bias,
    const int* __restrict__ flag, float* __restrict__ probs, void* __restrict__ outp) {
  int lane = threadIdx.x & 63;
  int e = blockIdx.x * 4 + (threadIdx.x >> 6);
  const float* row = evv + (size_t)e * H2;
  float s = 0.f;
  for (int f = lane; f < H2; f += 64) s += row[f] * (w_ec[f] + ves[f]);
  #pragma unroll
  for (int o = 32; o > 0; o >>= 1) s += __shfl_down(s, o, 64);
  if (lane == 0) {
    float p = s + c_tf[0] * tfs[e] + c_bias[0] + c_sent[0] * st[e / 3];
    probs[e] = p;
    if (flag[0]) ((bf16_t*)outp)[S_TOT + e] = (bf16_t)p;
    else         ((float*)outp)[S_TOT + e] = p;
  }
}

__global__ __launch_bounds__(256) void k_sentout(
    const float* __restrict__ sv, const float* __restrict__ u,
    const float* __restrict__ evv, const float* __restrict__ probs,
    const float* __restrict__ wsal, const float* __restrict__ w_sc,
    const float* __restrict__ dpe, const float* __restrict__ spe,
    const float* __restrict__ w_sdp, const float* __restrict__ w_sp,
    const float* __restrict__ b_rel, const float* __restrict__ para,
    const float* __restrict__ sbias, const int* __restrict__ flag,
    void* __restrict__ outp) {
  int lane = threadIdx.x & 63;
  int s = blockIdx.x * 4 + (threadIdx.x >> 6);
  int doc = s >> 5, jj = s & 31;
  const float* svr = sv + (size_t)s * H2;
  const float* ur  = u + (size_t)s * H2;
  const float* wd  = wsal + (size_t)doc * H2;
  float acc = 0.f, e0 = 0.f, e1 = 0.f, e2 = 0.f;
  for (int f = lane; f < H2; f += 64) {
    float svf = svr[f], uf = ur[f];
    acc += svf * (w_sc[f] + wd[f]);
    e0 += uf * evv[(size_t)(s * 3 + 0) * H2 + f];
    e1 += uf * evv[(size_t)(s * 3 + 1) * H2 + f];
    e2 += uf * evv[(size_t)(s * 3 + 2) * H2 + f];
  }
  if (lane < 50) {
    int dpos = (doc * 40) / 32;
    int spos = (jj * 30) / 32;
    acc += dpe[dpos * 50 + lane] * w_sdp[lane] + spe[spos * 50 + lane] * w_sp[lane];
  }
  #pragma unroll
  for (int o = 32; o > 0; o >>= 1) {
    acc += __shfl_down(acc, o, 64);
    e0  += __shfl_down(e0, o, 64);
    e1  += __shfl_down(e1, o, 64);
    e2  += __shfl_down(e2, o, 64);
  }
  if (lane == 0) {
    float br = b_rel[0];
    float rel = (e0 + br) * probs[s * 3 + 0] + (e1 + br) * probs[s * 3 + 1]
              + (e2 + br) * probs[s * 3 + 2];
    float v = acc + para[0] * rel + sbias[0];
    if (flag[0]) ((bf16_t*)outp)[s] = (bf16_t)v;
    else         ((float*)outp)[s] = v;
  }
}

// ---------------- launcher ----------------
extern "C" void kernel_launch(void* const* d_in, const int* in_sizes, int n_in,
                              void* d_out, int out_size, void* d_ws, size_t ws_size,
                              hipStream_t stream) {
  (void)in_sizes; (void)n_in; (void)out_size;
  const int* x      = (const int*)d_in[0];
  const int* events = (const int*)d_in[1];
  const void* embed = d_in[8];

  char* ws = (char*)d_ws;
  size_t off = 0;
  auto alloc = [&](size_t bytes) -> void* {
    void* p = ws + off;
    off += (bytes + 255) & ~(size_t)255;
    return p;
  };

  static const int cidx[NCANON] = {9,10,11,12, 13,14,15,16, 17,18,19,20, 21,22,23,24,
                                   25,26,27,28,29,30,31, 32,33,34,35, 36,37,38,40, 5,7};
  static const int csz[NCANON]  = {2*G3*D_EMB, 2*G3*Hh, 2*G3, 2*G3,
                                   2*G3*H2,    2*G3*Hh, 2*G3, 2*G3,
                                   2*G3*H2,    2*G3*Hh, 2*G3, 2*G3,
                                   2*G3*D_EMB, 2*G3*Hh, 2*G3, 2*G3,
                                   40*50, 30*50, H2, H2*H2, 1, 1, 1,
                                   H2, H2*2*H2, 50, 50,
                                   H2*H2, 1, 1, 1, E_TOT, S_TOT};
  Canon cd;
  int tot = 0;
  for (int i = 0; i < NCANON; ++i) { cd.src[i] = d_in[cidx[i]]; cd.off[i] = tot; tot += csz[i]; }
  cd.off[NCANON] = tot;

  int*   flag  = (int*)alloc(256);
  float* canon = (float*)alloc((size_t)tot * 4);
  float* cptr[NCANON];
  for (int i = 0; i < NCANON; ++i) cptr[i] = canon + cd.off[i];
  float *cw_wih = cptr[0], *cw_whh = cptr[1], *cw_bih = cptr[2], *cw_bhh = cptr[3];
  float *cs_wih = cptr[4], *cs_whh = cptr[5], *cs_bih = cptr[6], *cs_bhh = cptr[7];
  float *cd_wih = cptr[8], *cd_whh = cptr[9], *cd_bih = cptr[10], *cd_bhh = cptr[11];
  float *ce_wih = cptr[12], *ce_whh = cptr[13], *ce_bih = cptr[14], *ce_bhh = cptr[15];
  float *c_dpe = cptr[16], *c_spe = cptr[17], *c_wec = cptr[18], *c_Wes = cptr[19];
  float *c_tf = cptr[20], *c_sent = cptr[21], *c_ebias = cptr[22];
  float *c_wsc = cptr[23], *c_Wss = cptr[24], *c_wsdp = cptr[25], *c_wsp = cptr[26];
  float *c_Wer = cptr[27], *c_brel = cptr[28], *c_para = cptr[29], *c_sbias = cptr[30];
  float *c_tfs = cptr[31], *c_starg = cptr[32];

  bf16_t* whhW = (bf16_t*)alloc((size_t)2 * G3 * Hh * 2);
  bf16_t* whhE = (bf16_t*)alloc((size_t)2 * G3 * Hh * 2);
  bf16_t* whhS = (bf16_t*)alloc((size_t)2 * G3 * Hh * 2);
  bf16_t* whhD = (bf16_t*)alloc((size_t)2 * G3 * Hh * 2);
  float*  sv   = (float*)alloc((size_t)S_TOT * H2 * 4);
  float*  evv  = (float*)alloc((size_t)E_TOT * H2 * 4);
  float*  dv   = (float*)alloc((size_t)32 * H2 * 4);
  float*  blog = (float*)alloc((size_t)H2 * 4);
  float*  wSt  = (float*)alloc((size_t)2 * H2 * G3 * 4);
  float*  wDt  = (float*)alloc((size_t)2 * H2 * G3 * 4);
  float*  u    = (float*)alloc((size_t)S_TOT * H2 * 4);
  float*  part = (float*)alloc((size_t)48 * H2 * 4);
  float*  esum = (float*)alloc((size_t)H2 * 4);
  float*  ves  = (float*)alloc((size_t)H2 * 4);
  float*  wsal = (float*)alloc((size_t)32 * H2 * 4);
  float*  probs= (float*)alloc((size_t)E_TOT * 4);
  int*    lens = (int*)alloc((size_t)S_TOT * 4);

  size_t fixed = off;
  size_t avail = (ws_size > fixed) ? (ws_size - fixed) : 0;
  long long rpc = (long long)(avail / ((size_t)G3 * 4 * 2));
  rpc &= ~511LL;
  if (rpc < 512) rpc = 512;
  if (rpc > 32768) rpc = 32768;
  float* gib = (float*)(ws + fixed);

  // ---- prep ----
  k_detect<<<1, 64, 0, stream>>>((const unsigned short*)embed, flag);
  k_canon<<<(tot + 255) / 256, 256, 0, stream>>>(cd, flag, canon);
  int nwhh = 2 * G3 * Hh;
  k_f2b<<<(nwhh + 255) / 256, 256, 0, stream>>>(cw_whh, whhW, nwhh);
  k_f2b<<<(nwhh + 255) / 256, 256, 0, stream>>>(ce_whh, whhE, nwhh);
  k_f2b<<<(nwhh + 255) / 256, 256, 0, stream>>>(cs_whh, whhS, nwhh);
  k_f2b<<<(nwhh + 255) / 256, 256, 0, stream>>>(cd_whh, whhD, nwhh);
  k_lens<<<4, 256, 0, stream>>>(x, lens);
  k_transpose<<<dim3(24, 16, 2), 256, 0, stream>>>(cs_wih, wSt);
  k_transpose<<<dim3(24, 16, 2), 256, 0, stream>>>(cd_wih, wDt);

  // ---- word BiGRU -> sent_vec ----
  for (long long r0 = 0; r0 < 32768; r0 += rpc) {
    long long rows = 32768 - r0; if (rows > rpc) rows = rpc;
    for (int d = 0; d < 2; ++d)
      k_giA<<<dim3((int)(rows / 64), 12), 256, 0, stream>>>(
          x, embed, cw_wih + (size_t)d * G3 * D_EMB, cw_bih + d * G3, flag,
          gib + (size_t)d * rows * G3, (int)r0);
    k_gruM<<<dim3((int)(rows / 512), 2), 512, 0, stream>>>(
        gib, (size_t)rows * G3, whhW, cw_bhh, lens, sv, 32, (int)(r0 / 32));
  }
  // ---- event BiGRU -> event_vec ----
  for (long long r0 = 0; r0 < 12288; r0 += rpc) {
    long long rows = 12288 - r0; if (rows > rpc) rows = rpc;
    for (int d = 0; d < 2; ++d)
      k_giA<<<dim3((int)(rows / 64), 12), 256, 0, stream>>>(
          events, embed, ce_wih + (size_t)d * G3 * D_EMB, ce_bih + d * G3, flag,
          gib + (size_t)d * rows * G3, (int)r0);
    k_gruM<<<dim3((int)(rows / 64), 2), 512, 0, stream>>>(
        gib, (size_t)rows * G3, whhE, ce_bhh, nullptr, evv, 4, (int)(r0 / 4));
  }
  // ---- sent BiGRU (per doc) -> doc_vec ----
  for (int dir = 0; dir < 2; ++dir) {
    k_sgemm<<<dim3(16, 12), 256, 0, stream>>>(sv, wSt + (size_t)dir * H2 * G3,
                                              cs_bih + dir * G3, gib, 1024, G3, H2);
    k_gru1<<<32, 768, 0, stream>>>(gib, whhS + (size_t)dir * G3 * Hh,
                                   cs_bhh + dir * G3, dv, 32, dir);
  }
  // ---- doc BiGRU -> blog_vec ----
  for (int dir = 0; dir < 2; ++dir) {
    k_sgemm<<<dim3(1, 12), 256, 0, stream>>>(dv, wDt + (size_t)dir * H2 * G3,
                                             cd_bih + dir * G3, gib, 32, G3, H2);
    k_gru1<<<1, 768, 0, stream>>>(gib, whhD + (size_t)dir * G3 * Hh,
                                  cd_bhh + dir * G3, blog, 32, dir);
  }
  // ---- u = sent_vec @ W_event_rel ----
  k_sgemm<<<dim3(16, 8), 256, 0, stream>>>(sv, c_Wer, nullptr, u, 1024, H2, H2);
  // ---- event_sum, ves, wsal ----
  k_colsumP<<<48, 512, 0, stream>>>(evv, part);
  k_esum<<<1, 512, 0, stream>>>(part, esum);
  k_ves<<<8, 64, 0, stream>>>(c_Wes, esum, ves);
  k_sal<<<dim3(8, 32), 64, 0, stream>>>(c_Wss, blog, dv, wsal);
  // ---- outputs ----
  k_eventprobs<<<768, 256, 0, stream>>>(evv, ves, c_wec, c_tfs, c_starg,
                                        c_tf, c_sent, c_ebias, flag, probs, d_out);
  k_sentout<<<256, 256, 0, stream>>>(sv, u, evv, probs, wsal, c_wsc, c_dpe, c_spe,
                                     c_wsdp, c_wsp, c_brel, c_para, c_sbias, flag, d_out);
}

// Round 7
// 1794.588 us; speedup vs baseline: 2.2280x; 1.6046x over previous
//
#include <hip/hip_runtime.h>
#include <hip/hip_bf16.h>
#include <math.h>

typedef __bf16 bf16_t;
typedef __bf16 bf16x8 __attribute__((ext_vector_type(8)));
typedef __bf16 bf16x4 __attribute__((ext_vector_type(4)));
typedef float  f32x4  __attribute__((ext_vector_type(4)));

#define S_TOT 1024
#define T_W   32
#define D_EMB 300
#define KP    320
#define G3    768
#define Hh    256
#define H2    512
#define E_TOT 3072
#define NCANON 33

// ---------- dtype detector: flag=1 if float tensors are bf16, 0 if f32 ----------
__global__ void k_detect(const unsigned short* __restrict__ w, int* __restrict__ flag) {
  int lane = threadIdx.x;
  int sane = 0;
  for (int i = lane; i < 256; i += 64) {
    unsigned short v = w[2 * i];
    int ex = (v >> 7) & 0xFF;
    sane += (ex >= 96 && ex <= 134) ? 1 : 0;
  }
  #pragma unroll
  for (int o = 32; o > 0; o >>= 1) sane += __shfl_down(sane, o, 64);
  if (lane == 0) flag[0] = (sane >= 128) ? 1 : 0;
}

// ---------- canonicalize all float tensors to f32 ----------
struct Canon {
  const void* src[NCANON];
  int off[NCANON + 1];
};
__global__ void k_canon(Canon c, const int* __restrict__ flag, float* __restrict__ dst) {
  int i = blockIdx.x * 256 + threadIdx.x;
  if (i >= c.off[NCANON]) return;
  int seg = 0;
  while (c.off[seg + 1] <= i) ++seg;
  int j = i - c.off[seg];
  dst[i] = flag[0] ? (float)((const bf16_t*)c.src[seg])[j]
                   : ((const float*)c.src[seg])[j];
}

__global__ void k_f2b(const float* __restrict__ s, bf16_t* __restrict__ d, int n) {
  int i = blockIdx.x * 256 + threadIdx.x;
  if (i < n) d[i] = (bf16_t)s[i];
}

__global__ void k_lens(const int* __restrict__ x, int* __restrict__ lens) {
  int s = blockIdx.x * blockDim.x + threadIdx.x;
  if (s >= S_TOT) return;
  int c = 0;
  for (int t = 0; t < T_W; ++t) c += (x[s * T_W + t] != 0) ? 1 : 0;
  lens[s] = c;
}

// wih [2][768][512] f32 -> [2][512][768] f32
__global__ void k_transpose(const float* __restrict__ w, float* __restrict__ out) {
  __shared__ float tile[32][33];
  int d  = blockIdx.z;
  int n0 = blockIdx.x * 32, k0 = blockIdx.y * 32;
  int tx = threadIdx.x & 31, ty = threadIdx.x >> 5;
  for (int i = ty; i < 32; i += 8)
    tile[i][tx] = w[((size_t)d * G3 + n0 + i) * H2 + k0 + tx];
  __syncthreads();
  for (int i = ty; i < 32; i += 8)
    out[((size_t)d * H2 + k0 + i) * G3 + n0 + tx] = tile[tx][i];
}

// ---------- fused gather + input projection: gi = embed[toks] @ wih^T + bih ----------
__global__ __launch_bounds__(256) void k_giA(
    const int* __restrict__ toks, const void* __restrict__ embed,
    const float* __restrict__ wih, const float* __restrict__ bih,
    const int* __restrict__ flag, float* __restrict__ gi, int mbase) {
  __shared__ __align__(16) bf16_t Ah[64][32];
  __shared__ __align__(16) bf16_t Al[64][32];
  __shared__ __align__(16) bf16_t Bs[64][32];
  int tid = threadIdx.x;
  int wave = tid >> 6, lane = tid & 63;
  int l16 = lane & 15, quad = lane >> 4;
  int m0 = blockIdx.x * 64;
  int n0 = blockIdx.y * 64;
  int r  = tid >> 2;
  int kk = (tid & 3) * 8;
  int tok = toks[mbase + m0 + r];
  int isb = flag[0];
  const float*  ef = (const float*)embed + (size_t)tok * D_EMB;
  const bf16_t* eb = (const bf16_t*)embed + (size_t)tok * D_EMB;
  const float* wrow = wih + (size_t)(n0 + r) * D_EMB;
  f32x4 acc[4] = {{0.f,0.f,0.f,0.f},{0.f,0.f,0.f,0.f},{0.f,0.f,0.f,0.f},{0.f,0.f,0.f,0.f}};
  for (int k0 = 0; k0 < KP; k0 += 32) {
    int ka = k0 + kk;
    float av[8], bv[8];
    #pragma unroll
    for (int i = 0; i < 8; ++i) { av[i] = 0.f; bv[i] = 0.f; }
    if (ka < D_EMB) {
      if (isb) { bf16x4 t4 = *(const bf16x4*)(eb + ka);
                 av[0]=(float)t4[0]; av[1]=(float)t4[1]; av[2]=(float)t4[2]; av[3]=(float)t4[3]; }
      else     { float4 t4 = *(const float4*)(ef + ka);
                 av[0]=t4.x; av[1]=t4.y; av[2]=t4.z; av[3]=t4.w; }
      float4 w4 = *(const float4*)(wrow + ka);
      bv[0]=w4.x; bv[1]=w4.y; bv[2]=w4.z; bv[3]=w4.w;
    }
    if (ka + 4 < D_EMB) {
      if (isb) { bf16x4 t4 = *(const bf16x4*)(eb + ka + 4);
                 av[4]=(float)t4[0]; av[5]=(float)t4[1]; av[6]=(float)t4[2]; av[7]=(float)t4[3]; }
      else     { float4 t4 = *(const float4*)(ef + ka + 4);
                 av[4]=t4.x; av[5]=t4.y; av[6]=t4.z; av[7]=t4.w; }
      float4 w4 = *(const float4*)(wrow + ka + 4);
      bv[4]=w4.x; bv[5]=w4.y; bv[6]=w4.z; bv[7]=w4.w;
    }
    #pragma unroll
    for (int i = 0; i < 8; ++i) {
      bf16_t hi = (bf16_t)av[i];
      Ah[r][kk + i] = hi;
      Al[r][kk + i] = (bf16_t)(av[i] - (float)hi);
      Bs[r][kk + i] = (bf16_t)bv[i];
    }
    __syncthreads();
    bf16x8 ah = *(const bf16x8*)&Ah[wave * 16 + l16][quad * 8];
    bf16x8 al = *(const bf16x8*)&Al[wave * 16 + l16][quad * 8];
    #pragma unroll
    for (int j = 0; j < 4; ++j) {
      bf16x8 b8 = *(const bf16x8*)&Bs[j * 16 + l16][quad * 8];
      acc[j] = __builtin_amdgcn_mfma_f32_16x16x32_bf16(al, b8, acc[j], 0, 0, 0);
      acc[j] = __builtin_amdgcn_mfma_f32_16x16x32_bf16(ah, b8, acc[j], 0, 0, 0);
    }
    __syncthreads();
  }
  int row0 = m0 + wave * 16 + quad * 4;   // C/D: col=lane&15, row=quad*4+reg
  #pragma unroll
  for (int j = 0; j < 4; ++j) {
    int col = n0 + j * 16 + l16;
    float bvv = bih[col];
    #pragma unroll
    for (int rr = 0; rr < 4; ++rr)
      gi[(size_t)(row0 + rr) * G3 + col] = acc[j][rr] + bvv;
  }
}

// ---------- f32 SGEMM: C[M][N] = A[M][K] @ B[K][N] (+bias) ----------
__global__ __launch_bounds__(256) void k_sgemm(
    const float* __restrict__ A, const float* __restrict__ B,
    const float* __restrict__ bias, float* __restrict__ C,
    int M, int N, int K) {
  __shared__ float As[32][65];
  __shared__ float Bs[32][65];
  int bm = blockIdx.x * 64, bn = blockIdx.y * 64;
  int tid = threadIdx.x;
  int tx = tid & 15, ty = tid >> 4;
  float acc[4][4] = {};
  for (int k0 = 0; k0 < K; k0 += 32) {
    for (int i = tid; i < 64 * 32; i += 256) {
      int m = i >> 5, k = i & 31;
      As[k][m] = (bm + m < M) ? A[(size_t)(bm + m) * K + k0 + k] : 0.f;
    }
    for (int i = tid; i < 32 * 64; i += 256) {
      int k = i >> 6, n = i & 63;
      Bs[k][n] = B[(size_t)(k0 + k) * N + bn + n];
    }
    __syncthreads();
    #pragma unroll 8
    for (int k = 0; k < 32; ++k) {
      float a[4], b[4];
      #pragma unroll
      for (int i = 0; i < 4; ++i) a[i] = As[k][ty + i * 16];
      #pragma unroll
      for (int j = 0; j < 4; ++j) b[j] = Bs[k][tx + j * 16];
      #pragma unroll
      for (int i = 0; i < 4; ++i)
        #pragma unroll
        for (int j = 0; j < 4; ++j) acc[i][j] += a[i] * b[j];
    }
    __syncthreads();
  }
  for (int i = 0; i < 4; ++i) {
    int m = bm + ty + i * 16;
    if (m >= M) continue;
    for (int j = 0; j < 4; ++j) {
      int n = bn + tx + j * 16;
      C[(size_t)m * N + n] = acc[i][j] + (bias ? bias[n] : 0.f);
    }
  }
}

// ---------- batched MFMA GRU: 16 seqs/block, dirs fused via blockIdx.y ----------
// nsent = valid sequences in this chunk (pool writes masked; invalid rows compute
// garbage that stays confined to their own M-rows — MFMA mixes K, not M).
__global__ __launch_bounds__(512, 2) void k_gruM(
    const float* __restrict__ gi, size_t gi_dstride,
    const bf16_t* __restrict__ whh, const float* __restrict__ bhh,
    const int* __restrict__ lens, float* __restrict__ pool,
    int T, int sbase, int nsent) {
  int dir = blockIdx.y;
  int tid = threadIdx.x;
  int wave = tid >> 6, lane = tid & 63;
  int l16 = lane & 15, quad = lane >> 4;
  int sblk = blockIdx.x * 16;
  const float*  giD  = gi + (size_t)dir * gi_dstride;
  const bf16_t* whhD = whh + (size_t)dir * (size_t)G3 * Hh;
  const float*  bhhD = bhh + (size_t)dir * G3;

  __shared__ __align__(16) bf16_t hA[2][8][4][16][8];
  {
    bf16_t* hz = &hA[0][0][0][0][0];
    for (int i = tid; i < 2 * 8 * 4 * 16 * 8; i += 512) hz[i] = (bf16_t)0.f;
  }

  float bh[3][2];
  unsigned noff[3][2];
  #pragma unroll
  for (int g = 0; g < 3; ++g)
    #pragma unroll
    for (int jt = 0; jt < 2; ++jt) {
      int n = g * Hh + wave * 32 + jt * 16 + l16;
      bh[g][jt] = bhhD[n];
      noff[g][jt] = (unsigned)(n * Hh + quad * 8);
    }
  int Lm[4];
  #pragma unroll
  for (int r = 0; r < 4; ++r) {
    int sa = sblk + quad * 4 + r;
    Lm[r] = (lens && sa < nsent) ? lens[sbase + sa] : T;
  }

  float hprev[2][4], pmax[2][4];
  #pragma unroll
  for (int jt = 0; jt < 2; ++jt)
    #pragma unroll
    for (int r = 0; r < 4; ++r) { hprev[jt][r] = 0.f; pmax[jt][r] = -1e30f; }

  __syncthreads();

  for (int step = 0; step < T; ++step) {
    int t = dir ? (T - 1 - step) : step;
    float gv[3][2][4];
    #pragma unroll
    for (int jt = 0; jt < 2; ++jt) {
      int j = wave * 32 + jt * 16 + l16;
      #pragma unroll
      for (int r = 0; r < 4; ++r) {
        size_t rb = ((size_t)(sblk + quad * 4 + r) * T + t) * (size_t)G3;
        gv[0][jt][r] = giD[rb + j];
        gv[1][jt][r] = giD[rb + Hh + j];
        gv[2][jt][r] = giD[rb + 2 * Hh + j];
      }
    }
    f32x4 C[3][2];
    #pragma unroll
    for (int g = 0; g < 3; ++g)
      #pragma unroll
      for (int jt = 0; jt < 2; ++jt) C[g][jt] = (f32x4){0.f, 0.f, 0.f, 0.f};
    #pragma unroll
    for (int k0 = 0; k0 < 8; ++k0) {
      bf16x8 ah = *(const bf16x8*)&hA[0][k0][quad][l16][0];
      bf16x8 al = *(const bf16x8*)&hA[1][k0][quad][l16][0];
      #pragma unroll
      for (int g = 0; g < 3; ++g)
        #pragma unroll
        for (int jt = 0; jt < 2; ++jt) {
          bf16x8 b8 = *(const bf16x8*)(whhD + noff[g][jt] + k0 * 32);
          C[g][jt] = __builtin_amdgcn_mfma_f32_16x16x32_bf16(al, b8, C[g][jt], 0, 0, 0);
          C[g][jt] = __builtin_amdgcn_mfma_f32_16x16x32_bf16(ah, b8, C[g][jt], 0, 0, 0);
        }
    }
    __syncthreads();
    #pragma unroll
    for (int jt = 0; jt < 2; ++jt) {
      int q2 = jt * 2 + (l16 >> 3);
      int ii = l16 & 7;
      #pragma unroll
      for (int r = 0; r < 4; ++r) {
        int m = quad * 4 + r;
        float rr = 1.f / (1.f + expf(-(gv[0][jt][r] + C[0][jt][r] + bh[0][jt])));
        float zz = 1.f / (1.f + expf(-(gv[1][jt][r] + C[1][jt][r] + bh[1][jt])));
        float nn = tanhf(gv[2][jt][r] + rr * (C[2][jt][r] + bh[2][jt]));
        float hnew = (1.f - zz) * nn + zz * hprev[jt][r];
        hprev[jt][r] = hnew;
        bf16_t hi = (bf16_t)hnew;
        hA[0][wave][q2][m][ii] = hi;
        hA[1][wave][q2][m][ii] = (bf16_t)(hnew - (float)hi);
        if (t < Lm[r]) pmax[jt][r] = fmaxf(pmax[jt][r], hnew);
      }
    }
    __syncthreads();
  }
  #pragma unroll
  for (int jt = 0; jt < 2; ++jt) {
    int j = wave * 32 + jt * 16 + l16;
    #pragma unroll
    for (int r = 0; r < 4; ++r) {
      int sa = sblk + quad * 4 + r;
      if (sa < nsent) {
        float v = pmax[jt][r];
        if (v < -9e29f) v = 0.f;
        pool[(size_t)(sbase + sa) * H2 + dir * Hh + j] = v;
      }
    }
  }
}

// ---------- epilogue ----------
__global__ __launch_bounds__(512) void k_colsumP(const float* __restrict__ ev, float* __restrict__ part) {
  int t = threadIdx.x;
  int r0 = blockIdx.x * 64;
  float s = 0.f;
  for (int r = 0; r < 64; ++r) s += ev[(size_t)(r0 + r) * H2 + t];
  part[(size_t)blockIdx.x * H2 + t] = s;
}
__global__ __launch_bounds__(512) void k_esum(const float* __restrict__ part, float* __restrict__ out) {
  int t = threadIdx.x;
  float s = 0.f;
  for (int b = 0; b < 48; ++b) s += part[(size_t)b * H2 + t];
  out[t] = s;
}

__global__ void k_ves(const float* __restrict__ W, const float* __restrict__ sum, float* __restrict__ ves) {
  int d = blockIdx.x * 64 + threadIdx.x;
  const float* row = W + (size_t)d * H2;
  float s = 0.f;
  for (int f = 0; f < H2; ++f) s += row[f] * sum[f];
  ves[d] = s * (1.f / 3072.f);
}

__global__ void k_sal(const float* __restrict__ W, const float* __restrict__ blog,
                      const float* __restrict__ dv, float* __restrict__ out) {
  int doc = blockIdx.y;
  int i = blockIdx.x * 64 + threadIdx.x;
  const float* row = W + (size_t)i * (2 * H2);
  const float* dvr = dv + (size_t)doc * H2;
  float s = 0.f;
  for (int f = 0; f < H2; ++f) s += row[f] * blog[f];
  for (int f = 0; f < H2; ++f) s += row[H2 + f] * dvr[f];
  out[(size_t)doc * H2 + i] = s;
}

__global__ __launch_bounds__(256) void k_eventprobs(
    const float* __restrict__ evv, const float* __restrict__ ves,
    const float* __restrict__ w_ec, const float* __restrict__ tfs,
    const float* __restrict__ st, const float* __restrict__ c_tf,
    const float* __restrict__ c_sent, const float* __restrict__ c_bias,
    const int* __restrict__ flag, float* __restrict__ probs, void* __restrict__ outp) {
  int lane = threadIdx.x & 63;
  int e = blockIdx.x * 4 + (threadIdx.x >> 6);
  const float* row = evv + (size_t)e * H2;
  float s = 0.f;
  for (int f = lane; f < H2; f += 64) s += row[f] * (w_ec[f] + ves[f]);
  #pragma unroll
  for (int o = 32; o > 0; o >>= 1) s += __shfl_down(s, o, 64);
  if (lane == 0) {
    float p = s + c_tf[0] * tfs[e] + c_bias[0] + c_sent[0] * st[e / 3];
    probs[e] = p;
    if (flag[0]) ((bf16_t*)outp)[S_TOT + e] = (bf16_t)p;
    else         ((float*)outp)[S_TOT + e] = p;
  }
}

__global__ __launch_bounds__(256) void k_sentout(
    const float* __restrict__ sv, const float* __restrict__ u,
    const float* __restrict__ evv, const float* __restrict__ probs,
    const float* __restrict__ wsal, const float* __restrict__ w_sc,
    const float* __restrict__ dpe, const float* __restrict__ spe,
    const float* __restrict__ w_sdp, const float* __restrict__ w_sp,
    const float* __restrict__ b_rel, const float* __restrict__ para,
    const float* __restrict__ sbias, const int* __restrict__ flag,
    void* __restrict__ outp) {
  int lane = threadIdx.x & 63;
  int s = blockIdx.x * 4 + (threadIdx.x >> 6);
  int doc = s >> 5, jj = s & 31;
  const float* svr = sv + (size_t)s * H2;
  const float* ur  = u + (size_t)s * H2;
  const float* wd  = wsal + (size_t)doc * H2;
  float acc = 0.f, e0 = 0.f, e1 = 0.f, e2 = 0.f;
  for (int f = lane; f < H2; f += 64) {
    float svf = svr[f], uf = ur[f];
    acc += svf * (w_sc[f] + wd[f]);
    e0 += uf * evv[(size_t)(s * 3 + 0) * H2 + f];
    e1 += uf * evv[(size_t)(s * 3 + 1) * H2 + f];
    e2 += uf * evv[(size_t)(s * 3 + 2) * H2 + f];
  }
  if (lane < 50) {
    int dpos = (doc * 40) / 32;
    int spos = (jj * 30) / 32;
    acc += dpe[dpos * 50 + lane] * w_sdp[lane] + spe[spos * 50 + lane] * w_sp[lane];
  }
  #pragma unroll
  for (int o = 32; o > 0; o >>= 1) {
    acc += __shfl_down(acc, o, 64);
    e0  += __shfl_down(e0, o, 64);
    e1  += __shfl_down(e1, o, 64);
    e2  += __shfl_down(e2, o, 64);
  }
  if (lane == 0) {
    float br = b_rel[0];
    float rel = (e0 + br) * probs[s * 3 + 0] + (e1 + br) * probs[s * 3 + 1]
              + (e2 + br) * probs[s * 3 + 2];
    float v = acc + para[0] * rel + sbias[0];
    if (flag[0]) ((bf16_t*)outp)[s] = (bf16_t)v;
    else         ((float*)outp)[s] = v;
  }
}

// ---------------- launcher ----------------
extern "C" void kernel_launch(void* const* d_in, const int* in_sizes, int n_in,
                              void* d_out, int out_size, void* d_ws, size_t ws_size,
                              hipStream_t stream) {
  (void)in_sizes; (void)n_in; (void)out_size;
  const int* x      = (const int*)d_in[0];
  const int* events = (const int*)d_in[1];
  const void* embed = d_in[8];

  char* ws = (char*)d_ws;
  size_t off = 0;
  auto alloc = [&](size_t bytes) -> void* {
    void* p = ws + off;
    off += (bytes + 255) & ~(size_t)255;
    return p;
  };

  static const int cidx[NCANON] = {9,10,11,12, 13,14,15,16, 17,18,19,20, 21,22,23,24,
                                   25,26,27,28,29,30,31, 32,33,34,35, 36,37,38,40, 5,7};
  static const int csz[NCANON]  = {2*G3*D_EMB, 2*G3*Hh, 2*G3, 2*G3,
                                   2*G3*H2,    2*G3*Hh, 2*G3, 2*G3,
                                   2*G3*H2,    2*G3*Hh, 2*G3, 2*G3,
                                   2*G3*D_EMB, 2*G3*Hh, 2*G3, 2*G3,
                                   40*50, 30*50, H2, H2*H2, 1, 1, 1,
                                   H2, H2*2*H2, 50, 50,
                                   H2*H2, 1, 1, 1, E_TOT, S_TOT};
  Canon cd;
  int tot = 0;
  for (int i = 0; i < NCANON; ++i) { cd.src[i] = d_in[cidx[i]]; cd.off[i] = tot; tot += csz[i]; }
  cd.off[NCANON] = tot;

  int*   flag  = (int*)alloc(256);
  float* canon = (float*)alloc((size_t)tot * 4);
  float* cptr[NCANON];
  for (int i = 0; i < NCANON; ++i) cptr[i] = canon + cd.off[i];
  float *cw_wih = cptr[0], *cw_whh = cptr[1], *cw_bih = cptr[2], *cw_bhh = cptr[3];
  float *cs_wih = cptr[4], *cs_whh = cptr[5], *cs_bih = cptr[6], *cs_bhh = cptr[7];
  float *cd_wih = cptr[8], *cd_whh = cptr[9], *cd_bih = cptr[10], *cd_bhh = cptr[11];
  float *ce_wih = cptr[12], *ce_whh = cptr[13], *ce_bih = cptr[14], *ce_bhh = cptr[15];
  float *c_dpe = cptr[16], *c_spe = cptr[17], *c_wec = cptr[18], *c_Wes = cptr[19];
  float *c_tf = cptr[20], *c_sent = cptr[21], *c_ebias = cptr[22];
  float *c_wsc = cptr[23], *c_Wss = cptr[24], *c_wsdp = cptr[25], *c_wsp = cptr[26];
  float *c_Wer = cptr[27], *c_brel = cptr[28], *c_para = cptr[29], *c_sbias = cptr[30];
  float *c_tfs = cptr[31], *c_starg = cptr[32];

  bf16_t* whhW = (bf16_t*)alloc((size_t)2 * G3 * Hh * 2);
  bf16_t* whhE = (bf16_t*)alloc((size_t)2 * G3 * Hh * 2);
  bf16_t* whhS = (bf16_t*)alloc((size_t)2 * G3 * Hh * 2);
  bf16_t* whhD = (bf16_t*)alloc((size_t)2 * G3 * Hh * 2);
  float*  sv   = (float*)alloc((size_t)S_TOT * H2 * 4);
  float*  evv  = (float*)alloc((size_t)E_TOT * H2 * 4);
  float*  dv   = (float*)alloc((size_t)32 * H2 * 4);
  float*  blog = (float*)alloc((size_t)H2 * 4);
  float*  wSt  = (float*)alloc((size_t)2 * H2 * G3 * 4);
  float*  wDt  = (float*)alloc((size_t)2 * H2 * G3 * 4);
  float*  u    = (float*)alloc((size_t)S_TOT * H2 * 4);
  float*  part = (float*)alloc((size_t)48 * H2 * 4);
  float*  esum = (float*)alloc((size_t)H2 * 4);
  float*  ves  = (float*)alloc((size_t)H2 * 4);
  float*  wsal = (float*)alloc((size_t)32 * H2 * 4);
  float*  probs= (float*)alloc((size_t)E_TOT * 4);
  int*    lens = (int*)alloc((size_t)S_TOT * 4);
  // dedicated gi buffers for sent/doc levels (both dirs resident)
  float*  sgi  = (float*)alloc((size_t)2 * S_TOT * G3 * 4);   // 6.3 MB
  float*  dgi  = (float*)alloc((size_t)2 * 32 * G3 * 4);      // 0.2 MB

  size_t fixed = off;
  size_t avail = (ws_size > fixed) ? (ws_size - fixed) : 0;
  long long rpc = (long long)(avail / ((size_t)G3 * 4 * 2));
  rpc &= ~511LL;
  if (rpc < 512) rpc = 512;
  if (rpc > 32768) rpc = 32768;
  float* gib = (float*)(ws + fixed);

  // ---- prep ----
  k_detect<<<1, 64, 0, stream>>>((const unsigned short*)embed, flag);
  k_canon<<<(tot + 255) / 256, 256, 0, stream>>>(cd, flag, canon);
  int nwhh = 2 * G3 * Hh;
  k_f2b<<<(nwhh + 255) / 256, 256, 0, stream>>>(cw_whh, whhW, nwhh);
  k_f2b<<<(nwhh + 255) / 256, 256, 0, stream>>>(ce_whh, whhE, nwhh);
  k_f2b<<<(nwhh + 255) / 256, 256, 0, stream>>>(cs_whh, whhS, nwhh);
  k_f2b<<<(nwhh + 255) / 256, 256, 0, stream>>>(cd_whh, whhD, nwhh);
  k_lens<<<4, 256, 0, stream>>>(x, lens);
  k_transpose<<<dim3(24, 16, 2), 256, 0, stream>>>(cs_wih, wSt);
  k_transpose<<<dim3(24, 16, 2), 256, 0, stream>>>(cd_wih, wDt);

  // ---- word BiGRU -> sent_vec ----
  for (long long r0 = 0; r0 < 32768; r0 += rpc) {
    long long rows = 32768 - r0; if (rows > rpc) rows = rpc;
    for (int d = 0; d < 2; ++d)
      k_giA<<<dim3((int)(rows / 64), 12), 256, 0, stream>>>(
          x, embed, cw_wih + (size_t)d * G3 * D_EMB, cw_bih + d * G3, flag,
          gib + (size_t)d * rows * G3, (int)r0);
    k_gruM<<<dim3((int)(rows / 512), 2), 512, 0, stream>>>(
        gib, (size_t)rows * G3, whhW, cw_bhh, lens, sv, 32, (int)(r0 / 32),
        (int)(rows / 32));
  }
  // ---- event BiGRU -> event_vec ----
  for (long long r0 = 0; r0 < 12288; r0 += rpc) {
    long long rows = 12288 - r0; if (rows > rpc) rows = rpc;
    for (int d = 0; d < 2; ++d)
      k_giA<<<dim3((int)(rows / 64), 12), 256, 0, stream>>>(
          events, embed, ce_wih + (size_t)d * G3 * D_EMB, ce_bih + d * G3, flag,
          gib + (size_t)d * rows * G3, (int)r0);
    k_gruM<<<dim3((int)(rows / 64), 2), 512, 0, stream>>>(
        gib, (size_t)rows * G3, whhE, ce_bhh, nullptr, evv, 4, (int)(r0 / 4),
        (int)(rows / 4));
  }
  // ---- sent BiGRU (per doc, batch=32 docs, T=32) -> doc_vec ----
  for (int d = 0; d < 2; ++d)
    k_sgemm<<<dim3(16, 12), 256, 0, stream>>>(sv, wSt + (size_t)d * H2 * G3,
                                              cs_bih + d * G3,
                                              sgi + (size_t)d * S_TOT * G3, 1024, G3, H2);
  k_gruM<<<dim3(2, 2), 512, 0, stream>>>(sgi, (size_t)S_TOT * G3, whhS, cs_bhh,
                                         nullptr, dv, 32, 0, 32);
  // ---- doc BiGRU (batch=1, T=32) -> blog_vec ----
  for (int d = 0; d < 2; ++d)
    k_sgemm<<<dim3(1, 12), 256, 0, stream>>>(dv, wDt + (size_t)d * H2 * G3,
                                             cd_bih + d * G3,
                                             dgi + (size_t)d * 32 * G3, 32, G3, H2);
  k_gruM<<<dim3(1, 2), 512, 0, stream>>>(dgi, (size_t)32 * G3, whhD, cd_bhh,
                                         nullptr, blog, 32, 0, 1);
  // ---- u = sent_vec @ W_event_rel ----
  k_sgemm<<<dim3(16, 8), 256, 0, stream>>>(sv, c_Wer, nullptr, u, 1024, H2, H2);
  // ---- event_sum, ves, wsal ----
  k_colsumP<<<48, 512, 0, stream>>>(evv, part);
  k_esum<<<1, 512, 0, stream>>>(part, esum);
  k_ves<<<8, 64, 0, stream>>>(c_Wes, esum, ves);
  k_sal<<<dim3(8, 32), 64, 0, stream>>>(c_Wss, blog, dv, wsal);
  // ---- outputs ----
  k_eventprobs<<<768, 256, 0, stream>>>(evv, ves, c_wec, c_tfs, c_starg,
                                        c_tf, c_sent, c_ebias, flag, probs, d_out);
  k_sentout<<<256, 256, 0, stream>>>(sv, u, evv, probs, wsal, c_wsc, c_dpe, c_spe,
                                     c_wsdp, c_wsp, c_brel, c_para, c_sbias, flag, d_out);
}

// Round 8
// 1730.855 us; speedup vs baseline: 2.3100x; 1.0368x over previous
//
#include <hip/hip_runtime.h>
#include <hip/hip_bf16.h>
#include <math.h>

typedef __bf16 bf16_t;
typedef __bf16 bf16x8 __attribute__((ext_vector_type(8)));
typedef __bf16 bf16x4 __attribute__((ext_vector_type(4)));
typedef float  f32x4  __attribute__((ext_vector_type(4)));

#define S_TOT 1024
#define T_W   32
#define D_EMB 300
#define KP    320
#define G3    768
#define Hh    256
#define H2    512
#define E_TOT 3072
#define NCANON 33

// ---------- dtype detector: flag=1 if float tensors are bf16, 0 if f32 ----------
__global__ void k_detect(const unsigned short* __restrict__ w, int* __restrict__ flag) {
  int lane = threadIdx.x;
  int sane = 0;
  for (int i = lane; i < 256; i += 64) {
    unsigned short v = w[2 * i];
    int ex = (v >> 7) & 0xFF;
    sane += (ex >= 96 && ex <= 134) ? 1 : 0;
  }
  #pragma unroll
  for (int o = 32; o > 0; o >>= 1) sane += __shfl_down(sane, o, 64);
  if (lane == 0) flag[0] = (sane >= 128) ? 1 : 0;
}

// ---------- canonicalize all float tensors to f32 ----------
struct Canon {
  const void* src[NCANON];
  int off[NCANON + 1];
};
__global__ void k_canon(Canon c, const int* __restrict__ flag, float* __restrict__ dst) {
  int i = blockIdx.x * 256 + threadIdx.x;
  if (i >= c.off[NCANON]) return;
  int seg = 0;
  while (c.off[seg + 1] <= i) ++seg;
  int j = i - c.off[seg];
  dst[i] = flag[0] ? (float)((const bf16_t*)c.src[seg])[j]
                   : ((const float*)c.src[seg])[j];
}

__global__ void k_lens(const int* __restrict__ x, int* __restrict__ lens) {
  int s = blockIdx.x * blockDim.x + threadIdx.x;
  if (s >= S_TOT) return;
  int c = 0;
  for (int t = 0; t < T_W; ++t) c += (x[s * T_W + t] != 0) ? 1 : 0;
  lens[s] = c;
}

// wih [2][768][512] f32 -> [2][512][768] f32
__global__ void k_transpose(const float* __restrict__ w, float* __restrict__ out) {
  __shared__ float tile[32][33];
  int d  = blockIdx.z;
  int n0 = blockIdx.x * 32, k0 = blockIdx.y * 32;
  int tx = threadIdx.x & 31, ty = threadIdx.x >> 5;
  for (int i = ty; i < 32; i += 8)
    tile[i][tx] = w[((size_t)d * G3 + n0 + i) * H2 + k0 + tx];
  __syncthreads();
  for (int i = ty; i < 32; i += 8)
    out[((size_t)d * H2 + k0 + i) * G3 + n0 + tx] = tile[tx][i];
}

// ---------- pack whh [2][768][256] f32 -> B-fragment-major bf16 ----------
// layout: [dir][wave(8)][sl(6)][k0(8)][lane(64)][8 bf16], sl = g*2+jt
__global__ void k_packB(const float* __restrict__ whh, bf16_t* __restrict__ packed) {
  int id = blockIdx.x * 256 + threadIdx.x;     // 49152 groups of 8 elems
  if (id >= 49152) return;
  int lane = id & 63;
  int k0 = (id >> 6) & 7;
  int t9 = id >> 9;
  int sl = t9 % 6;
  int wb = t9 / 6;
  int wv = wb & 7;
  int dir = wb >> 3;
  int g = sl >> 1, jt = sl & 1;
  int l16 = lane & 15, quad = lane >> 4;
  int n = g * Hh + wv * 32 + jt * 16 + l16;
  const float* src = whh + ((size_t)dir * G3 + n) * Hh + k0 * 32 + quad * 8;
  bf16_t* dst = packed + (size_t)id * 8;
  #pragma unroll
  for (int i = 0; i < 8; ++i) dst[i] = (bf16_t)src[i];
}

// ---------- combined bias: biasC[dir][c] = bih[dir][c] + (c<512 ? bhh[dir][c] : 0) ----------
__global__ void k_biasC(const float* __restrict__ bih, const float* __restrict__ bhh,
                        float* __restrict__ out) {
  int i = blockIdx.x * 256 + threadIdx.x;
  if (i >= 2 * G3) return;
  int c = i % G3;
  out[i] = bih[i] + (c < 2 * Hh ? bhh[i] : 0.f);
}

// ---------- fused gather + input projection: gi = embed[toks] @ wih^T + biasC ----------
__global__ __launch_bounds__(256) void k_giA(
    const int* __restrict__ toks, const void* __restrict__ embed,
    const float* __restrict__ wih, const float* __restrict__ bih,
    const int* __restrict__ flag, float* __restrict__ gi, int mbase) {
  __shared__ __align__(16) bf16_t Ah[64][32];
  __shared__ __align__(16) bf16_t Al[64][32];
  __shared__ __align__(16) bf16_t Bs[64][32];
  int tid = threadIdx.x;
  int wave = tid >> 6, lane = tid & 63;
  int l16 = lane & 15, quad = lane >> 4;
  int m0 = blockIdx.x * 64;
  int n0 = blockIdx.y * 64;
  int r  = tid >> 2;
  int kk = (tid & 3) * 8;
  int tok = toks[mbase + m0 + r];
  int isb = flag[0];
  const float*  ef = (const float*)embed + (size_t)tok * D_EMB;
  const bf16_t* eb = (const bf16_t*)embed + (size_t)tok * D_EMB;
  const float* wrow = wih + (size_t)(n0 + r) * D_EMB;
  f32x4 acc[4] = {{0.f,0.f,0.f,0.f},{0.f,0.f,0.f,0.f},{0.f,0.f,0.f,0.f},{0.f,0.f,0.f,0.f}};
  for (int k0 = 0; k0 < KP; k0 += 32) {
    int ka = k0 + kk;
    float av[8], bv[8];
    #pragma unroll
    for (int i = 0; i < 8; ++i) { av[i] = 0.f; bv[i] = 0.f; }
    if (ka < D_EMB) {
      if (isb) { bf16x4 t4 = *(const bf16x4*)(eb + ka);
                 av[0]=(float)t4[0]; av[1]=(float)t4[1]; av[2]=(float)t4[2]; av[3]=(float)t4[3]; }
      else     { float4 t4 = *(const float4*)(ef + ka);
                 av[0]=t4.x; av[1]=t4.y; av[2]=t4.z; av[3]=t4.w; }
      float4 w4 = *(const float4*)(wrow + ka);
      bv[0]=w4.x; bv[1]=w4.y; bv[2]=w4.z; bv[3]=w4.w;
    }
    if (ka + 4 < D_EMB) {
      if (isb) { bf16x4 t4 = *(const bf16x4*)(eb + ka + 4);
                 av[4]=(float)t4[0]; av[5]=(float)t4[1]; av[6]=(float)t4[2]; av[7]=(float)t4[3]; }
      else     { float4 t4 = *(const float4*)(ef + ka + 4);
                 av[4]=t4.x; av[5]=t4.y; av[6]=t4.z; av[7]=t4.w; }
      float4 w4 = *(const float4*)(wrow + ka + 4);
      bv[4]=w4.x; bv[5]=w4.y; bv[6]=w4.z; bv[7]=w4.w;
    }
    #pragma unroll
    for (int i = 0; i < 8; ++i) {
      bf16_t hi = (bf16_t)av[i];
      Ah[r][kk + i] = hi;
      Al[r][kk + i] = (bf16_t)(av[i] - (float)hi);
      Bs[r][kk + i] = (bf16_t)bv[i];
    }
    __syncthreads();
    bf16x8 ah = *(const bf16x8*)&Ah[wave * 16 + l16][quad * 8];
    bf16x8 al = *(const bf16x8*)&Al[wave * 16 + l16][quad * 8];
    #pragma unroll
    for (int j = 0; j < 4; ++j) {
      bf16x8 b8 = *(const bf16x8*)&Bs[j * 16 + l16][quad * 8];
      acc[j] = __builtin_amdgcn_mfma_f32_16x16x32_bf16(al, b8, acc[j], 0, 0, 0);
      acc[j] = __builtin_amdgcn_mfma_f32_16x16x32_bf16(ah, b8, acc[j], 0, 0, 0);
    }
    __syncthreads();
  }
  int row0 = m0 + wave * 16 + quad * 4;   // C/D: col=lane&15, row=quad*4+reg
  #pragma unroll
  for (int j = 0; j < 4; ++j) {
    int col = n0 + j * 16 + l16;
    float bvv = bih[col];
    #pragma unroll
    for (int rr = 0; rr < 4; ++rr)
      gi[(size_t)(row0 + rr) * G3 + col] = acc[j][rr] + bvv;
  }
}

// ---------- f32 SGEMM: C[M][N] = A[M][K] @ B[K][N] (+bias) ----------
__global__ __launch_bounds__(256) void k_sgemm(
    const float* __restrict__ A, const float* __restrict__ B,
    const float* __restrict__ bias, float* __restrict__ C,
    int M, int N, int K) {
  __shared__ float As[32][65];
  __shared__ float Bs[32][65];
  int bm = blockIdx.x * 64, bn = blockIdx.y * 64;
  int tid = threadIdx.x;
  int tx = tid & 15, ty = tid >> 4;
  float acc[4][4] = {};
  for (int k0 = 0; k0 < K; k0 += 32) {
    for (int i = tid; i < 64 * 32; i += 256) {
      int m = i >> 5, k = i & 31;
      As[k][m] = (bm + m < M) ? A[(size_t)(bm + m) * K + k0 + k] : 0.f;
    }
    for (int i = tid; i < 32 * 64; i += 256) {
      int k = i >> 6, n = i & 63;
      Bs[k][n] = B[(size_t)(k0 + k) * N + bn + n];
    }
    __syncthreads();
    #pragma unroll 8
    for (int k = 0; k < 32; ++k) {
      float a[4], b[4];
      #pragma unroll
      for (int i = 0; i < 4; ++i) a[i] = As[k][ty + i * 16];
      #pragma unroll
      for (int j = 0; j < 4; ++j) b[j] = Bs[k][tx + j * 16];
      #pragma unroll
      for (int i = 0; i < 4; ++i)
        #pragma unroll
        for (int j = 0; j < 4; ++j) acc[i][j] += a[i] * b[j];
    }
    __syncthreads();
  }
  for (int i = 0; i < 4; ++i) {
    int m = bm + ty + i * 16;
    if (m >= M) continue;
    for (int j = 0; j < 4; ++j) {
      int n = bn + tx + j * 16;
      C[(size_t)m * N + n] = acc[i][j] + (bias ? bias[n] : 0.f);
    }
  }
}

// ---------- batched MFMA GRU, whh B-fragments REGISTER-RESIDENT across all T steps ----------
// (512,1): 1 block/CU -> 256-VGPR cap; Bf[48] = 192 VGPR holds this wave's whh slice.
// whhP is k_packB fragment-major layout -> the one-time load is 48 coalesced 1KB loads.
// gi bias includes bhh for r,z gates (k_biasC); only n-gate bhh applied here.
__global__ __launch_bounds__(512, 1) void k_gruM(
    const float* __restrict__ gi, size_t gi_dstride,
    const bf16_t* __restrict__ whhP, const float* __restrict__ bhh,
    const int* __restrict__ lens, float* __restrict__ pool,
    int T, int sbase, int nsent) {
  int dir = blockIdx.y;
  int tid = threadIdx.x;
  int wave = tid >> 6, lane = tid & 63;
  int l16 = lane & 15, quad = lane >> 4;
  int sblk = blockIdx.x * 16;
  const float* giD  = gi + (size_t)dir * gi_dstride;
  const float* bhhD = bhh + (size_t)dir * G3;

  __shared__ __align__(16) bf16_t hA[2][8][4][16][8];
  {
    bf16_t* hz = &hA[0][0][0][0][0];
    for (int i = tid; i < 2 * 8 * 4 * 16 * 8; i += 512) hz[i] = (bf16_t)0.f;
  }

  // one-time coalesced load of this wave's whh fragments into registers
  bf16x8 Bf[48];
  {
    const bf16_t* Bb = whhP + (size_t)dir * G3 * Hh + (size_t)wave * 48 * 512 + lane * 8;
    #pragma unroll
    for (int s = 0; s < 48; ++s) Bf[s] = *(const bf16x8*)(Bb + s * 512);
  }
  float bhn[2];
  #pragma unroll
  for (int jt = 0; jt < 2; ++jt)
    bhn[jt] = bhhD[2 * Hh + wave * 32 + jt * 16 + l16];
  int Lm[4];
  #pragma unroll
  for (int r = 0; r < 4; ++r) {
    int sa = sblk + quad * 4 + r;
    Lm[r] = (lens && sa < nsent) ? lens[sbase + sa] : T;
  }
  float pmax[2][4];
  #pragma unroll
  for (int jt = 0; jt < 2; ++jt)
    #pragma unroll
    for (int r = 0; r < 4; ++r) pmax[jt][r] = -1e30f;

  __syncthreads();

  for (int step = 0; step < T; ++step) {
    int t = dir ? (T - 1 - step) : step;
    // MFMA phase: gh = h @ whh^T  (B from registers, A from LDS)
    f32x4 C[3][2];
    #pragma unroll
    for (int g = 0; g < 3; ++g)
      #pragma unroll
      for (int jt = 0; jt < 2; ++jt) C[g][jt] = (f32x4){0.f, 0.f, 0.f, 0.f};
    #pragma unroll
    for (int k0 = 0; k0 < 8; ++k0) {
      bf16x8 ah = *(const bf16x8*)&hA[0][k0][quad][l16][0];
      bf16x8 al = *(const bf16x8*)&hA[1][k0][quad][l16][0];
      #pragma unroll
      for (int g = 0; g < 3; ++g)
        #pragma unroll
        for (int jt = 0; jt < 2; ++jt) {
          bf16x8 b8 = Bf[(g * 2 + jt) * 8 + k0];
          C[g][jt] = __builtin_amdgcn_mfma_f32_16x16x32_bf16(al, b8, C[g][jt], 0, 0, 0);
          C[g][jt] = __builtin_amdgcn_mfma_f32_16x16x32_bf16(ah, b8, C[g][jt], 0, 0, 0);
        }
    }
    __syncthreads();   // hA reads complete before rewrite
    // gi loads (gv includes bih + bhh for r,z via biasC)
    float gv[3][2][4];
    #pragma unroll
    for (int jt = 0; jt < 2; ++jt) {
      int j = wave * 32 + jt * 16 + l16;
      #pragma unroll
      for (int r = 0; r < 4; ++r) {
        size_t rb = ((size_t)(sblk + quad * 4 + r) * T + t) * (size_t)G3;
        gv[0][jt][r] = giD[rb + j];
        gv[1][jt][r] = giD[rb + Hh + j];
        gv[2][jt][r] = giD[rb + 2 * Hh + j];
      }
    }
    #pragma unroll
    for (int jt = 0; jt < 2; ++jt) {
      int q2 = jt * 2 + (l16 >> 3);
      int ii = l16 & 7;
      #pragma unroll
      for (int r = 0; r < 4; ++r) {
        int m = quad * 4 + r;
        float hp = (float)hA[0][wave][q2][m][ii] + (float)hA[1][wave][q2][m][ii];
        float rr = 1.f / (1.f + expf(-(gv[0][jt][r] + C[0][jt][r])));
        float zz = 1.f / (1.f + expf(-(gv[1][jt][r] + C[1][jt][r])));
        float nn = tanhf(gv[2][jt][r] + rr * (C[2][jt][r] + bhn[jt]));
        float hnew = (1.f - zz) * nn + zz * hp;
        bf16_t hi = (bf16_t)hnew;
        hA[0][wave][q2][m][ii] = hi;
        hA[1][wave][q2][m][ii] = (bf16_t)(hnew - (float)hi);
        if (t < Lm[r]) pmax[jt][r] = fmaxf(pmax[jt][r], hnew);
      }
    }
    __syncthreads();   // h writes visible before next step's A reads
  }
  #pragma unroll
  for (int jt = 0; jt < 2; ++jt) {
    int j = wave * 32 + jt * 16 + l16;
    #pragma unroll
    for (int r = 0; r < 4; ++r) {
      int sa = sblk + quad * 4 + r;
      if (sa < nsent) {
        float v = pmax[jt][r];
        if (v < -9e29f) v = 0.f;
        pool[(size_t)(sbase + sa) * H2 + dir * Hh + j] = v;
      }
    }
  }
}

// ---------- epilogue ----------
__global__ __launch_bounds__(512) void k_colsumP(const float* __restrict__ ev, float* __restrict__ part) {
  int t = threadIdx.x;
  int r0 = blockIdx.x * 64;
  float s = 0.f;
  for (int r = 0; r < 64; ++r) s += ev[(size_t)(r0 + r) * H2 + t];
  part[(size_t)blockIdx.x * H2 + t] = s;
}
__global__ __launch_bounds__(512) void k_esum(const float* __restrict__ part, float* __restrict__ out) {
  int t = threadIdx.x;
  float s = 0.f;
  for (int b = 0; b < 48; ++b) s += part[(size_t)b * H2 + t];
  out[t] = s;
}

__global__ void k_ves(const float* __restrict__ W, const float* __restrict__ sum, float* __restrict__ ves) {
  int d = blockIdx.x * 64 + threadIdx.x;
  const float* row = W + (size_t)d * H2;
  float s = 0.f;
  for (int f = 0; f < H2; ++f) s += row[f] * sum[f];
  ves[d] = s * (1.f / 3072.f);
}

__global__ void k_sal(const float* __restrict__ W, const float* __restrict__ blog,
                      const float* __restrict__ dv, float* __restrict__ out) {
  int doc = blockIdx.y;
  int i = blockIdx.x * 64 + threadIdx.x;
  const float* row = W + (size_t)i * (2 * H2);
  const float* dvr = dv + (size_t)doc * H2;
  float s = 0.f;
  for (int f = 0; f < H2; ++f) s += row[f] * blog[f];
  for (int f = 0; f < H2; ++f) s += row[H2 + f] * dvr[f];
  out[(size_t)doc * H2 + i] = s;
}

__global__ __launch_bounds__(256) void k_eventprobs(
    const float* __restrict__ evv, const float* __restrict__ ves,
    const float* __restrict__ w_ec, const float* __restrict__ tfs,
    const float* __restrict__ st, const float* __restrict__ c_tf,
    const float* __restrict__ c_sent, const float* __restrict__ c_bias,
    const int* __restrict__ flag, float* __restrict__ probs, void* __restrict__ outp) {
  int lane = threadIdx.x & 63;
  int e = blockIdx.x * 4 + (threadIdx.x >> 6);
  const float* row = evv + (size_t)e * H2;
  float s = 0.f;
  for (int f = lane; f < H2; f += 64) s += row[f] * (w_ec[f] + ves[f]);
  #pragma unroll
  for (int o = 32; o > 0; o >>= 1) s += __shfl_down(s, o, 64);
  if (lane == 0) {
    float p = s + c_tf[0] * tfs[e] + c_bias[0] + c_sent[0] * st[e / 3];
    probs[e] = p;
    if (flag[0]) ((bf16_t*)outp)[S_TOT + e] = (bf16_t)p;
    else         ((float*)outp)[S_TOT + e] = p;
  }
}

__global__ __launch_bounds__(256) void k_sentout(
    const float* __restrict__ sv, const float* __restrict__ u,
    const float* __restrict__ evv, const float* __restrict__ probs,
    const float* __restrict__ wsal, const float* __restrict__ w_sc,
    const float* __restrict__ dpe, const float* __restrict__ spe,
    const float* __restrict__ w_sdp, const float* __restrict__ w_sp,
    const float* __restrict__ b_rel, const float* __restrict__ para,
    const float* __restrict__ sbias, const int* __restrict__ flag,
    void* __restrict__ outp) {
  int lane = threadIdx.x & 63;
  int s = blockIdx.x * 4 + (threadIdx.x >> 6);
  int doc = s >> 5, jj = s & 31;
  const float* svr = sv + (size_t)s * H2;
  const float* ur  = u + (size_t)s * H2;
  const float* wd  = wsal + (size_t)doc * H2;
  float acc = 0.f, e0 = 0.f, e1 = 0.f, e2 = 0.f;
  for (int f = lane; f < H2; f += 64) {
    float svf = svr[f], uf = ur[f];
    acc += svf * (w_sc[f] + wd[f]);
    e0 += uf * evv[(size_t)(s * 3 + 0) * H2 + f];
    e1 += uf * evv[(size_t)(s * 3 + 1) * H2 + f];
    e2 += uf * evv[(size_t)(s * 3 + 2) * H2 + f];
  }
  if (lane < 50) {
    int dpos = (doc * 40) / 32;
    int spos = (jj * 30) / 32;
    acc += dpe[dpos * 50 + lane] * w_sdp[lane] + spe[spos * 50 + lane] * w_sp[lane];
  }
  #pragma unroll
  for (int o = 32; o > 0; o >>= 1) {
    acc += __shfl_down(acc, o, 64);
    e0  += __shfl_down(e0, o, 64);
    e1  += __shfl_down(e1, o, 64);
    e2  += __shfl_down(e2, o, 64);
  }
  if (lane == 0) {
    float br = b_rel[0];
    float rel = (e0 + br) * probs[s * 3 + 0] + (e1 + br) * probs[s * 3 + 1]
              + (e2 + br) * probs[s * 3 + 2];
    float v = acc + para[0] * rel + sbias[0];
    if (flag[0]) ((bf16_t*)outp)[s] = (bf16_t)v;
    else         ((float*)outp)[s] = v;
  }
}

// ---------------- launcher ----------------
extern "C" void kernel_launch(void* const* d_in, const int* in_sizes, int n_in,
                              void* d_out, int out_size, void* d_ws, size_t ws_size,
                              hipStream_t stream) {
  (void)in_sizes; (void)n_in; (void)out_size;
  const int* x      = (const int*)d_in[0];
  const int* events = (const int*)d_in[1];
  const void* embed = d_in[8];

  char* ws = (char*)d_ws;
  size_t off = 0;
  auto alloc = [&](size_t bytes) -> void* {
    void* p = ws + off;
    off += (bytes + 255) & ~(size_t)255;
    return p;
  };

  static const int cidx[NCANON] = {9,10,11,12, 13,14,15,16, 17,18,19,20, 21,22,23,24,
                                   25,26,27,28,29,30,31, 32,33,34,35, 36,37,38,40, 5,7};
  static const int csz[NCANON]  = {2*G3*D_EMB, 2*G3*Hh, 2*G3, 2*G3,
                                   2*G3*H2,    2*G3*Hh, 2*G3, 2*G3,
                                   2*G3*H2,    2*G3*Hh, 2*G3, 2*G3,
                                   2*G3*D_EMB, 2*G3*Hh, 2*G3, 2*G3,
                                   40*50, 30*50, H2, H2*H2, 1, 1, 1,
                                   H2, H2*2*H2, 50, 50,
                                   H2*H2, 1, 1, 1, E_TOT, S_TOT};
  Canon cd;
  int tot = 0;
  for (int i = 0; i < NCANON; ++i) { cd.src[i] = d_in[cidx[i]]; cd.off[i] = tot; tot += csz[i]; }
  cd.off[NCANON] = tot;

  int*   flag  = (int*)alloc(256);
  float* canon = (float*)alloc((size_t)tot * 4);
  float* cptr[NCANON];
  for (int i = 0; i < NCANON; ++i) cptr[i] = canon + cd.off[i];
  float *cw_wih = cptr[0], *cw_whh = cptr[1], *cw_bih = cptr[2], *cw_bhh = cptr[3];
  float *cs_wih = cptr[4], *cs_whh = cptr[5], *cs_bih = cptr[6], *cs_bhh = cptr[7];
  float *cd_wih = cptr[8], *cd_whh = cptr[9], *cd_bih = cptr[10], *cd_bhh = cptr[11];
  float *ce_wih = cptr[12], *ce_whh = cptr[13], *ce_bih = cptr[14], *ce_bhh = cptr[15];
  float *c_dpe = cptr[16], *c_spe = cptr[17], *c_wec = cptr[18], *c_Wes = cptr[19];
  float *c_tf = cptr[20], *c_sent = cptr[21], *c_ebias = cptr[22];
  float *c_wsc = cptr[23], *c_Wss = cptr[24], *c_wsdp = cptr[25], *c_wsp = cptr[26];
  float *c_Wer = cptr[27], *c_brel = cptr[28], *c_para = cptr[29], *c_sbias = cptr[30];
  float *c_tfs = cptr[31], *c_starg = cptr[32];

  bf16_t* packW = (bf16_t*)alloc((size_t)2 * G3 * Hh * 2);
  bf16_t* packE = (bf16_t*)alloc((size_t)2 * G3 * Hh * 2);
  bf16_t* packS = (bf16_t*)alloc((size_t)2 * G3 * Hh * 2);
  bf16_t* packD = (bf16_t*)alloc((size_t)2 * G3 * Hh * 2);
  float*  bcW  = (float*)alloc((size_t)2 * G3 * 4);
  float*  bcE  = (float*)alloc((size_t)2 * G3 * 4);
  float*  bcS  = (float*)alloc((size_t)2 * G3 * 4);
  float*  bcD  = (float*)alloc((size_t)2 * G3 * 4);
  float*  sv   = (float*)alloc((size_t)S_TOT * H2 * 4);
  float*  evv  = (float*)alloc((size_t)E_TOT * H2 * 4);
  float*  dv   = (float*)alloc((size_t)32 * H2 * 4);
  float*  blog = (float*)alloc((size_t)H2 * 4);
  float*  wSt  = (float*)alloc((size_t)2 * H2 * G3 * 4);
  float*  wDt  = (float*)alloc((size_t)2 * H2 * G3 * 4);
  float*  u    = (float*)alloc((size_t)S_TOT * H2 * 4);
  float*  part = (float*)alloc((size_t)48 * H2 * 4);
  float*  esum = (float*)alloc((size_t)H2 * 4);
  float*  ves  = (float*)alloc((size_t)H2 * 4);
  float*  wsal = (float*)alloc((size_t)32 * H2 * 4);
  float*  probs= (float*)alloc((size_t)E_TOT * 4);
  int*    lens = (int*)alloc((size_t)S_TOT * 4);
  float*  sgi  = (float*)alloc((size_t)2 * S_TOT * G3 * 4);
  float*  dgi  = (float*)alloc((size_t)2 * 32 * G3 * 4);

  size_t fixed = off;
  size_t avail = (ws_size > fixed) ? (ws_size - fixed) : 0;
  long long rpc = (long long)(avail / ((size_t)G3 * 4 * 2));
  rpc &= ~511LL;
  if (rpc < 512) rpc = 512;
  if (rpc > 32768) rpc = 32768;
  float* gib = (float*)(ws + fixed);

  // ---- prep ----
  k_detect<<<1, 64, 0, stream>>>((const unsigned short*)embed, flag);
  k_canon<<<(tot + 255) / 256, 256, 0, stream>>>(cd, flag, canon);
  k_packB<<<192, 256, 0, stream>>>(cw_whh, packW);
  k_packB<<<192, 256, 0, stream>>>(ce_whh, packE);
  k_packB<<<192, 256, 0, stream>>>(cs_whh, packS);
  k_packB<<<192, 256, 0, stream>>>(cd_whh, packD);
  k_biasC<<<6, 256, 0, stream>>>(cw_bih, cw_bhh, bcW);
  k_biasC<<<6, 256, 0, stream>>>(ce_bih, ce_bhh, bcE);
  k_biasC<<<6, 256, 0, stream>>>(cs_bih, cs_bhh, bcS);
  k_biasC<<<6, 256, 0, stream>>>(cd_bih, cd_bhh, bcD);
  k_lens<<<4, 256, 0, stream>>>(x, lens);
  k_transpose<<<dim3(24, 16, 2), 256, 0, stream>>>(cs_wih, wSt);
  k_transpose<<<dim3(24, 16, 2), 256, 0, stream>>>(cd_wih, wDt);

  // ---- word BiGRU -> sent_vec ----
  for (long long r0 = 0; r0 < 32768; r0 += rpc) {
    long long rows = 32768 - r0; if (rows > rpc) rows = rpc;
    for (int d = 0; d < 2; ++d)
      k_giA<<<dim3((int)(rows / 64), 12), 256, 0, stream>>>(
          x, embed, cw_wih + (size_t)d * G3 * D_EMB, bcW + d * G3, flag,
          gib + (size_t)d * rows * G3, (int)r0);
    k_gruM<<<dim3((int)(rows / 512), 2), 512, 0, stream>>>(
        gib, (size_t)rows * G3, packW, cw_bhh, lens, sv, 32, (int)(r0 / 32),
        (int)(rows / 32));
  }
  // ---- event BiGRU -> event_vec ----
  for (long long r0 = 0; r0 < 12288; r0 += rpc) {
    long long rows = 12288 - r0; if (rows > rpc) rows = rpc;
    for (int d = 0; d < 2; ++d)
      k_giA<<<dim3((int)(rows / 64), 12), 256, 0, stream>>>(
          events, embed, ce_wih + (size_t)d * G3 * D_EMB, bcE + d * G3, flag,
          gib + (size_t)d * rows * G3, (int)r0);
    k_gruM<<<dim3((int)(rows / 64), 2), 512, 0, stream>>>(
        gib, (size_t)rows * G3, packE, ce_bhh, nullptr, evv, 4, (int)(r0 / 4),
        (int)(rows / 4));
  }
  // ---- sent BiGRU (batch=32 docs, T=32) -> doc_vec ----
  for (int d = 0; d < 2; ++d)
    k_sgemm<<<dim3(16, 12), 256, 0, stream>>>(sv, wSt + (size_t)d * H2 * G3,
                                              bcS + d * G3,
                                              sgi + (size_t)d * S_TOT * G3, 1024, G3, H2);
  k_gruM<<<dim3(2, 2), 512, 0, stream>>>(sgi, (size_t)S_TOT * G3, packS, cs_bhh,
                                         nullptr, dv, 32, 0, 32);
  // ---- doc BiGRU (batch=1, T=32) -> blog_vec ----
  for (int d = 0; d < 2; ++d)
    k_sgemm<<<dim3(1, 12), 256, 0, stream>>>(dv, wDt + (size_t)d * H2 * G3,
                                             bcD + d * G3,
                                             dgi + (size_t)d * 32 * G3, 32, G3, H2);
  k_gruM<<<dim3(1, 2), 512, 0, stream>>>(dgi, (size_t)32 * G3, packD, cd_bhh,
                                         nullptr, blog, 32, 0, 1);
  // ---- u = sent_vec @ W_event_rel ----
  k_sgemm<<<dim3(16, 8), 256, 0, stream>>>(sv, c_Wer, nullptr, u, 1024, H2, H2);
  // ---- event_sum, ves, wsal ----
  k_colsumP<<<48, 512, 0, stream>>>(evv, part);
  k_esum<<<1, 512, 0, stream>>>(part, esum);
  k_ves<<<8, 64, 0, stream>>>(c_Wes, esum, ves);
  k_sal<<<dim3(8, 32), 64, 0, stream>>>(c_Wss, blog, dv, wsal);
  // ---- outputs ----
  k_eventprobs<<<768, 256, 0, stream>>>(evv, ves, c_wec, c_tfs, c_starg,
                                        c_tf, c_sent, c_ebias, flag, probs, d_out);
  k_sentout<<<256, 256, 0, stream>>>(sv, u, evv, probs, wsal, c_wsc, c_dpe, c_spe,
                                     c_wsdp, c_wsp, c_brel, c_para, c_sbias, flag, d_out);
}

// Round 9
// 1553.030 us; speedup vs baseline: 2.5745x; 1.1145x over previous
//
#include <hip/hip_runtime.h>
#include <hip/hip_bf16.h>
#include <math.h>

typedef __bf16 bf16_t;
typedef __bf16 bf16x8 __attribute__((ext_vector_type(8)));
typedef __bf16 bf16x4 __attribute__((ext_vector_type(4)));
typedef float  f32x4  __attribute__((ext_vector_type(4)));

#define S_TOT 1024
#define T_W   32
#define D_EMB 300
#define KP    320
#define G3    768
#define Hh    256
#define H2    512
#define E_TOT 3072
#define NCANON 33

// ---------- dtype detector: flag=1 if float tensors are bf16, 0 if f32 ----------
__global__ void k_detect(const unsigned short* __restrict__ w, int* __restrict__ flag) {
  int lane = threadIdx.x;
  int sane = 0;
  for (int i = lane; i < 256; i += 64) {
    unsigned short v = w[2 * i];
    int ex = (v >> 7) & 0xFF;
    sane += (ex >= 96 && ex <= 134) ? 1 : 0;
  }
  #pragma unroll
  for (int o = 32; o > 0; o >>= 1) sane += __shfl_down(sane, o, 64);
  if (lane == 0) flag[0] = (sane >= 128) ? 1 : 0;
}

// ---------- canonicalize all float tensors to f32 ----------
struct Canon {
  const void* src[NCANON];
  int off[NCANON + 1];
};
__global__ void k_canon(Canon c, const int* __restrict__ flag, float* __restrict__ dst) {
  int i = blockIdx.x * 256 + threadIdx.x;
  if (i >= c.off[NCANON]) return;
  int seg = 0;
  while (c.off[seg + 1] <= i) ++seg;
  int j = i - c.off[seg];
  dst[i] = flag[0] ? (float)((const bf16_t*)c.src[seg])[j]
                   : ((const float*)c.src[seg])[j];
}

__global__ void k_lens(const int* __restrict__ x, int* __restrict__ lens) {
  int s = blockIdx.x * blockDim.x + threadIdx.x;
  if (s >= S_TOT) return;
  int c = 0;
  for (int t = 0; t < T_W; ++t) c += (x[s * T_W + t] != 0) ? 1 : 0;
  lens[s] = c;
}

// wih [2][768][512] f32 -> [2][512][768] f32
__global__ void k_transpose(const float* __restrict__ w, float* __restrict__ out) {
  __shared__ float tile[32][33];
  int d  = blockIdx.z;
  int n0 = blockIdx.x * 32, k0 = blockIdx.y * 32;
  int tx = threadIdx.x & 31, ty = threadIdx.x >> 5;
  for (int i = ty; i < 32; i += 8)
    tile[i][tx] = w[((size_t)d * G3 + n0 + i) * H2 + k0 + tx];
  __syncthreads();
  for (int i = ty; i < 32; i += 8)
    out[((size_t)d * H2 + k0 + i) * G3 + n0 + tx] = tile[tx][i];
}

// ---------- pack whh [2][768][256] f32 -> B-fragment-major bf16 ----------
// layout: [dir][wave(8)][sl(6)][k0(8)][lane(64)][8 bf16], sl = g*2+jt
__global__ void k_packB(const float* __restrict__ whh, bf16_t* __restrict__ packed) {
  int id = blockIdx.x * 256 + threadIdx.x;     // 49152 groups of 8 elems
  if (id >= 49152) return;
  int lane = id & 63;
  int k0 = (id >> 6) & 7;
  int t9 = id >> 9;
  int sl = t9 % 6;
  int wb = t9 / 6;
  int wv = wb & 7;
  int dir = wb >> 3;
  int g = sl >> 1, jt = sl & 1;
  int l16 = lane & 15, quad = lane >> 4;
  int n = g * Hh + wv * 32 + jt * 16 + l16;
  const float* src = whh + ((size_t)dir * G3 + n) * Hh + k0 * 32 + quad * 8;
  bf16_t* dst = packed + (size_t)id * 8;
  #pragma unroll
  for (int i = 0; i < 8; ++i) dst[i] = (bf16_t)src[i];
}

// ---------- combined bias: biasC[dir][c] = bih[dir][c] + (c<512 ? bhh[dir][c] : 0) ----------
__global__ void k_biasC(const float* __restrict__ bih, const float* __restrict__ bhh,
                        float* __restrict__ out) {
  int i = blockIdx.x * 256 + threadIdx.x;
  if (i >= 2 * G3) return;
  int c = i % G3;
  out[i] = bih[i] + (c < 2 * Hh ? bhh[i] : 0.f);
}

// ---------- fused gather + input projection: gi(bf16) = embed[toks] @ wih^T + biasC ----------
__global__ __launch_bounds__(256) void k_giA(
    const int* __restrict__ toks, const void* __restrict__ embed,
    const float* __restrict__ wih, const float* __restrict__ bih,
    const int* __restrict__ flag, bf16_t* __restrict__ gi, int mbase) {
  __shared__ __align__(16) bf16_t Ah[64][32];
  __shared__ __align__(16) bf16_t Al[64][32];
  __shared__ __align__(16) bf16_t Bs[64][32];
  int tid = threadIdx.x;
  int wave = tid >> 6, lane = tid & 63;
  int l16 = lane & 15, quad = lane >> 4;
  int m0 = blockIdx.x * 64;
  int n0 = blockIdx.y * 64;
  int r  = tid >> 2;
  int kk = (tid & 3) * 8;
  int tok = toks[mbase + m0 + r];
  int isb = flag[0];
  const float*  ef = (const float*)embed + (size_t)tok * D_EMB;
  const bf16_t* eb = (const bf16_t*)embed + (size_t)tok * D_EMB;
  const float* wrow = wih + (size_t)(n0 + r) * D_EMB;
  f32x4 acc[4] = {{0.f,0.f,0.f,0.f},{0.f,0.f,0.f,0.f},{0.f,0.f,0.f,0.f},{0.f,0.f,0.f,0.f}};
  for (int k0 = 0; k0 < KP; k0 += 32) {
    int ka = k0 + kk;
    float av[8], bv[8];
    #pragma unroll
    for (int i = 0; i < 8; ++i) { av[i] = 0.f; bv[i] = 0.f; }
    if (ka < D_EMB) {
      if (isb) { bf16x4 t4 = *(const bf16x4*)(eb + ka);
                 av[0]=(float)t4[0]; av[1]=(float)t4[1]; av[2]=(float)t4[2]; av[3]=(float)t4[3]; }
      else     { float4 t4 = *(const float4*)(ef + ka);
                 av[0]=t4.x; av[1]=t4.y; av[2]=t4.z; av[3]=t4.w; }
      float4 w4 = *(const float4*)(wrow + ka);
      bv[0]=w4.x; bv[1]=w4.y; bv[2]=w4.z; bv[3]=w4.w;
    }
    if (ka + 4 < D_EMB) {
      if (isb) { bf16x4 t4 = *(const bf16x4*)(eb + ka + 4);
                 av[4]=(float)t4[0]; av[5]=(float)t4[1]; av[6]=(float)t4[2]; av[7]=(float)t4[3]; }
      else     { float4 t4 = *(const float4*)(ef + ka + 4);
                 av[4]=t4.x; av[5]=t4.y; av[6]=t4.z; av[7]=t4.w; }
      float4 w4 = *(const float4*)(wrow + ka + 4);
      bv[4]=w4.x; bv[5]=w4.y; bv[6]=w4.z; bv[7]=w4.w;
    }
    #pragma unroll
    for (int i = 0; i < 8; ++i) {
      bf16_t hi = (bf16_t)av[i];
      Ah[r][kk + i] = hi;
      Al[r][kk + i] = (bf16_t)(av[i] - (float)hi);
      Bs[r][kk + i] = (bf16_t)bv[i];
    }
    __syncthreads();
    bf16x8 ah = *(const bf16x8*)&Ah[wave * 16 + l16][quad * 8];
    bf16x8 al = *(const bf16x8*)&Al[wave * 16 + l16][quad * 8];
    #pragma unroll
    for (int j = 0; j < 4; ++j) {
      bf16x8 b8 = *(const bf16x8*)&Bs[j * 16 + l16][quad * 8];
      acc[j] = __builtin_amdgcn_mfma_f32_16x16x32_bf16(al, b8, acc[j], 0, 0, 0);
      acc[j] = __builtin_amdgcn_mfma_f32_16x16x32_bf16(ah, b8, acc[j], 0, 0, 0);
    }
    __syncthreads();
  }
  int row0 = m0 + wave * 16 + quad * 4;   // C/D: col=lane&15, row=quad*4+reg
  #pragma unroll
  for (int j = 0; j < 4; ++j) {
    int col = n0 + j * 16 + l16;
    float bvv = bih[col];
    #pragma unroll
    for (int rr = 0; rr < 4; ++rr)
      gi[(size_t)(row0 + rr) * G3 + col] = (bf16_t)(acc[j][rr] + bvv);
  }
}

// ---------- f32 SGEMM: C[M][N] = A[M][K] @ B[K][N] (+bias), out f32 or bf16 ----------
__global__ __launch_bounds__(256) void k_sgemm(
    const float* __restrict__ A, const float* __restrict__ B,
    const float* __restrict__ bias, void* __restrict__ C,
    int M, int N, int K, int obf) {
  __shared__ float As[32][65];
  __shared__ float Bs[32][65];
  int bm = blockIdx.x * 64, bn = blockIdx.y * 64;
  int tid = threadIdx.x;
  int tx = tid & 15, ty = tid >> 4;
  float acc[4][4] = {};
  for (int k0 = 0; k0 < K; k0 += 32) {
    for (int i = tid; i < 64 * 32; i += 256) {
      int m = i >> 5, k = i & 31;
      As[k][m] = (bm + m < M) ? A[(size_t)(bm + m) * K + k0 + k] : 0.f;
    }
    for (int i = tid; i < 32 * 64; i += 256) {
      int k = i >> 6, n = i & 63;
      Bs[k][n] = B[(size_t)(k0 + k) * N + bn + n];
    }
    __syncthreads();
    #pragma unroll 8
    for (int k = 0; k < 32; ++k) {
      float a[4], b[4];
      #pragma unroll
      for (int i = 0; i < 4; ++i) a[i] = As[k][ty + i * 16];
      #pragma unroll
      for (int j = 0; j < 4; ++j) b[j] = Bs[k][tx + j * 16];
      #pragma unroll
      for (int i = 0; i < 4; ++i)
        #pragma unroll
        for (int j = 0; j < 4; ++j) acc[i][j] += a[i] * b[j];
    }
    __syncthreads();
  }
  for (int i = 0; i < 4; ++i) {
    int m = bm + ty + i * 16;
    if (m >= M) continue;
    for (int j = 0; j < 4; ++j) {
      int n = bn + tx + j * 16;
      float v = acc[i][j] + (bias ? bias[n] : 0.f);
      if (obf) ((bf16_t*)C)[(size_t)m * N + n] = (bf16_t)v;
      else     ((float*)C)[(size_t)m * N + n] = v;
    }
  }
}

// ---------- batched MFMA GRU, whh register-resident via amdgpu_waves_per_eu(2,2) ----------
// 2 waves/EU -> 256-VGPR budget (launch_bounds' 2nd arg empirically does NOT raise the
// 128 cap on this compiler; rounds 5/8). h stored single-bf16 (no hi/lo) to fit:
// Bf 192 + C 24 + gv 24 + state ~14 = ~254 regs. gi is bf16.
__global__ __launch_bounds__(512)
__attribute__((amdgpu_waves_per_eu(2, 2)))
void k_gruM(
    const bf16_t* __restrict__ gi, size_t gi_dstride,
    const bf16_t* __restrict__ whhP, const float* __restrict__ bhh,
    const int* __restrict__ lens, float* __restrict__ pool,
    int T, int sbase, int nsent) {
  int dir = blockIdx.y;
  int tid = threadIdx.x;
  int wave = tid >> 6, lane = tid & 63;
  int l16 = lane & 15, quad = lane >> 4;
  int sblk = blockIdx.x * 16;
  const bf16_t* giD  = gi + (size_t)dir * gi_dstride;
  const float*  bhhD = bhh + (size_t)dir * G3;

  __shared__ __align__(16) bf16_t hA[8][4][16][8];   // [k0][q2][m][ii], single bf16 h
  {
    bf16_t* hz = &hA[0][0][0][0];
    for (int i = tid; i < 8 * 4 * 16 * 8; i += 512) hz[i] = (bf16_t)0.f;
  }

  // one-time coalesced load of this wave's whh fragments into registers (stays resident)
  bf16x8 Bf[48];
  {
    const bf16_t* Bb = whhP + (size_t)dir * G3 * Hh + (size_t)wave * 48 * 512 + lane * 8;
    #pragma unroll
    for (int s = 0; s < 48; ++s) Bf[s] = *(const bf16x8*)(Bb + s * 512);
  }
  float bhn[2];
  #pragma unroll
  for (int jt = 0; jt < 2; ++jt)
    bhn[jt] = bhhD[2 * Hh + wave * 32 + jt * 16 + l16];
  int Lm[4];
  #pragma unroll
  for (int r = 0; r < 4; ++r) {
    int sa = sblk + quad * 4 + r;
    Lm[r] = (lens && sa < nsent) ? lens[sbase + sa] : T;
  }
  float pmax[2][4];
  #pragma unroll
  for (int jt = 0; jt < 2; ++jt)
    #pragma unroll
    for (int r = 0; r < 4; ++r) pmax[jt][r] = -1e30f;

  // incremental gi row pointers (advance by +-G3 per step)
  int t0 = dir ? (T - 1) : 0;
  long long stepoff = dir ? -(long long)G3 : (long long)G3;
  const bf16_t* rp[4];
  #pragma unroll
  for (int r = 0; r < 4; ++r)
    rp[r] = giD + ((size_t)(sblk + quad * 4 + r) * T + t0) * (size_t)G3;

  __syncthreads();

  for (int step = 0; step < T; ++step) {
    int t = dir ? (T - 1 - step) : step;
    // MFMA phase: gh = h @ whh^T  (B register-resident, A from LDS)
    f32x4 C[3][2];
    #pragma unroll
    for (int g = 0; g < 3; ++g)
      #pragma unroll
      for (int jt = 0; jt < 2; ++jt) C[g][jt] = (f32x4){0.f, 0.f, 0.f, 0.f};
    #pragma unroll
    for (int k0 = 0; k0 < 8; ++k0) {
      bf16x8 a8 = *(const bf16x8*)&hA[k0][quad][l16][0];
      #pragma unroll
      for (int g = 0; g < 3; ++g)
        #pragma unroll
        for (int jt = 0; jt < 2; ++jt)
          C[g][jt] = __builtin_amdgcn_mfma_f32_16x16x32_bf16(a8, Bf[(g * 2 + jt) * 8 + k0], C[g][jt], 0, 0, 0);
    }
    __syncthreads();   // hA reads complete before rewrite
    // gi loads (bf16; bih + bhh(r,z) pre-folded by k_biasC)
    float gv[3][2][4];
    #pragma unroll
    for (int jt = 0; jt < 2; ++jt) {
      int j = wave * 32 + jt * 16 + l16;
      #pragma unroll
      for (int r = 0; r < 4; ++r) {
        gv[0][jt][r] = (float)rp[r][j];
        gv[1][jt][r] = (float)rp[r][Hh + j];
        gv[2][jt][r] = (float)rp[r][2 * Hh + j];
      }
    }
    #pragma unroll
    for (int jt = 0; jt < 2; ++jt) {
      int q2 = jt * 2 + (l16 >> 3);
      int ii = l16 & 7;
      #pragma unroll
      for (int r = 0; r < 4; ++r) {
        int m = quad * 4 + r;
        float hp = (float)hA[wave][q2][m][ii];
        float rr = 1.f / (1.f + expf(-(gv[0][jt][r] + C[0][jt][r])));
        float zz = 1.f / (1.f + expf(-(gv[1][jt][r] + C[1][jt][r])));
        float nn = tanhf(gv[2][jt][r] + rr * (C[2][jt][r] + bhn[jt]));
        float hnew = (1.f - zz) * nn + zz * hp;
        hA[wave][q2][m][ii] = (bf16_t)hnew;
        if (t < Lm[r]) pmax[jt][r] = fmaxf(pmax[jt][r], hnew);
      }
    }
    #pragma unroll
    for (int r = 0; r < 4; ++r) rp[r] += stepoff;
    __syncthreads();   // h writes visible before next step's A reads
  }
  #pragma unroll
  for (int jt = 0; jt < 2; ++jt) {
    int j = wave * 32 + jt * 16 + l16;
    #pragma unroll
    for (int r = 0; r < 4; ++r) {
      int sa = sblk + quad * 4 + r;
      if (sa < nsent) {
        float v = pmax[jt][r];
        if (v < -9e29f) v = 0.f;
        pool[(size_t)(sbase + sa) * H2 + dir * Hh + j] = v;
      }
    }
  }
}

// ---------- epilogue ----------
__global__ __launch_bounds__(512) void k_colsumP(const float* __restrict__ ev, float* __restrict__ part) {
  int t = threadIdx.x;
  int r0 = blockIdx.x * 64;
  float s = 0.f;
  for (int r = 0; r < 64; ++r) s += ev[(size_t)(r0 + r) * H2 + t];
  part[(size_t)blockIdx.x * H2 + t] = s;
}
__global__ __launch_bounds__(512) void k_esum(const float* __restrict__ part, float* __restrict__ out) {
  int t = threadIdx.x;
  float s = 0.f;
  for (int b = 0; b < 48; ++b) s += part[(size_t)b * H2 + t];
  out[t] = s;
}

__global__ void k_ves(const float* __restrict__ W, const float* __restrict__ sum, float* __restrict__ ves) {
  int d = blockIdx.x * 64 + threadIdx.x;
  const float* row = W + (size_t)d * H2;
  float s = 0.f;
  for (int f = 0; f < H2; ++f) s += row[f] * sum[f];
  ves[d] = s * (1.f / 3072.f);
}

__global__ void k_sal(const float* __restrict__ W, const float* __restrict__ blog,
                      const float* __restrict__ dv, float* __restrict__ out) {
  int doc = blockIdx.y;
  int i = blockIdx.x * 64 + threadIdx.x;
  const float* row = W + (size_t)i * (2 * H2);
  const float* dvr = dv + (size_t)doc * H2;
  float s = 0.f;
  for (int f = 0; f < H2; ++f) s += row[f] * blog[f];
  for (int f = 0; f < H2; ++f) s += row[H2 + f] * dvr[f];
  out[(size_t)doc * H2 + i] = s;
}

__global__ __launch_bounds__(256) void k_eventprobs(
    const float* __restrict__ evv, const float* __restrict__ ves,
    const float* __restrict__ w_ec, const float* __restrict__ tfs,
    const float* __restrict__ st, const float* __restrict__ c_tf,
    const float* __restrict__ c_sent, const float* __restrict__ c_bias,
    const int* __restrict__ flag, float* __restrict__ probs, void* __restrict__ outp) {
  int lane = threadIdx.x & 63;
  int e = blockIdx.x * 4 + (threadIdx.x >> 6);
  const float* row = evv + (size_t)e * H2;
  float s = 0.f;
  for (int f = lane; f < H2; f += 64) s += row[f] * (w_ec[f] + ves[f]);
  #pragma unroll
  for (int o = 32; o > 0; o >>= 1) s += __shfl_down(s, o, 64);
  if (lane == 0) {
    float p = s + c_tf[0] * tfs[e] + c_bias[0] + c_sent[0] * st[e / 3];
    probs[e] = p;
    if (flag[0]) ((bf16_t*)outp)[S_TOT + e] = (bf16_t)p;
    else         ((float*)outp)[S_TOT + e] = p;
  }
}

__global__ __launch_bounds__(256) void k_sentout(
    const float* __restrict__ sv, const float* __restrict__ u,
    const float* __restrict__ evv, const float* __restrict__ probs,
    const float* __restrict__ wsal, const float* __restrict__ w_sc,
    const float* __restrict__ dpe, const float* __restrict__ spe,
    const float* __restrict__ w_sdp, const float* __restrict__ w_sp,
    const float* __restrict__ b_rel, const float* __restrict__ para,
    const float* __restrict__ sbias, const int* __restrict__ flag,
    void* __restrict__ outp) {
  int lane = threadIdx.x & 63;
  int s = blockIdx.x * 4 + (threadIdx.x >> 6);
  int doc = s >> 5, jj = s & 31;
  const float* svr = sv + (size_t)s * H2;
  const float* ur  = u + (size_t)s * H2;
  const float* wd  = wsal + (size_t)doc * H2;
  float acc = 0.f, e0 = 0.f, e1 = 0.f, e2 = 0.f;
  for (int f = lane; f < H2; f += 64) {
    float svf = svr[f], uf = ur[f];
    acc += svf * (w_sc[f] + wd[f]);
    e0 += uf * evv[(size_t)(s * 3 + 0) * H2 + f];
    e1 += uf * evv[(size_t)(s * 3 + 1) * H2 + f];
    e2 += uf * evv[(size_t)(s * 3 + 2) * H2 + f];
  }
  if (lane < 50) {
    int dpos = (doc * 40) / 32;
    int spos = (jj * 30) / 32;
    acc += dpe[dpos * 50 + lane] * w_sdp[lane] + spe[spos * 50 + lane] * w_sp[lane];
  }
  #pragma unroll
  for (int o = 32; o > 0; o >>= 1) {
    acc += __shfl_down(acc, o, 64);
    e0  += __shfl_down(e0, o, 64);
    e1  += __shfl_down(e1, o, 64);
    e2  += __shfl_down(e2, o, 64);
  }
  if (lane == 0) {
    float br = b_rel[0];
    float rel = (e0 + br) * probs[s * 3 + 0] + (e1 + br) * probs[s * 3 + 1]
              + (e2 + br) * probs[s * 3 + 2];
    float v = acc + para[0] * rel + sbias[0];
    if (flag[0]) ((bf16_t*)outp)[s] = (bf16_t)v;
    else         ((float*)outp)[s] = v;
  }
}

// ---------------- launcher ----------------
extern "C" void kernel_launch(void* const* d_in, const int* in_sizes, int n_in,
                              void* d_out, int out_size, void* d_ws, size_t ws_size,
                              hipStream_t stream) {
  (void)in_sizes; (void)n_in; (void)out_size;
  const int* x      = (const int*)d_in[0];
  const int* events = (const int*)d_in[1];
  const void* embed = d_in[8];

  char* ws = (char*)d_ws;
  size_t off = 0;
  auto alloc = [&](size_t bytes) -> void* {
    void* p = ws + off;
    off += (bytes + 255) & ~(size_t)255;
    return p;
  };

  static const int cidx[NCANON] = {9,10,11,12, 13,14,15,16, 17,18,19,20, 21,22,23,24,
                                   25,26,27,28,29,30,31, 32,33,34,35, 36,37,38,40, 5,7};
  static const int csz[NCANON]  = {2*G3*D_EMB, 2*G3*Hh, 2*G3, 2*G3,
                                   2*G3*H2,    2*G3*Hh, 2*G3, 2*G3,
                                   2*G3*H2,    2*G3*Hh, 2*G3, 2*G3,
                                   2*G3*D_EMB, 2*G3*Hh, 2*G3, 2*G3,
                                   40*50, 30*50, H2, H2*H2, 1, 1, 1,
                                   H2, H2*2*H2, 50, 50,
                                   H2*H2, 1, 1, 1, E_TOT, S_TOT};
  Canon cd;
  int tot = 0;
  for (int i = 0; i < NCANON; ++i) { cd.src[i] = d_in[cidx[i]]; cd.off[i] = tot; tot += csz[i]; }
  cd.off[NCANON] = tot;

  int*   flag  = (int*)alloc(256);
  float* canon = (float*)alloc((size_t)tot * 4);
  float* cptr[NCANON];
  for (int i = 0; i < NCANON; ++i) cptr[i] = canon + cd.off[i];
  float *cw_wih = cptr[0], *cw_whh = cptr[1], *cw_bih = cptr[2], *cw_bhh = cptr[3];
  float *cs_wih = cptr[4], *cs_whh = cptr[5], *cs_bih = cptr[6], *cs_bhh = cptr[7];
  float *cd_wih = cptr[8], *cd_whh = cptr[9], *cd_bih = cptr[10], *cd_bhh = cptr[11];
  float *ce_wih = cptr[12], *ce_whh = cptr[13], *ce_bih = cptr[14], *ce_bhh = cptr[15];
  float *c_dpe = cptr[16], *c_spe = cptr[17], *c_wec = cptr[18], *c_Wes = cptr[19];
  float *c_tf = cptr[20], *c_sent = cptr[21], *c_ebias = cptr[22];
  float *c_wsc = cptr[23], *c_Wss = cptr[24], *c_wsdp = cptr[25], *c_wsp = cptr[26];
  float *c_Wer = cptr[27], *c_brel = cptr[28], *c_para = cptr[29], *c_sbias = cptr[30];
  float *c_tfs = cptr[31], *c_starg = cptr[32];

  bf16_t* packW = (bf16_t*)alloc((size_t)2 * G3 * Hh * 2);
  bf16_t* packE = (bf16_t*)alloc((size_t)2 * G3 * Hh * 2);
  bf16_t* packS = (bf16_t*)alloc((size_t)2 * G3 * Hh * 2);
  bf16_t* packD = (bf16_t*)alloc((size_t)2 * G3 * Hh * 2);
  float*  bcW  = (float*)alloc((size_t)2 * G3 * 4);
  float*  bcE  = (float*)alloc((size_t)2 * G3 * 4);
  float*  bcS  = (float*)alloc((size_t)2 * G3 * 4);
  float*  bcD  = (float*)alloc((size_t)2 * G3 * 4);
  float*  sv   = (float*)alloc((size_t)S_TOT * H2 * 4);
  float*  evv  = (float*)alloc((size_t)E_TOT * H2 * 4);
  float*  dv   = (float*)alloc((size_t)32 * H2 * 4);
  float*  blog = (float*)alloc((size_t)H2 * 4);
  float*  wSt  = (float*)alloc((size_t)2 * H2 * G3 * 4);
  float*  wDt  = (float*)alloc((size_t)2 * H2 * G3 * 4);
  float*  u    = (float*)alloc((size_t)S_TOT * H2 * 4);
  float*  part = (float*)alloc((size_t)48 * H2 * 4);
  float*  esum = (float*)alloc((size_t)H2 * 4);
  float*  ves  = (float*)alloc((size_t)H2 * 4);
  float*  wsal = (float*)alloc((size_t)32 * H2 * 4);
  float*  probs= (float*)alloc((size_t)E_TOT * 4);
  int*    lens = (int*)alloc((size_t)S_TOT * 4);
  bf16_t* sgi  = (bf16_t*)alloc((size_t)2 * S_TOT * G3 * 2);  // bf16 now
  bf16_t* dgi  = (bf16_t*)alloc((size_t)2 * 32 * G3 * 2);

  size_t fixed = off;
  size_t avail = (ws_size > fixed) ? (ws_size - fixed) : 0;
  long long rpc = (long long)(avail / ((size_t)G3 * 2 * 2));   // bf16 rows, both dirs
  rpc &= ~511LL;
  if (rpc < 512) rpc = 512;
  if (rpc > 32768) rpc = 32768;
  bf16_t* gib = (bf16_t*)(ws + fixed);

  // ---- prep ----
  k_detect<<<1, 64, 0, stream>>>((const unsigned short*)embed, flag);
  k_canon<<<(tot + 255) / 256, 256, 0, stream>>>(cd, flag, canon);
  k_packB<<<192, 256, 0, stream>>>(cw_whh, packW);
  k_packB<<<192, 256, 0, stream>>>(ce_whh, packE);
  k_packB<<<192, 256, 0, stream>>>(cs_whh, packS);
  k_packB<<<192, 256, 0, stream>>>(cd_whh, packD);
  k_biasC<<<6, 256, 0, stream>>>(cw_bih, cw_bhh, bcW);
  k_biasC<<<6, 256, 0, stream>>>(ce_bih, ce_bhh, bcE);
  k_biasC<<<6, 256, 0, stream>>>(cs_bih, cs_bhh, bcS);
  k_biasC<<<6, 256, 0, stream>>>(cd_bih, cd_bhh, bcD);
  k_lens<<<4, 256, 0, stream>>>(x, lens);
  k_transpose<<<dim3(24, 16, 2), 256, 0, stream>>>(cs_wih, wSt);
  k_transpose<<<dim3(24, 16, 2), 256, 0, stream>>>(cd_wih, wDt);

  // ---- word BiGRU -> sent_vec ----
  for (long long r0 = 0; r0 < 32768; r0 += rpc) {
    long long rows = 32768 - r0; if (rows > rpc) rows = rpc;
    for (int d = 0; d < 2; ++d)
      k_giA<<<dim3((int)(rows / 64), 12), 256, 0, stream>>>(
          x, embed, cw_wih + (size_t)d * G3 * D_EMB, bcW + d * G3, flag,
          gib + (size_t)d * rows * G3, (int)r0);
    k_gruM<<<dim3((int)(rows / 512), 2), 512, 0, stream>>>(
        gib, (size_t)rows * G3, packW, cw_bhh, lens, sv, 32, (int)(r0 / 32),
        (int)(rows / 32));
  }
  // ---- event BiGRU -> event_vec ----
  for (long long r0 = 0; r0 < 12288; r0 += rpc) {
    long long rows = 12288 - r0; if (rows > rpc) rows = rpc;
    for (int d = 0; d < 2; ++d)
      k_giA<<<dim3((int)(rows / 64), 12), 256, 0, stream>>>(
          events, embed, ce_wih + (size_t)d * G3 * D_EMB, bcE + d * G3, flag,
          gib + (size_t)d * rows * G3, (int)r0);
    k_gruM<<<dim3((int)(rows / 64), 2), 512, 0, stream>>>(
        gib, (size_t)rows * G3, packE, ce_bhh, nullptr, evv, 4, (int)(r0 / 4),
        (int)(rows / 4));
  }
  // ---- sent BiGRU (batch=32 docs, T=32) -> doc_vec ----
  for (int d = 0; d < 2; ++d)
    k_sgemm<<<dim3(16, 12), 256, 0, stream>>>(sv, wSt + (size_t)d * H2 * G3,
                                              bcS + d * G3,
                                              sgi + (size_t)d * S_TOT * G3, 1024, G3, H2, 1);
  k_gruM<<<dim3(2, 2), 512, 0, stream>>>(sgi, (size_t)S_TOT * G3, packS, cs_bhh,
                                         nullptr, dv, 32, 0, 32);
  // ---- doc BiGRU (batch=1, T=32) -> blog_vec ----
  for (int d = 0; d < 2; ++d)
    k_sgemm<<<dim3(1, 12), 256, 0, stream>>>(dv, wDt + (size_t)d * H2 * G3,
                                             bcD + d * G3,
                                             dgi + (size_t)d * 32 * G3, 32, G3, H2, 1);
  k_gruM<<<dim3(1, 2), 512, 0, stream>>>(dgi, (size_t)32 * G3, packD, cd_bhh,
                                         nullptr, blog, 32, 0, 1);
  // ---- u = sent_vec @ W_event_rel (f32 out) ----
  k_sgemm<<<dim3(16, 8), 256, 0, stream>>>(sv, c_Wer, nullptr, u, 1024, H2, H2, 0);
  // ---- event_sum, ves, wsal ----
  k_colsumP<<<48, 512, 0, stream>>>(evv, part);
  k_esum<<<1, 512, 0, stream>>>(part, esum);
  k_ves<<<8, 64, 0, stream>>>(c_Wes, esum, ves);
  k_sal<<<dim3(8, 32), 64, 0, stream>>>(c_Wss, blog, dv, wsal);
  // ---- outputs ----
  k_eventprobs<<<768, 256, 0, stream>>>(evv, ves, c_wec, c_tfs, c_starg,
                                        c_tf, c_sent, c_ebias, flag, probs, d_out);
  k_sentout<<<256, 256, 0, stream>>>(sv, u, evv, probs, wsal, c_wsc, c_dpe, c_spe,
                                     c_wsdp, c_wsp, c_brel, c_para, c_sbias, flag, d_out);
}